// Round 7
// baseline (744.076 us; speedup 1.0000x reference)
//
#include <hip/hip_runtime.h>
#include <hip/hip_bf16.h>

// Round 7: conv1 K-loop icc-outer (tap-halo reuse lands in L1; w1bf re-laid),
//          gmap + lmap get explicit depth-2 register pipelines.
// ws layout (61.28 MB, aliased):
//   [0, 39,337,984)           hcat8 bf16 [8][8][9604][32]   -- ALSO curbf bf16 [8][9216][256] (dead at memset)
//   [39,337,984, 40,567,296)  hcat1 bf16 [8][9604][8] (tail ch 256..263)
//   [40,567,296, 59,441,664)  hmid bf16 [8][128][9216]
//       -- phase1 alias: fibf bf16 [8][640][256] @ +0, si f32 [8][2][640] @ +2,621,440
//       -- phase2 alias: prevbf bf16 [4][9216][256] (exactly 18,874,368 B)
//   [59,441,664, 60,105,216)  W1bf bf16 [81][128][32]  (slab s = icc*9+tap)
//   [60,105,216, 60,695,040)  gout f32 [8][2][9216]
//   [60,695,040, 61,284,864)  lout f32 [8][2][9216]

typedef __hip_bfloat16 bf16;
typedef __attribute__((ext_vector_type(8))) short short8;
typedef __attribute__((ext_vector_type(4))) float f32x4;

constexpr int B_  = 8;
constexpr int C_  = 256;
constexpr int H_  = 96;
constexpr int W_  = 96;
constexpr int HW_ = H_ * W_;       // 9216
constexpr int PW_ = 24;
constexpr int KP_ = 576;
constexpr int KPP = 640;
constexpr int HP_ = 98;
constexpr int HPW = HP_ * HP_;     // 9604
constexpr int C1O = 128;
constexpr int CHK = HPW * 32;      // per 32-ch chunk

__device__ __forceinline__ unsigned short bfb(float f) {
    bf16 h = __float2bfloat16(f);
    return *reinterpret_cast<unsigned short*>(&h);
}

// ------------------------------------------------------------ W1 convert ----
// slab s = icc*9 + tap : [128 oc][32 ic]
__global__ __launch_bounds__(256)
void w1cvt_kernel(const float* __restrict__ W1, bf16* __restrict__ w1bf)
{
    int idx = blockIdx.x * 256 + threadIdx.x;
    if (idx >= 81 * 128 * 32) return;
    int ic = idx & 31;
    int oc = (idx >> 5) & 127;
    int ks = idx >> 12;
    int icc = ks / 9, tap = ks % 9;
    int icg = icc * 32 + ic;
    float v = (icg < 264) ? W1[((size_t)oc * 264 + icg) * 9 + tap] : 0.f;
    w1bf[idx] = __float2bfloat16(v);
}

// ------------------------------------------------------- NCHW->NHWC bf16 ----
__global__ __launch_bounds__(256)
void tcur_kernel(const float* __restrict__ cur, bf16* __restrict__ curbf)
{
    __shared__ float tile[64][68];
    int b = blockIdx.z, c0 = blockIdx.y * 64, p0 = blockIdx.x * 64;
    int t = threadIdx.x;
    const float* src = cur + ((size_t)b * C_ + c0) * HW_ + p0;
    #pragma unroll
    for (int it = 0; it < 4; it++) {
        int f = t + it * 256;
        int cl = f >> 4, p4 = (f & 15) * 4;
        float4 v = *reinterpret_cast<const float4*>(src + (size_t)cl * HW_ + p4);
        *reinterpret_cast<float4*>(&tile[cl][p4]) = v;
    }
    __syncthreads();
    bf16* dst = curbf + ((size_t)b * HW_ + p0) * 256 + c0;
    #pragma unroll
    for (int it = 0; it < 4; it++) {
        int f = t + it * 256;
        int pl = f >> 4, c4 = (f & 15) * 4;
        ushort4 u;
        u.x = bfb(tile[c4 + 0][pl]); u.y = bfb(tile[c4 + 1][pl]);
        u.z = bfb(tile[c4 + 2][pl]); u.w = bfb(tile[c4 + 3][pl]);
        *reinterpret_cast<ushort4*>(dst + (size_t)pl * 256 + c4) = u;
    }
}

// ---------------------------------------------------------------- pool ----
__global__ __launch_bounds__(256)
void pool_kernel(const float* __restrict__ init_embed,
                 const float* __restrict__ init_seg,
                 bf16* __restrict__ fibf, float* __restrict__ si)
{
    int idx = blockIdx.x * 256 + threadIdx.x;
    int total = B_ * (C_ + 2) * KPP;
    if (idx >= total) return;
    int k  = idx % KPP;
    int ch = (idx / KPP) % (C_ + 2);
    int b  = idx / (KPP * (C_ + 2));
    float s = 0.f;
    if (k < KP_) {
        int ph = k / PW_, pw = k % PW_;
        const float* src = (ch < C_)
            ? (init_embed + (((size_t)b * C_ + ch) * H_ + ph * 4) * W_ + pw * 4)
            : (init_seg   + (((size_t)b * 2 + (ch - C_)) * H_ + ph * 4) * W_ + pw * 4);
        #pragma unroll
        for (int r = 0; r < 4; r++) {
            float4 v = *reinterpret_cast<const float4*>(src + r * W_);
            s += v.x + v.y + v.z + v.w;
        }
        s *= (1.f / 16.f);
    }
    if (ch < C_) fibf[((size_t)b * KPP + k) * C_ + ch] = __float2bfloat16(s);
    else         si[(size_t)b * 2 * KPP + (ch - C_) * KPP + k] = s;
}

// ---------------------------------------------------------------- gmap ----
// Pipelined: 40 flattened (ch,kc) steps, 3 rotating frag buffers (depth 2),
// per-chunk seg-max epilogue in-loop.
__global__ __launch_bounds__(128)
void gmap_mfma(const bf16* __restrict__ curbf, const bf16* __restrict__ fibf,
               const float* __restrict__ si, float* __restrict__ gout)
{
    __shared__ float bred[2][2][64];
    int b = blockIdx.y;
    int p0 = blockIdx.x * 64;
    int t = threadIdx.x, lane = t & 63, wm = t >> 6;
    int l15 = lane & 15, lk = lane >> 4;
    const bf16* cb = curbf + (size_t)b * HW_ * 256;
    const bf16* fb = fibf + (size_t)b * KPP * 256;
    const float* sib = si + (size_t)b * 2 * KPP;
    size_t bo[4];
    #pragma unroll
    for (int nt = 0; nt < 4; nt++)
        bo[nt] = (size_t)(p0 + nt * 16 + l15) * 256 + lk * 8;
    float best[2][4];
    #pragma unroll
    for (int s = 0; s < 2; s++)
        #pragma unroll
        for (int nt = 0; nt < 4; nt++) best[s][nt] = -INFINITY;

    short8 ab[3][4], bb[3][4];
    auto LOADG = [&](int s, int ph) {
        int ch = s >> 3, kc = s & 7;
        #pragma unroll
        for (int mt = 0; mt < 4; mt++)
            ab[ph][mt] = *reinterpret_cast<const short8*>(
                fb + (size_t)(ch * 128 + wm * 64 + mt * 16 + l15) * 256 + kc * 32 + lk * 8);
        #pragma unroll
        for (int nt = 0; nt < 4; nt++)
            bb[ph][nt] = *reinterpret_cast<const short8*>(cb + bo[nt] + kc * 32);
    };

    f32x4 acc[4][4] = {};
    LOADG(0, 0); LOADG(1, 1);
    #pragma unroll
    for (int s = 0; s < 40; ++s) {
        int ph = s % 3;
        if (s + 2 < 40) LOADG(s + 2, (s + 2) % 3);
        #pragma unroll
        for (int mt = 0; mt < 4; mt++)
            #pragma unroll
            for (int nt = 0; nt < 4; nt++)
                acc[mt][nt] = __builtin_amdgcn_mfma_f32_16x16x32_bf16(
                    ab[ph][mt], bb[ph][nt], acc[mt][nt], 0, 0, 0);
        if ((s & 7) == 7) {
            int kp0 = (s >> 3) * 128;
            #pragma unroll
            for (int mt = 0; mt < 4; mt++) {
                int rb = kp0 + wm * 64 + mt * 16 + lk * 4;
                float4 s0 = *reinterpret_cast<const float4*>(sib + rb);
                float4 s1 = *reinterpret_cast<const float4*>(sib + KPP + rb);
                const float* s0p = reinterpret_cast<const float*>(&s0);
                const float* s1p = reinterpret_cast<const float*>(&s1);
                #pragma unroll
                for (int nt = 0; nt < 4; nt++) {
                    #pragma unroll
                    for (int r = 0; r < 4; r++) {
                        float v = acc[mt][nt][r];
                        best[0][nt] = fmaxf(best[0][nt], v * s0p[r]);
                        best[1][nt] = fmaxf(best[1][nt], v * s1p[r]);
                    }
                    acc[mt][nt] = (f32x4){0.f, 0.f, 0.f, 0.f};
                }
            }
        }
    }
    #pragma unroll
    for (int s = 0; s < 2; s++)
        #pragma unroll
        for (int nt = 0; nt < 4; nt++) {
            float v = best[s][nt];
            v = fmaxf(v, __shfl_xor(v, 16));
            v = fmaxf(v, __shfl_xor(v, 32));
            if (lk == 0) bred[wm][s][nt * 16 + l15] = v;
        }
    __syncthreads();
    if (t < 128) {
        int s = t >> 6, pxl = t & 63;
        gout[((size_t)b * 2 + s) * HW_ + p0 + pxl] = fmaxf(bred[0][s][pxl], bred[1][s][pxl]);
    }
}

// ---------------------------------------------------------------- lmap ----
__global__ __launch_bounds__(256)
void lmap_mfma(const bf16* __restrict__ curbf, const bf16* __restrict__ prevbf,
               const float* __restrict__ prev_seg, float* __restrict__ lout, int b0)
{
    constexpr int GSTR = 257;
    constexpr int SEGB = 64 * GSTR;
    constexpr int REDB = SEGB + 512;
    __shared__ float gl[REDB + 256];
    int b = b0 + blockIdx.y;
    const bf16* pb = prevbf + (size_t)blockIdx.y * HW_ * 256;
    const bf16* cb = curbf + (size_t)b * HW_ * 256;
    int tile = blockIdx.x;
    int ty0 = (tile / 12) * 8, tx0 = (tile % 12) * 8;
    int t = threadIdx.x, lane = t & 63, wq = t >> 6;
    int l15 = lane & 15, lk = lane >> 4;

    size_t aoff[4];
    #pragma unroll
    for (int mt = 0; mt < 4; mt++) {
        int m = mt * 16 + l15;
        int gpx = (ty0 + (m >> 3)) * W_ + tx0 + (m & 7);
        aoff[mt] = (size_t)gpx * 256 + lk * 8;
    }
    bool pred[4];
    size_t boff[4];
    int gx = tx0 - 4 + l15;
    bool colok = (gx >= 0) && (gx < W_);
    #pragma unroll
    for (int nt = 0; nt < 4; nt++) {
        int gy = ty0 - 4 + wq * 4 + nt;
        pred[nt] = colok && (gy >= 0) && (gy < H_);
        boff[nt] = pred[nt] ? ((size_t)(gy * W_ + gx) * 256 + lk * 8) : 0;
    }

    const short8 Z8 = {0, 0, 0, 0, 0, 0, 0, 0};
    short8 ab[3][4], bb[3][4];
    auto LOADL = [&](int s, int ph) {
        #pragma unroll
        for (int mt = 0; mt < 4; mt++)
            ab[ph][mt] = *reinterpret_cast<const short8*>(cb + aoff[mt] + s * 32);
        #pragma unroll
        for (int nt = 0; nt < 4; nt++) {
            short8 v = Z8;
            if (pred[nt]) v = *reinterpret_cast<const short8*>(pb + boff[nt] + s * 32);
            bb[ph][nt] = v;
        }
    };

    f32x4 acc[4][4] = {};
    LOADL(0, 0); LOADL(1, 1);
    #pragma unroll
    for (int s = 0; s < 8; ++s) {
        int ph = s % 3;
        if (s + 2 < 8) LOADL(s + 2, (s + 2) % 3);
        #pragma unroll
        for (int mt = 0; mt < 4; mt++)
            #pragma unroll
            for (int nt = 0; nt < 4; nt++)
                acc[mt][nt] = __builtin_amdgcn_mfma_f32_16x16x32_bf16(
                    ab[ph][mt], bb[ph][nt], acc[mt][nt], 0, 0, 0);
    }
    #pragma unroll
    for (int mt = 0; mt < 4; mt++)
        #pragma unroll
        for (int nt = 0; nt < 4; nt++)
            #pragma unroll
            for (int r = 0; r < 4; r++)
                gl[(mt * 16 + lk * 4 + r) * GSTR + wq * 64 + nt * 16 + l15] = acc[mt][nt][r];
    #pragma unroll
    for (int it = 0; it < 2; it++) {
        int f = t + it * 256;
        int s = f >> 8, wp = f & 255;
        int wy = wp >> 4, wx = wp & 15;
        int gy = ty0 - 4 + wy, gxx = tx0 - 4 + wx;
        float v = 0.f;
        if (gy >= 0 && gy < H_ && gxx >= 0 && gxx < W_)
            v = prev_seg[((size_t)b * 2 + s) * HW_ + gy * W_ + gxx] * (1.f / 256.f);
        gl[SEGB + f] = v;
    }
    __syncthreads();
    {
        int m = t & 63;
        int sh = t >> 6;
        int s = sh >> 1, hh = sh & 1;
        int py = m >> 3, lx = m & 7;
        const float* gr = gl + m * GSTR;
        const float* sr = gl + SEGB + s * 256;
        float mx = -INFINITY;
        int wr0 = hh * 5, wr1 = hh ? 9 : 5;
        for (int wr = wr0; wr < wr1; ++wr) {
            int base = (py + wr) * 16 + lx;
            #pragma unroll
            for (int wc = 0; wc < 9; ++wc)
                mx = fmaxf(mx, gr[base + wc] * sr[base + wc]);
        }
        gl[REDB + sh * 64 + m] = mx;
    }
    __syncthreads();
    if (t < 128) {
        int s = t >> 6, m = t & 63;
        float v = fmaxf(gl[REDB + (s * 2 + 0) * 64 + m], gl[REDB + (s * 2 + 1) * 64 + m]);
        int gpx = (ty0 + (m >> 3)) * W_ + tx0 + (m & 7);
        lout[((size_t)b * 2 + s) * HW_ + gpx] = v;
    }
}

// ---------------------------------------------------------------- packs ----
__global__ __launch_bounds__(256)
void pack_dec_kernel(const float* __restrict__ dec, bf16* __restrict__ hcat8)
{
    __shared__ float tile[64][68];
    int b = blockIdx.z, c0 = blockIdx.y * 64, p0 = blockIdx.x * 64;
    int t = threadIdx.x;
    const float* src = dec + ((size_t)b * C_ + c0) * HW_ + p0;
    #pragma unroll
    for (int it = 0; it < 4; it++) {
        int f = t + it * 256;
        int cl = f >> 4, p4 = (f & 15) * 4;
        float4 v = *reinterpret_cast<const float4*>(src + (size_t)cl * HW_ + p4);
        *reinterpret_cast<float4*>(&tile[cl][p4]) = v;
    }
    __syncthreads();
    #pragma unroll
    for (int it = 0; it < 4; it++) {
        int f = t + it * 256;
        int pl = f >> 4, c4 = (f & 15) * 4;
        int p = p0 + pl;
        int y = p / 96, x = p % 96;
        int pos = (y + 1) * HP_ + x + 1;
        int ch = c0 + c4;
        ushort4 u;
        u.x = bfb(tile[c4 + 0][pl]); u.y = bfb(tile[c4 + 1][pl]);
        u.z = bfb(tile[c4 + 2][pl]); u.w = bfb(tile[c4 + 3][pl]);
        bf16* dst = hcat8 + ((size_t)b * 8 + (ch >> 5)) * CHK + (size_t)pos * 32 + (ch & 31);
        *reinterpret_cast<ushort4*>(dst) = u;
    }
}

__global__ __launch_bounds__(256)
void pack_small_kernel(const float* __restrict__ gout,
                       const float* __restrict__ lout,
                       const float* __restrict__ init_seg,
                       const float* __restrict__ prev_seg,
                       bf16* __restrict__ hcat1)
{
    int idx = blockIdx.x * 256 + threadIdx.x;
    if (idx >= B_ * HW_) return;
    int b = idx / HW_, p = idx % HW_;
    int y = p / 96, x = p % 96;
    int pos = (y + 1) * HP_ + x + 1;
    bf16* dst = hcat1 + ((size_t)b * HPW + pos) * 8;
    float g0 = gout[((size_t)b * 2 + 0) * HW_ + p];
    float g1 = gout[((size_t)b * 2 + 1) * HW_ + p];
    float i0 = init_seg[((size_t)b * 2 + 0) * HW_ + p];
    float i1 = init_seg[((size_t)b * 2 + 1) * HW_ + p];
    float l0 = lout[((size_t)b * 2 + 0) * HW_ + p];
    float l1 = lout[((size_t)b * 2 + 1) * HW_ + p];
    float q0 = prev_seg[((size_t)b * 2 + 0) * HW_ + p];
    float q1 = prev_seg[((size_t)b * 2 + 1) * HW_ + p];
    ushort4 u; u.x = bfb(g0); u.y = bfb(g1); u.z = bfb(i0); u.w = bfb(i1);
    *reinterpret_cast<ushort4*>(dst) = u;
    ushort4 u2; u2.x = bfb(l0); u2.y = bfb(l1); u2.z = bfb(q0); u2.w = bfb(q1);
    *reinterpret_cast<ushort4*>(dst + 4) = u2;
}

// ---------------------------------------------------------------- conv1 ----
// icc-outer / tap-inner: 9 tap-shifted reads of the same strip window fall in
// 9 consecutive steps -> L1-resident. XCD swizzle + depth-3 pipeline kept.
__global__ __launch_bounds__(128)
void conv1_mfma(const bf16* __restrict__ hcat8, const bf16* __restrict__ hcat1,
                const bf16* __restrict__ w1bf, const float* __restrict__ b1,
                bf16* __restrict__ hmid)
{
    int gid = blockIdx.x;              // 1152; XCD ~= gid % 8
    int b = gid & 7;                   // one batch per XCD
    int p0 = (gid >> 3) * 64;          // sequential strips within XCD
    int t = threadIdx.x, lane = t & 63, wm = t >> 6;
    int l15 = lane & 15, lk = lane >> 4;
    const bf16* hb8 = hcat8 + (size_t)b * 8 * CHK;
    const bf16* hb1 = hcat1 + (size_t)b * HPW * 8;
    int pos[4];
    #pragma unroll
    for (int nt = 0; nt < 4; nt++) {
        int p = p0 + nt * 16 + l15;
        pos[nt] = (p / 96) * HP_ + (p % 96);
    }
    int aocb = (wm * 64 + l15) * 32 + lk * 8;
    f32x4 acc[4][4] = {};
    short8 abuf[4][4], bbuf[4][4];
    const short8 Z8 = {0, 0, 0, 0, 0, 0, 0, 0};

    auto LOAD = [&](int s, int ph) {
        int icc = s / 9, tap = s % 9;
        int toff = (tap / 3) * HP_ + (tap % 3);
        const bf16* wp = w1bf + (size_t)s * 4096;
        #pragma unroll
        for (int mt = 0; mt < 4; mt++)
            abuf[ph][mt] = *reinterpret_cast<const short8*>(wp + aocb + mt * 512);
        if (icc < 8) {
            const bf16* cp = hb8 + (size_t)icc * CHK;
            #pragma unroll
            for (int nt = 0; nt < 4; nt++)
                bbuf[ph][nt] = *reinterpret_cast<const short8*>(
                    cp + (size_t)(pos[nt] + toff) * 32 + lk * 8);
        } else {
            #pragma unroll
            for (int nt = 0; nt < 4; nt++) {
                short8 v = *reinterpret_cast<const short8*>(
                    hb1 + (size_t)(pos[nt] + toff) * 8);
                bbuf[ph][nt] = (lk == 0) ? v : Z8;
            }
        }
    };

    LOAD(0, 0);
    LOAD(1, 1);
    LOAD(2, 2);
    #pragma unroll
    for (int s = 0; s < 81; ++s) {
        int ph = s & 3;
        if (s + 3 < 81) LOAD(s + 3, (s + 3) & 3);
        #pragma unroll
        for (int mt = 0; mt < 4; mt++)
            #pragma unroll
            for (int nt = 0; nt < 4; nt++)
                acc[mt][nt] = __builtin_amdgcn_mfma_f32_16x16x32_bf16(
                    abuf[ph][mt], bbuf[ph][nt], acc[mt][nt], 0, 0, 0);
    }

    bf16* hm = hmid + (size_t)b * C1O * HW_;
    #pragma unroll
    for (int mt = 0; mt < 4; mt++) {
        int ocb = wm * 64 + mt * 16 + lk * 4;
        float4 bias = *reinterpret_cast<const float4*>(b1 + ocb);
        const float* bp = reinterpret_cast<const float*>(&bias);
        #pragma unroll
        for (int nt = 0; nt < 4; nt++) {
            int p = p0 + nt * 16 + l15;
            #pragma unroll
            for (int r = 0; r < 4; r++) {
                float v = fmaxf(acc[mt][nt][r] + bp[r], 0.f);
                hm[(size_t)(ocb + r) * HW_ + p] = __float2bfloat16(v);
            }
        }
    }
}

// ---------------------------------------------------------------- conv2 ----
__global__ __launch_bounds__(256)
void conv2_kernel(const bf16* __restrict__ hmid,
                  const float* __restrict__ W2,
                  const float* __restrict__ b2,
                  float* __restrict__ out)
{
    __shared__ float in_s[16][18 * 19];
    __shared__ float w2_s[2][128 * 9];
    int b = blockIdx.y;
    int tile = blockIdx.x;
    int y0 = (tile / 6) * 16, x0 = (tile % 6) * 16;
    int t = threadIdx.x;
    int r = t >> 4, c = t & 15;
    for (int f = t; f < 2 * 128 * 9; f += 256) w2_s[f / 1152][f % 1152] = W2[f];
    float acc0 = 0.f, acc1 = 0.f;
    const bf16* hb = hmid + (size_t)b * C1O * HW_;
    for (int ic0 = 0; ic0 < 128; ic0 += 16) {
        __syncthreads();
        for (int f = t; f < 16 * 18 * 18; f += 256) {
            int ic = f / 324; int rem = f % 324; int row = rem / 18, col = rem % 18;
            int gy = y0 - 1 + row, gxx = x0 - 1 + col;
            float v = 0.f;
            if (gy >= 0 && gy < H_ && gxx >= 0 && gxx < W_)
                v = __bfloat162float(hb[(size_t)(ic0 + ic) * HW_ + gy * W_ + gxx]);
            in_s[ic][row * 19 + col] = v;
        }
        __syncthreads();
        for (int ic = 0; ic < 16; ic++) {
            #pragma unroll
            for (int ky = 0; ky < 3; ky++) {
                #pragma unroll
                for (int kx = 0; kx < 3; kx++) {
                    float x = in_s[ic][(r + ky) * 19 + c + kx];
                    int wk = (ic0 + ic) * 9 + ky * 3 + kx;
                    acc0 += x * w2_s[0][wk];
                    acc1 += x * w2_s[1][wk];
                }
            }
        }
    }
    int py = (y0 + r) * W_ + x0 + c;
    out[((size_t)b * 2 + 0) * HW_ + py] = acc0 + b2[0];
    out[((size_t)b * 2 + 1) * HW_ + py] = acc1 + b2[1];
}

// ---------------------------------------------------------------- launch ----
extern "C" void kernel_launch(void* const* d_in, const int* in_sizes, int n_in,
                              void* d_out, int out_size, void* d_ws, size_t ws_size,
                              hipStream_t stream)
{
    const float* cur_embed  = (const float*)d_in[0];
    const float* cur_decode = (const float*)d_in[1];
    const float* init_embed = (const float*)d_in[2];
    const float* init_seg   = (const float*)d_in[3];
    const float* prev_embed = (const float*)d_in[4];
    const float* prev_seg   = (const float*)d_in[5];
    const float* W1 = (const float*)d_in[6];
    const float* b1 = (const float*)d_in[7];
    const float* W2 = (const float*)d_in[8];
    const float* b2 = (const float*)d_in[9];
    float* out = (float*)d_out;

    char* ws = (char*)d_ws;
    bf16* hcat8 = (bf16*)ws;                          // [8][8][9604][32]
    bf16* curbf = (bf16*)ws;                          // alias (dead at memset)
    bf16* hcat1 = (bf16*)(ws + 39337984);             // [8][9604][8]
    const size_t HCAT_REGION = 40567296;
    bf16* hmid   = (bf16*)(ws + HCAT_REGION);
    bf16* fibf   = (bf16*)(ws + HCAT_REGION);         // phase-1 alias
    bf16* prevbf = (bf16*)(ws + HCAT_REGION);         // phase-2 alias (4 batches)
    float* si  = (float*)(ws + HCAT_REGION + 2621440);
    bf16* w1bf = (bf16*)(ws + 59441664);
    float* gout = (float*)(ws + 60105216);
    float* lout = (float*)(ws + 60695040);

    { int total = 81 * 128 * 32;
      w1cvt_kernel<<<(total + 255) / 256, 256, 0, stream>>>(W1, w1bf); }
    { dim3 g(144, 4, B_);
      tcur_kernel<<<g, 256, 0, stream>>>(cur_embed, curbf); }
    { int total = B_ * (C_ + 2) * KPP;
      pool_kernel<<<(total + 255) / 256, 256, 0, stream>>>(init_embed, init_seg, fibf, si); }
    { dim3 g(144, B_);
      gmap_mfma<<<g, 128, 0, stream>>>(curbf, fibf, si, gout); }
    for (int g = 0; g < 2; g++) {
        dim3 gt(144, 4, 4);
        tcur_kernel<<<gt, 256, 0, stream>>>(prev_embed + (size_t)g * 4 * C_ * HW_, prevbf);
        dim3 gl(144, 4);
        lmap_mfma<<<gl, 256, 0, stream>>>(curbf, prevbf, prev_seg, lout, g * 4);
    }
    hipMemsetAsync(ws, 0, HCAT_REGION, stream);       // zero hcat8+hcat1; curbf dead
    { dim3 g(144, 4, B_);
      pack_dec_kernel<<<g, 256, 0, stream>>>(cur_decode, hcat8); }
    { int total = B_ * HW_;
      pack_small_kernel<<<(total + 255) / 256, 256, 0, stream>>>(gout, lout, init_seg, prev_seg, hcat1); }
    { conv1_mfma<<<1152, 128, 0, stream>>>(hcat8, hcat1, w1bf, b1, hmid); }
    { dim3 g(36, B_);
      conv2_kernel<<<g, 256, 0, stream>>>(hmid, W2, b2, out); }
}

// Round 8
// 513.508 us; speedup vs baseline: 1.4490x; 1.4490x over previous
//
#include <hip/hip_runtime.h>
#include <hip/hip_bf16.h>

// Round 8: REVERT gmap/lmap to r6 (r7 explicit pipelines spilled to scratch:
//          685 MB WRITE_SIZE). KEEP conv1 icc-outer layout + XCD swizzle (r7).
// ws layout (61.28 MB, aliased):
//   [0, 39,337,984)           hcat8 bf16 [8][8][9604][32]   -- ALSO curbf bf16 [8][9216][256] (dead at memset)
//   [39,337,984, 40,567,296)  hcat1 bf16 [8][9604][8] (tail ch 256..263)
//   [40,567,296, 59,441,664)  hmid bf16 [8][128][9216]
//       -- phase1 alias: fibf bf16 [8][640][256] @ +0, si f32 [8][2][640] @ +2,621,440
//       -- phase2 alias: prevbf bf16 [4][9216][256] (exactly 18,874,368 B)
//   [59,441,664, 60,105,216)  W1bf bf16 [81][128][32]  (slab s = icc*9+tap)
//   [60,105,216, 60,695,040)  gout f32 [8][2][9216]
//   [60,695,040, 61,284,864)  lout f32 [8][2][9216]

typedef __hip_bfloat16 bf16;
typedef __attribute__((ext_vector_type(8))) short short8;
typedef __attribute__((ext_vector_type(4))) float f32x4;

constexpr int B_  = 8;
constexpr int C_  = 256;
constexpr int H_  = 96;
constexpr int W_  = 96;
constexpr int HW_ = H_ * W_;       // 9216
constexpr int PW_ = 24;
constexpr int KP_ = 576;
constexpr int KPP = 640;
constexpr int HP_ = 98;
constexpr int HPW = HP_ * HP_;     // 9604
constexpr int C1O = 128;
constexpr int CHK = HPW * 32;      // per 32-ch chunk

__device__ __forceinline__ unsigned short bfb(float f) {
    bf16 h = __float2bfloat16(f);
    return *reinterpret_cast<unsigned short*>(&h);
}

// ------------------------------------------------------------ W1 convert ----
// slab s = icc*9 + tap : [128 oc][32 ic]
__global__ __launch_bounds__(256)
void w1cvt_kernel(const float* __restrict__ W1, bf16* __restrict__ w1bf)
{
    int idx = blockIdx.x * 256 + threadIdx.x;
    if (idx >= 81 * 128 * 32) return;
    int ic = idx & 31;
    int oc = (idx >> 5) & 127;
    int ks = idx >> 12;
    int icc = ks / 9, tap = ks % 9;
    int icg = icc * 32 + ic;
    float v = (icg < 264) ? W1[((size_t)oc * 264 + icg) * 9 + tap] : 0.f;
    w1bf[idx] = __float2bfloat16(v);
}

// ------------------------------------------------------- NCHW->NHWC bf16 ----
__global__ __launch_bounds__(256)
void tcur_kernel(const float* __restrict__ cur, bf16* __restrict__ curbf)
{
    __shared__ float tile[64][68];
    int b = blockIdx.z, c0 = blockIdx.y * 64, p0 = blockIdx.x * 64;
    int t = threadIdx.x;
    const float* src = cur + ((size_t)b * C_ + c0) * HW_ + p0;
    #pragma unroll
    for (int it = 0; it < 4; it++) {
        int f = t + it * 256;
        int cl = f >> 4, p4 = (f & 15) * 4;
        float4 v = *reinterpret_cast<const float4*>(src + (size_t)cl * HW_ + p4);
        *reinterpret_cast<float4*>(&tile[cl][p4]) = v;
    }
    __syncthreads();
    bf16* dst = curbf + ((size_t)b * HW_ + p0) * 256 + c0;
    #pragma unroll
    for (int it = 0; it < 4; it++) {
        int f = t + it * 256;
        int pl = f >> 4, c4 = (f & 15) * 4;
        ushort4 u;
        u.x = bfb(tile[c4 + 0][pl]); u.y = bfb(tile[c4 + 1][pl]);
        u.z = bfb(tile[c4 + 2][pl]); u.w = bfb(tile[c4 + 3][pl]);
        *reinterpret_cast<ushort4*>(dst + (size_t)pl * 256 + c4) = u;
    }
}

// ---------------------------------------------------------------- pool ----
__global__ __launch_bounds__(256)
void pool_kernel(const float* __restrict__ init_embed,
                 const float* __restrict__ init_seg,
                 bf16* __restrict__ fibf, float* __restrict__ si)
{
    int idx = blockIdx.x * 256 + threadIdx.x;
    int total = B_ * (C_ + 2) * KPP;
    if (idx >= total) return;
    int k  = idx % KPP;
    int ch = (idx / KPP) % (C_ + 2);
    int b  = idx / (KPP * (C_ + 2));
    float s = 0.f;
    if (k < KP_) {
        int ph = k / PW_, pw = k % PW_;
        const float* src = (ch < C_)
            ? (init_embed + (((size_t)b * C_ + ch) * H_ + ph * 4) * W_ + pw * 4)
            : (init_seg   + (((size_t)b * 2 + (ch - C_)) * H_ + ph * 4) * W_ + pw * 4);
        #pragma unroll
        for (int r = 0; r < 4; r++) {
            float4 v = *reinterpret_cast<const float4*>(src + r * W_);
            s += v.x + v.y + v.z + v.w;
        }
        s *= (1.f / 16.f);
    }
    if (ch < C_) fibf[((size_t)b * KPP + k) * C_ + ch] = __float2bfloat16(s);
    else         si[(size_t)b * 2 * KPP + (ch - C_) * KPP + k] = s;
}

// ---------------------------------------------------------------- gmap ----
// (r6 version: compiler-scheduled loads, per-chunk epilogue after kc loop)
__global__ __launch_bounds__(128)
void gmap_mfma(const bf16* __restrict__ curbf, const bf16* __restrict__ fibf,
               const float* __restrict__ si, float* __restrict__ gout)
{
    __shared__ float bred[2][2][64];
    int b = blockIdx.y;
    int p0 = blockIdx.x * 64;
    int t = threadIdx.x, lane = t & 63, wm = t >> 6;
    int l15 = lane & 15, lk = lane >> 4;
    const bf16* cb = curbf + (size_t)b * HW_ * 256;
    const bf16* fb = fibf + (size_t)b * KPP * 256;
    const float* sib = si + (size_t)b * 2 * KPP;
    size_t bo[4];
    #pragma unroll
    for (int nt = 0; nt < 4; nt++)
        bo[nt] = (size_t)(p0 + nt * 16 + l15) * 256 + lk * 8;
    float best[2][4];
    #pragma unroll
    for (int s = 0; s < 2; s++)
        #pragma unroll
        for (int nt = 0; nt < 4; nt++) best[s][nt] = -INFINITY;

    for (int ch = 0; ch < 5; ch++) {
        int kp0 = ch * 128;
        f32x4 acc[4][4] = {};
        for (int kc = 0; kc < 8; kc++) {
            short8 a[4], bbf[4];
            #pragma unroll
            for (int mt = 0; mt < 4; mt++)
                a[mt] = *reinterpret_cast<const short8*>(
                    fb + (size_t)(kp0 + wm * 64 + mt * 16 + l15) * 256 + kc * 32 + lk * 8);
            #pragma unroll
            for (int nt = 0; nt < 4; nt++)
                bbf[nt] = *reinterpret_cast<const short8*>(cb + bo[nt] + kc * 32);
            #pragma unroll
            for (int mt = 0; mt < 4; mt++)
                #pragma unroll
                for (int nt = 0; nt < 4; nt++)
                    acc[mt][nt] = __builtin_amdgcn_mfma_f32_16x16x32_bf16(
                        a[mt], bbf[nt], acc[mt][nt], 0, 0, 0);
        }
        #pragma unroll
        for (int mt = 0; mt < 4; mt++) {
            int rb = kp0 + wm * 64 + mt * 16 + lk * 4;
            float4 s0 = *reinterpret_cast<const float4*>(sib + rb);
            float4 s1 = *reinterpret_cast<const float4*>(sib + KPP + rb);
            const float* s0p = reinterpret_cast<const float*>(&s0);
            const float* s1p = reinterpret_cast<const float*>(&s1);
            #pragma unroll
            for (int nt = 0; nt < 4; nt++)
                #pragma unroll
                for (int r = 0; r < 4; r++) {
                    float v = acc[mt][nt][r];
                    best[0][nt] = fmaxf(best[0][nt], v * s0p[r]);
                    best[1][nt] = fmaxf(best[1][nt], v * s1p[r]);
                }
        }
    }
    #pragma unroll
    for (int s = 0; s < 2; s++)
        #pragma unroll
        for (int nt = 0; nt < 4; nt++) {
            float v = best[s][nt];
            v = fmaxf(v, __shfl_xor(v, 16));
            v = fmaxf(v, __shfl_xor(v, 32));
            if (lk == 0) bred[wm][s][nt * 16 + l15] = v;
        }
    __syncthreads();
    if (t < 128) {
        int s = t >> 6, pxl = t & 63;
        gout[((size_t)b * 2 + s) * HW_ + p0 + pxl] = fmaxf(bred[0][s][pxl], bred[1][s][pxl]);
    }
}

// ---------------------------------------------------------------- lmap ----
// (r6 version)
__global__ __launch_bounds__(256)
void lmap_mfma(const bf16* __restrict__ curbf, const bf16* __restrict__ prevbf,
               const float* __restrict__ prev_seg, float* __restrict__ lout, int b0)
{
    constexpr int GSTR = 257;
    constexpr int SEGB = 64 * GSTR;
    constexpr int REDB = SEGB + 512;
    __shared__ float gl[REDB + 256];
    int b = b0 + blockIdx.y;
    const bf16* pb = prevbf + (size_t)blockIdx.y * HW_ * 256;
    const bf16* cb = curbf + (size_t)b * HW_ * 256;
    int tile = blockIdx.x;
    int ty0 = (tile / 12) * 8, tx0 = (tile % 12) * 8;
    int t = threadIdx.x, lane = t & 63, wq = t >> 6;
    int l15 = lane & 15, lk = lane >> 4;

    size_t aoff[4];
    #pragma unroll
    for (int mt = 0; mt < 4; mt++) {
        int m = mt * 16 + l15;
        int gpx = (ty0 + (m >> 3)) * W_ + tx0 + (m & 7);
        aoff[mt] = (size_t)gpx * 256 + lk * 8;
    }
    bool pred[4];
    size_t boff[4];
    int gx = tx0 - 4 + l15;
    bool colok = (gx >= 0) && (gx < W_);
    #pragma unroll
    for (int nt = 0; nt < 4; nt++) {
        int gy = ty0 - 4 + wq * 4 + nt;
        pred[nt] = colok && (gy >= 0) && (gy < H_);
        boff[nt] = pred[nt] ? ((size_t)(gy * W_ + gx) * 256 + lk * 8) : 0;
    }

    f32x4 acc[4][4] = {};
    const short8 Z8 = {0, 0, 0, 0, 0, 0, 0, 0};
    for (int kc = 0; kc < 8; kc++) {
        short8 a[4], bb[4];
        #pragma unroll
        for (int mt = 0; mt < 4; mt++)
            a[mt] = *reinterpret_cast<const short8*>(cb + aoff[mt] + kc * 32);
        #pragma unroll
        for (int nt = 0; nt < 4; nt++) {
            short8 v = Z8;
            if (pred[nt]) v = *reinterpret_cast<const short8*>(pb + boff[nt] + kc * 32);
            bb[nt] = v;
        }
        #pragma unroll
        for (int mt = 0; mt < 4; mt++)
            #pragma unroll
            for (int nt = 0; nt < 4; nt++)
                acc[mt][nt] = __builtin_amdgcn_mfma_f32_16x16x32_bf16(
                    a[mt], bb[nt], acc[mt][nt], 0, 0, 0);
    }
    #pragma unroll
    for (int mt = 0; mt < 4; mt++)
        #pragma unroll
        for (int nt = 0; nt < 4; nt++)
            #pragma unroll
            for (int r = 0; r < 4; r++)
                gl[(mt * 16 + lk * 4 + r) * GSTR + wq * 64 + nt * 16 + l15] = acc[mt][nt][r];
    #pragma unroll
    for (int it = 0; it < 2; it++) {
        int f = t + it * 256;
        int s = f >> 8, wp = f & 255;
        int wy = wp >> 4, wx = wp & 15;
        int gy = ty0 - 4 + wy, gxx = tx0 - 4 + wx;
        float v = 0.f;
        if (gy >= 0 && gy < H_ && gxx >= 0 && gxx < W_)
            v = prev_seg[((size_t)b * 2 + s) * HW_ + gy * W_ + gxx] * (1.f / 256.f);
        gl[SEGB + f] = v;
    }
    __syncthreads();
    {
        int m = t & 63;
        int sh = t >> 6;
        int s = sh >> 1, hh = sh & 1;
        int py = m >> 3, lx = m & 7;
        const float* gr = gl + m * GSTR;
        const float* sr = gl + SEGB + s * 256;
        float mx = -INFINITY;
        int wr0 = hh * 5, wr1 = hh ? 9 : 5;
        for (int wr = wr0; wr < wr1; ++wr) {
            int base = (py + wr) * 16 + lx;
            #pragma unroll
            for (int wc = 0; wc < 9; ++wc)
                mx = fmaxf(mx, gr[base + wc] * sr[base + wc]);
        }
        gl[REDB + sh * 64 + m] = mx;
    }
    __syncthreads();
    if (t < 128) {
        int s = t >> 6, m = t & 63;
        float v = fmaxf(gl[REDB + (s * 2 + 0) * 64 + m], gl[REDB + (s * 2 + 1) * 64 + m]);
        int gpx = (ty0 + (m >> 3)) * W_ + tx0 + (m & 7);
        lout[((size_t)b * 2 + s) * HW_ + gpx] = v;
    }
}

// ---------------------------------------------------------------- packs ----
__global__ __launch_bounds__(256)
void pack_dec_kernel(const float* __restrict__ dec, bf16* __restrict__ hcat8)
{
    __shared__ float tile[64][68];
    int b = blockIdx.z, c0 = blockIdx.y * 64, p0 = blockIdx.x * 64;
    int t = threadIdx.x;
    const float* src = dec + ((size_t)b * C_ + c0) * HW_ + p0;
    #pragma unroll
    for (int it = 0; it < 4; it++) {
        int f = t + it * 256;
        int cl = f >> 4, p4 = (f & 15) * 4;
        float4 v = *reinterpret_cast<const float4*>(src + (size_t)cl * HW_ + p4);
        *reinterpret_cast<float4*>(&tile[cl][p4]) = v;
    }
    __syncthreads();
    #pragma unroll
    for (int it = 0; it < 4; it++) {
        int f = t + it * 256;
        int pl = f >> 4, c4 = (f & 15) * 4;
        int p = p0 + pl;
        int y = p / 96, x = p % 96;
        int pos = (y + 1) * HP_ + x + 1;
        int ch = c0 + c4;
        ushort4 u;
        u.x = bfb(tile[c4 + 0][pl]); u.y = bfb(tile[c4 + 1][pl]);
        u.z = bfb(tile[c4 + 2][pl]); u.w = bfb(tile[c4 + 3][pl]);
        bf16* dst = hcat8 + ((size_t)b * 8 + (ch >> 5)) * CHK + (size_t)pos * 32 + (ch & 31);
        *reinterpret_cast<ushort4*>(dst) = u;
    }
}

__global__ __launch_bounds__(256)
void pack_small_kernel(const float* __restrict__ gout,
                       const float* __restrict__ lout,
                       const float* __restrict__ init_seg,
                       const float* __restrict__ prev_seg,
                       bf16* __restrict__ hcat1)
{
    int idx = blockIdx.x * 256 + threadIdx.x;
    if (idx >= B_ * HW_) return;
    int b = idx / HW_, p = idx % HW_;
    int y = p / 96, x = p % 96;
    int pos = (y + 1) * HP_ + x + 1;
    bf16* dst = hcat1 + ((size_t)b * HPW + pos) * 8;
    float g0 = gout[((size_t)b * 2 + 0) * HW_ + p];
    float g1 = gout[((size_t)b * 2 + 1) * HW_ + p];
    float i0 = init_seg[((size_t)b * 2 + 0) * HW_ + p];
    float i1 = init_seg[((size_t)b * 2 + 1) * HW_ + p];
    float l0 = lout[((size_t)b * 2 + 0) * HW_ + p];
    float l1 = lout[((size_t)b * 2 + 1) * HW_ + p];
    float q0 = prev_seg[((size_t)b * 2 + 0) * HW_ + p];
    float q1 = prev_seg[((size_t)b * 2 + 1) * HW_ + p];
    ushort4 u; u.x = bfb(g0); u.y = bfb(g1); u.z = bfb(i0); u.w = bfb(i1);
    *reinterpret_cast<ushort4*>(dst) = u;
    ushort4 u2; u2.x = bfb(l0); u2.y = bfb(l1); u2.z = bfb(q0); u2.w = bfb(q1);
    *reinterpret_cast<ushort4*>(dst + 4) = u2;
}

// ---------------------------------------------------------------- conv1 ----
// (r7 version: icc-outer / tap-inner + XCD swizzle + depth-3 pipeline)
__global__ __launch_bounds__(128)
void conv1_mfma(const bf16* __restrict__ hcat8, const bf16* __restrict__ hcat1,
                const bf16* __restrict__ w1bf, const float* __restrict__ b1,
                bf16* __restrict__ hmid)
{
    int gid = blockIdx.x;              // 1152; XCD ~= gid % 8
    int b = gid & 7;                   // one batch per XCD
    int p0 = (gid >> 3) * 64;          // sequential strips within XCD
    int t = threadIdx.x, lane = t & 63, wm = t >> 6;
    int l15 = lane & 15, lk = lane >> 4;
    const bf16* hb8 = hcat8 + (size_t)b * 8 * CHK;
    const bf16* hb1 = hcat1 + (size_t)b * HPW * 8;
    int pos[4];
    #pragma unroll
    for (int nt = 0; nt < 4; nt++) {
        int p = p0 + nt * 16 + l15;
        pos[nt] = (p / 96) * HP_ + (p % 96);
    }
    int aocb = (wm * 64 + l15) * 32 + lk * 8;
    f32x4 acc[4][4] = {};
    short8 abuf[4][4], bbuf[4][4];
    const short8 Z8 = {0, 0, 0, 0, 0, 0, 0, 0};

    auto LOAD = [&](int s, int ph) {
        int icc = s / 9, tap = s % 9;
        int toff = (tap / 3) * HP_ + (tap % 3);
        const bf16* wp = w1bf + (size_t)s * 4096;
        #pragma unroll
        for (int mt = 0; mt < 4; mt++)
            abuf[ph][mt] = *reinterpret_cast<const short8*>(wp + aocb + mt * 512);
        if (icc < 8) {
            const bf16* cp = hb8 + (size_t)icc * CHK;
            #pragma unroll
            for (int nt = 0; nt < 4; nt++)
                bbuf[ph][nt] = *reinterpret_cast<const short8*>(
                    cp + (size_t)(pos[nt] + toff) * 32 + lk * 8);
        } else {
            #pragma unroll
            for (int nt = 0; nt < 4; nt++) {
                short8 v = *reinterpret_cast<const short8*>(
                    hb1 + (size_t)(pos[nt] + toff) * 8);
                bbuf[ph][nt] = (lk == 0) ? v : Z8;
            }
        }
    };

    LOAD(0, 0);
    LOAD(1, 1);
    LOAD(2, 2);
    #pragma unroll
    for (int s = 0; s < 81; ++s) {
        int ph = s & 3;
        if (s + 3 < 81) LOAD(s + 3, (s + 3) & 3);
        #pragma unroll
        for (int mt = 0; mt < 4; mt++)
            #pragma unroll
            for (int nt = 0; nt < 4; nt++)
                acc[mt][nt] = __builtin_amdgcn_mfma_f32_16x16x32_bf16(
                    abuf[ph][mt], bbuf[ph][nt], acc[mt][nt], 0, 0, 0);
    }

    bf16* hm = hmid + (size_t)b * C1O * HW_;
    #pragma unroll
    for (int mt = 0; mt < 4; mt++) {
        int ocb = wm * 64 + mt * 16 + lk * 4;
        float4 bias = *reinterpret_cast<const float4*>(b1 + ocb);
        const float* bp = reinterpret_cast<const float*>(&bias);
        #pragma unroll
        for (int nt = 0; nt < 4; nt++) {
            int p = p0 + nt * 16 + l15;
            #pragma unroll
            for (int r = 0; r < 4; r++) {
                float v = fmaxf(acc[mt][nt][r] + bp[r], 0.f);
                hm[(size_t)(ocb + r) * HW_ + p] = __float2bfloat16(v);
            }
        }
    }
}

// ---------------------------------------------------------------- conv2 ----
__global__ __launch_bounds__(256)
void conv2_kernel(const bf16* __restrict__ hmid,
                  const float* __restrict__ W2,
                  const float* __restrict__ b2,
                  float* __restrict__ out)
{
    __shared__ float in_s[16][18 * 19];
    __shared__ float w2_s[2][128 * 9];
    int b = blockIdx.y;
    int tile = blockIdx.x;
    int y0 = (tile / 6) * 16, x0 = (tile % 6) * 16;
    int t = threadIdx.x;
    int r = t >> 4, c = t & 15;
    for (int f = t; f < 2 * 128 * 9; f += 256) w2_s[f / 1152][f % 1152] = W2[f];
    float acc0 = 0.f, acc1 = 0.f;
    const bf16* hb = hmid + (size_t)b * C1O * HW_;
    for (int ic0 = 0; ic0 < 128; ic0 += 16) {
        __syncthreads();
        for (int f = t; f < 16 * 18 * 18; f += 256) {
            int ic = f / 324; int rem = f % 324; int row = rem / 18, col = rem % 18;
            int gy = y0 - 1 + row, gxx = x0 - 1 + col;
            float v = 0.f;
            if (gy >= 0 && gy < H_ && gxx >= 0 && gxx < W_)
                v = __bfloat162float(hb[(size_t)(ic0 + ic) * HW_ + gy * W_ + gxx]);
            in_s[ic][row * 19 + col] = v;
        }
        __syncthreads();
        for (int ic = 0; ic < 16; ic++) {
            #pragma unroll
            for (int ky = 0; ky < 3; ky++) {
                #pragma unroll
                for (int kx = 0; kx < 3; kx++) {
                    float x = in_s[ic][(r + ky) * 19 + c + kx];
                    int wk = (ic0 + ic) * 9 + ky * 3 + kx;
                    acc0 += x * w2_s[0][wk];
                    acc1 += x * w2_s[1][wk];
                }
            }
        }
    }
    int py = (y0 + r) * W_ + x0 + c;
    out[((size_t)b * 2 + 0) * HW_ + py] = acc0 + b2[0];
    out[((size_t)b * 2 + 1) * HW_ + py] = acc1 + b2[1];
}

// ---------------------------------------------------------------- launch ----
extern "C" void kernel_launch(void* const* d_in, const int* in_sizes, int n_in,
                              void* d_out, int out_size, void* d_ws, size_t ws_size,
                              hipStream_t stream)
{
    const float* cur_embed  = (const float*)d_in[0];
    const float* cur_decode = (const float*)d_in[1];
    const float* init_embed = (const float*)d_in[2];
    const float* init_seg   = (const float*)d_in[3];
    const float* prev_embed = (const float*)d_in[4];
    const float* prev_seg   = (const float*)d_in[5];
    const float* W1 = (const float*)d_in[6];
    const float* b1 = (const float*)d_in[7];
    const float* W2 = (const float*)d_in[8];
    const float* b2 = (const float*)d_in[9];
    float* out = (float*)d_out;

    char* ws = (char*)d_ws;
    bf16* hcat8 = (bf16*)ws;                          // [8][8][9604][32]
    bf16* curbf = (bf16*)ws;                          // alias (dead at memset)
    bf16* hcat1 = (bf16*)(ws + 39337984);             // [8][9604][8]
    const size_t HCAT_REGION = 40567296;
    bf16* hmid   = (bf16*)(ws + HCAT_REGION);
    bf16* fibf   = (bf16*)(ws + HCAT_REGION);         // phase-1 alias
    bf16* prevbf = (bf16*)(ws + HCAT_REGION);         // phase-2 alias (4 batches)
    float* si  = (float*)(ws + HCAT_REGION + 2621440);
    bf16* w1bf = (bf16*)(ws + 59441664);
    float* gout = (float*)(ws + 60105216);
    float* lout = (float*)(ws + 60695040);

    { int total = 81 * 128 * 32;
      w1cvt_kernel<<<(total + 255) / 256, 256, 0, stream>>>(W1, w1bf); }
    { dim3 g(144, 4, B_);
      tcur_kernel<<<g, 256, 0, stream>>>(cur_embed, curbf); }
    { int total = B_ * (C_ + 2) * KPP;
      pool_kernel<<<(total + 255) / 256, 256, 0, stream>>>(init_embed, init_seg, fibf, si); }
    { dim3 g(144, B_);
      gmap_mfma<<<g, 128, 0, stream>>>(curbf, fibf, si, gout); }
    for (int g = 0; g < 2; g++) {
        dim3 gt(144, 4, 4);
        tcur_kernel<<<gt, 256, 0, stream>>>(prev_embed + (size_t)g * 4 * C_ * HW_, prevbf);
        dim3 gl(144, 4);
        lmap_mfma<<<gl, 256, 0, stream>>>(curbf, prevbf, prev_seg, lout, g * 4);
    }
    hipMemsetAsync(ws, 0, HCAT_REGION, stream);       // zero hcat8+hcat1; curbf dead
    { dim3 g(144, 4, B_);
      pack_dec_kernel<<<g, 256, 0, stream>>>(cur_decode, hcat8); }
    { int total = B_ * HW_;
      pack_small_kernel<<<(total + 255) / 256, 256, 0, stream>>>(gout, lout, init_seg, prev_seg, hcat1); }
    { conv1_mfma<<<1152, 128, 0, stream>>>(hcat8, hcat1, w1bf, b1, hmid); }
    { dim3 g(36, B_);
      conv2_kernel<<<g, 256, 0, stream>>>(hmid, W2, b2, out); }
}

// Round 9
// 437.339 us; speedup vs baseline: 1.7014x; 1.1742x over previous
//
#include <hip/hip_runtime.h>
#include <hip/hip_bf16.h>

// Round 9: conv1 -> m97-class LDS GEMM: 128oc x 256px tile, 8 waves, BK=64 pairs,
//          global_load_lds(16B) staging, chunk-XOR swizzle (pre-swizzled source +
//          swizzled ds_read), double buffer, 1 batch/XCD. gmap/lmap = r8 (passing).
// ws layout (61.29 MB, aliased):
//   [0, 39,337,984)           hcat8 bf16 [8][8][9604][32]   -- ALSO curbf bf16 [8][9216][256] (dead at memset)
//   [39,337,984, 40,567,296)  hcat1 bf16 [8][9604][8] (tail ch 256..263)
//   [40,567,296, 59,441,664)  hmid bf16 [8][128][9216]
//       -- phase1 alias: fibf bf16 [8][640][256] @ +0, si f32 [8][2][640] @ +2,621,440
//       -- phase2 alias: prevbf bf16 [4][9216][256] (exactly 18,874,368 B)
//   [59,441,664, 60,113,408)  W1bf bf16 [82][128][32]  (slab s = icc*9+tap; slab 81 = zeros)
//   [60,113,408, 60,703,232)  gout f32 [8][2][9216]
//   [60,703,232, 61,293,056)  lout f32 [8][2][9216]

typedef __hip_bfloat16 bf16;
typedef __attribute__((ext_vector_type(8))) short short8;
typedef __attribute__((ext_vector_type(4))) float f32x4;

constexpr int B_  = 8;
constexpr int C_  = 256;
constexpr int H_  = 96;
constexpr int W_  = 96;
constexpr int HW_ = H_ * W_;       // 9216
constexpr int PW_ = 24;
constexpr int KP_ = 576;
constexpr int KPP = 640;
constexpr int HP_ = 98;
constexpr int HPW = HP_ * HP_;     // 9604
constexpr int C1O = 128;
constexpr int CHK = HPW * 32;      // per 32-ch chunk

__device__ __forceinline__ unsigned short bfb(float f) {
    bf16 h = __float2bfloat16(f);
    return *reinterpret_cast<unsigned short*>(&h);
}

__device__ __forceinline__ void gload_lds16(const bf16* g, bf16* l) {
    __builtin_amdgcn_global_load_lds((const void*)g, (void*)l, 16, 0, 0);
}

// ------------------------------------------------------------ W1 convert ----
// slab s = icc*9 + tap : [128 oc][32 ic] ; 82 slabs, slab 81 all-zero (icc=9 -> icg>=264)
__global__ __launch_bounds__(256)
void w1cvt_kernel(const float* __restrict__ W1, bf16* __restrict__ w1bf)
{
    int idx = blockIdx.x * 256 + threadIdx.x;
    if (idx >= 82 * 128 * 32) return;
    int ic = idx & 31;
    int oc = (idx >> 5) & 127;
    int ks = idx >> 12;
    int icc = ks / 9, tap = ks % 9;
    int icg = icc * 32 + ic;
    float v = (icg < 264) ? W1[((size_t)oc * 264 + icg) * 9 + tap] : 0.f;
    w1bf[idx] = __float2bfloat16(v);
}

// ------------------------------------------------------- NCHW->NHWC bf16 ----
__global__ __launch_bounds__(256)
void tcur_kernel(const float* __restrict__ cur, bf16* __restrict__ curbf)
{
    __shared__ float tile[64][68];
    int b = blockIdx.z, c0 = blockIdx.y * 64, p0 = blockIdx.x * 64;
    int t = threadIdx.x;
    const float* src = cur + ((size_t)b * C_ + c0) * HW_ + p0;
    #pragma unroll
    for (int it = 0; it < 4; it++) {
        int f = t + it * 256;
        int cl = f >> 4, p4 = (f & 15) * 4;
        float4 v = *reinterpret_cast<const float4*>(src + (size_t)cl * HW_ + p4);
        *reinterpret_cast<float4*>(&tile[cl][p4]) = v;
    }
    __syncthreads();
    bf16* dst = curbf + ((size_t)b * HW_ + p0) * 256 + c0;
    #pragma unroll
    for (int it = 0; it < 4; it++) {
        int f = t + it * 256;
        int pl = f >> 4, c4 = (f & 15) * 4;
        ushort4 u;
        u.x = bfb(tile[c4 + 0][pl]); u.y = bfb(tile[c4 + 1][pl]);
        u.z = bfb(tile[c4 + 2][pl]); u.w = bfb(tile[c4 + 3][pl]);
        *reinterpret_cast<ushort4*>(dst + (size_t)pl * 256 + c4) = u;
    }
}

// ---------------------------------------------------------------- pool ----
__global__ __launch_bounds__(256)
void pool_kernel(const float* __restrict__ init_embed,
                 const float* __restrict__ init_seg,
                 bf16* __restrict__ fibf, float* __restrict__ si)
{
    int idx = blockIdx.x * 256 + threadIdx.x;
    int total = B_ * (C_ + 2) * KPP;
    if (idx >= total) return;
    int k  = idx % KPP;
    int ch = (idx / KPP) % (C_ + 2);
    int b  = idx / (KPP * (C_ + 2));
    float s = 0.f;
    if (k < KP_) {
        int ph = k / PW_, pw = k % PW_;
        const float* src = (ch < C_)
            ? (init_embed + (((size_t)b * C_ + ch) * H_ + ph * 4) * W_ + pw * 4)
            : (init_seg   + (((size_t)b * 2 + (ch - C_)) * H_ + ph * 4) * W_ + pw * 4);
        #pragma unroll
        for (int r = 0; r < 4; r++) {
            float4 v = *reinterpret_cast<const float4*>(src + r * W_);
            s += v.x + v.y + v.z + v.w;
        }
        s *= (1.f / 16.f);
    }
    if (ch < C_) fibf[((size_t)b * KPP + k) * C_ + ch] = __float2bfloat16(s);
    else         si[(size_t)b * 2 * KPP + (ch - C_) * KPP + k] = s;
}

// ---------------------------------------------------------------- gmap ----
__global__ __launch_bounds__(128)
void gmap_mfma(const bf16* __restrict__ curbf, const bf16* __restrict__ fibf,
               const float* __restrict__ si, float* __restrict__ gout)
{
    __shared__ float bred[2][2][64];
    int b = blockIdx.y;
    int p0 = blockIdx.x * 64;
    int t = threadIdx.x, lane = t & 63, wm = t >> 6;
    int l15 = lane & 15, lk = lane >> 4;
    const bf16* cb = curbf + (size_t)b * HW_ * 256;
    const bf16* fb = fibf + (size_t)b * KPP * 256;
    const float* sib = si + (size_t)b * 2 * KPP;
    size_t bo[4];
    #pragma unroll
    for (int nt = 0; nt < 4; nt++)
        bo[nt] = (size_t)(p0 + nt * 16 + l15) * 256 + lk * 8;
    float best[2][4];
    #pragma unroll
    for (int s = 0; s < 2; s++)
        #pragma unroll
        for (int nt = 0; nt < 4; nt++) best[s][nt] = -INFINITY;

    for (int ch = 0; ch < 5; ch++) {
        int kp0 = ch * 128;
        f32x4 acc[4][4] = {};
        for (int kc = 0; kc < 8; kc++) {
            short8 a[4], bbf[4];
            #pragma unroll
            for (int mt = 0; mt < 4; mt++)
                a[mt] = *reinterpret_cast<const short8*>(
                    fb + (size_t)(kp0 + wm * 64 + mt * 16 + l15) * 256 + kc * 32 + lk * 8);
            #pragma unroll
            for (int nt = 0; nt < 4; nt++)
                bbf[nt] = *reinterpret_cast<const short8*>(cb + bo[nt] + kc * 32);
            #pragma unroll
            for (int mt = 0; mt < 4; mt++)
                #pragma unroll
                for (int nt = 0; nt < 4; nt++)
                    acc[mt][nt] = __builtin_amdgcn_mfma_f32_16x16x32_bf16(
                        a[mt], bbf[nt], acc[mt][nt], 0, 0, 0);
        }
        #pragma unroll
        for (int mt = 0; mt < 4; mt++) {
            int rb = kp0 + wm * 64 + mt * 16 + lk * 4;
            float4 s0 = *reinterpret_cast<const float4*>(sib + rb);
            float4 s1 = *reinterpret_cast<const float4*>(sib + KPP + rb);
            const float* s0p = reinterpret_cast<const float*>(&s0);
            const float* s1p = reinterpret_cast<const float*>(&s1);
            #pragma unroll
            for (int nt = 0; nt < 4; nt++)
                #pragma unroll
                for (int r = 0; r < 4; r++) {
                    float v = acc[mt][nt][r];
                    best[0][nt] = fmaxf(best[0][nt], v * s0p[r]);
                    best[1][nt] = fmaxf(best[1][nt], v * s1p[r]);
                }
        }
    }
    #pragma unroll
    for (int s = 0; s < 2; s++)
        #pragma unroll
        for (int nt = 0; nt < 4; nt++) {
            float v = best[s][nt];
            v = fmaxf(v, __shfl_xor(v, 16));
            v = fmaxf(v, __shfl_xor(v, 32));
            if (lk == 0) bred[wm][s][nt * 16 + l15] = v;
        }
    __syncthreads();
    if (t < 128) {
        int s = t >> 6, pxl = t & 63;
        gout[((size_t)b * 2 + s) * HW_ + p0 + pxl] = fmaxf(bred[0][s][pxl], bred[1][s][pxl]);
    }
}

// ---------------------------------------------------------------- lmap ----
__global__ __launch_bounds__(256)
void lmap_mfma(const bf16* __restrict__ curbf, const bf16* __restrict__ prevbf,
               const float* __restrict__ prev_seg, float* __restrict__ lout, int b0)
{
    constexpr int GSTR = 257;
    constexpr int SEGB = 64 * GSTR;
    constexpr int REDB = SEGB + 512;
    __shared__ float gl[REDB + 256];
    int b = b0 + blockIdx.y;
    const bf16* pb = prevbf + (size_t)blockIdx.y * HW_ * 256;
    const bf16* cb = curbf + (size_t)b * HW_ * 256;
    int tile = blockIdx.x;
    int ty0 = (tile / 12) * 8, tx0 = (tile % 12) * 8;
    int t = threadIdx.x, lane = t & 63, wq = t >> 6;
    int l15 = lane & 15, lk = lane >> 4;

    size_t aoff[4];
    #pragma unroll
    for (int mt = 0; mt < 4; mt++) {
        int m = mt * 16 + l15;
        int gpx = (ty0 + (m >> 3)) * W_ + tx0 + (m & 7);
        aoff[mt] = (size_t)gpx * 256 + lk * 8;
    }
    bool pred[4];
    size_t boff[4];
    int gx = tx0 - 4 + l15;
    bool colok = (gx >= 0) && (gx < W_);
    #pragma unroll
    for (int nt = 0; nt < 4; nt++) {
        int gy = ty0 - 4 + wq * 4 + nt;
        pred[nt] = colok && (gy >= 0) && (gy < H_);
        boff[nt] = pred[nt] ? ((size_t)(gy * W_ + gx) * 256 + lk * 8) : 0;
    }

    f32x4 acc[4][4] = {};
    const short8 Z8 = {0, 0, 0, 0, 0, 0, 0, 0};
    for (int kc = 0; kc < 8; kc++) {
        short8 a[4], bb[4];
        #pragma unroll
        for (int mt = 0; mt < 4; mt++)
            a[mt] = *reinterpret_cast<const short8*>(cb + aoff[mt] + kc * 32);
        #pragma unroll
        for (int nt = 0; nt < 4; nt++) {
            short8 v = Z8;
            if (pred[nt]) v = *reinterpret_cast<const short8*>(pb + boff[nt] + kc * 32);
            bb[nt] = v;
        }
        #pragma unroll
        for (int mt = 0; mt < 4; mt++)
            #pragma unroll
            for (int nt = 0; nt < 4; nt++)
                acc[mt][nt] = __builtin_amdgcn_mfma_f32_16x16x32_bf16(
                    a[mt], bb[nt], acc[mt][nt], 0, 0, 0);
    }
    #pragma unroll
    for (int mt = 0; mt < 4; mt++)
        #pragma unroll
        for (int nt = 0; nt < 4; nt++)
            #pragma unroll
            for (int r = 0; r < 4; r++)
                gl[(mt * 16 + lk * 4 + r) * GSTR + wq * 64 + nt * 16 + l15] = acc[mt][nt][r];
    #pragma unroll
    for (int it = 0; it < 2; it++) {
        int f = t + it * 256;
        int s = f >> 8, wp = f & 255;
        int wy = wp >> 4, wx = wp & 15;
        int gy = ty0 - 4 + wy, gxx = tx0 - 4 + wx;
        float v = 0.f;
        if (gy >= 0 && gy < H_ && gxx >= 0 && gxx < W_)
            v = prev_seg[((size_t)b * 2 + s) * HW_ + gy * W_ + gxx] * (1.f / 256.f);
        gl[SEGB + f] = v;
    }
    __syncthreads();
    {
        int m = t & 63;
        int sh = t >> 6;
        int s = sh >> 1, hh = sh & 1;
        int py = m >> 3, lx = m & 7;
        const float* gr = gl + m * GSTR;
        const float* sr = gl + SEGB + s * 256;
        float mx = -INFINITY;
        int wr0 = hh * 5, wr1 = hh ? 9 : 5;
        for (int wr = wr0; wr < wr1; ++wr) {
            int base = (py + wr) * 16 + lx;
            #pragma unroll
            for (int wc = 0; wc < 9; ++wc)
                mx = fmaxf(mx, gr[base + wc] * sr[base + wc]);
        }
        gl[REDB + sh * 64 + m] = mx;
    }
    __syncthreads();
    if (t < 128) {
        int s = t >> 6, m = t & 63;
        float v = fmaxf(gl[REDB + (s * 2 + 0) * 64 + m], gl[REDB + (s * 2 + 1) * 64 + m]);
        int gpx = (ty0 + (m >> 3)) * W_ + tx0 + (m & 7);
        lout[((size_t)b * 2 + s) * HW_ + gpx] = v;
    }
}

// ---------------------------------------------------------------- packs ----
__global__ __launch_bounds__(256)
void pack_dec_kernel(const float* __restrict__ dec, bf16* __restrict__ hcat8)
{
    __shared__ float tile[64][68];
    int b = blockIdx.z, c0 = blockIdx.y * 64, p0 = blockIdx.x * 64;
    int t = threadIdx.x;
    const float* src = dec + ((size_t)b * C_ + c0) * HW_ + p0;
    #pragma unroll
    for (int it = 0; it < 4; it++) {
        int f = t + it * 256;
        int cl = f >> 4, p4 = (f & 15) * 4;
        float4 v = *reinterpret_cast<const float4*>(src + (size_t)cl * HW_ + p4);
        *reinterpret_cast<float4*>(&tile[cl][p4]) = v;
    }
    __syncthreads();
    #pragma unroll
    for (int it = 0; it < 4; it++) {
        int f = t + it * 256;
        int pl = f >> 4, c4 = (f & 15) * 4;
        int p = p0 + pl;
        int y = p / 96, x = p % 96;
        int pos = (y + 1) * HP_ + x + 1;
        int ch = c0 + c4;
        ushort4 u;
        u.x = bfb(tile[c4 + 0][pl]); u.y = bfb(tile[c4 + 1][pl]);
        u.z = bfb(tile[c4 + 2][pl]); u.w = bfb(tile[c4 + 3][pl]);
        bf16* dst = hcat8 + ((size_t)b * 8 + (ch >> 5)) * CHK + (size_t)pos * 32 + (ch & 31);
        *reinterpret_cast<ushort4*>(dst) = u;
    }
}

__global__ __launch_bounds__(256)
void pack_small_kernel(const float* __restrict__ gout,
                       const float* __restrict__ lout,
                       const float* __restrict__ init_seg,
                       const float* __restrict__ prev_seg,
                       bf16* __restrict__ hcat1)
{
    int idx = blockIdx.x * 256 + threadIdx.x;
    if (idx >= B_ * HW_) return;
    int b = idx / HW_, p = idx % HW_;
    int y = p / 96, x = p % 96;
    int pos = (y + 1) * HP_ + x + 1;
    bf16* dst = hcat1 + ((size_t)b * HPW + pos) * 8;
    float g0 = gout[((size_t)b * 2 + 0) * HW_ + p];
    float g1 = gout[((size_t)b * 2 + 1) * HW_ + p];
    float i0 = init_seg[((size_t)b * 2 + 0) * HW_ + p];
    float i1 = init_seg[((size_t)b * 2 + 1) * HW_ + p];
    float l0 = lout[((size_t)b * 2 + 0) * HW_ + p];
    float l1 = lout[((size_t)b * 2 + 1) * HW_ + p];
    float q0 = prev_seg[((size_t)b * 2 + 0) * HW_ + p];
    float q1 = prev_seg[((size_t)b * 2 + 1) * HW_ + p];
    ushort4 u; u.x = bfb(g0); u.y = bfb(g1); u.z = bfb(i0); u.w = bfb(i1);
    *reinterpret_cast<ushort4*>(dst) = u;
    ushort4 u2; u2.x = bfb(l0); u2.y = bfb(l1); u2.z = bfb(q0); u2.w = bfb(q1);
    *reinterpret_cast<ushort4*>(dst + 4) = u2;
}

// ---------------------------------------------------------------- conv1 ----
// 128oc x 256px tile, 8 waves (2M x 4N), BK=64 (step pair), double-buffered LDS,
// global_load_lds staging with inverse-swizzled source, swizzled ds_read (2-way).
__global__ __launch_bounds__(512)
void conv1_mfma(const bf16* __restrict__ hcat8, const bf16* __restrict__ hcat1,
                const bf16* __restrict__ w1bf, const float* __restrict__ b1,
                bf16* __restrict__ hmid)
{
    __shared__ bf16 Abuf[2][8192];    // [128 oc][64 ch]  16 KB per buffer
    __shared__ bf16 Bbuf[2][16384];   // [256 px][64 ch]  32 KB per buffer
    int gid = blockIdx.x;             // 288 = 8 batches (XCD) x 36 px-tiles
    int b = gid & 7;
    int p0 = (gid >> 3) * 256;
    int tid = threadIdx.x, lane = tid & 63;
    int w = tid >> 6, wm = w & 1, wn = w >> 1;
    int l15 = lane & 15, lk = lane >> 4;
    const bf16* hb8 = hcat8 + (size_t)b * 8 * CHK;
    const bf16* hb1 = hcat1 + (size_t)b * HPW * 8;

    // --- staging constants (thread handles chunk f = i*512+tid; row=f>>3, swz col=f&7) ---
    int wbase = tid & 448;                 // wave-uniform chunk base
    int t3 = (tid >> 3) & 7;               // row&7 for all iterations
    int cX = (tid & 7) ^ t3;               // actual chunk (inverse swizzle)
    int selX = cX >> 2;                    // 0 -> step s0, 1 -> step s1
    int cin8 = (cX & 3) * 8;               // element offset within 32-ch slab
    int rA0 = tid >> 3;                    // A row, iteration 0 (iter 1: +64)
    int posB[4];
    #pragma unroll
    for (int i = 0; i < 4; i++) {
        int px = p0 + i * 64 + (tid >> 3);
        posB[i] = (px / 96) * HP_ + (px % 96);
    }
    // --- frag-read swizzled offsets: chunk (k*4+lk) ^ (row&7), row&7 = l15&7 ---
    int swzE0 = ((lk) ^ (l15 & 7)) * 8;
    int swzE1 = ((4 + lk) ^ (l15 & 7)) * 8;

    f32x4 acc[4][4] = {};

    auto STAGE = [&](int p, int bsel) {
        int s0 = 2 * p, s1 = s0 + 1;
        int icc0 = s0 / 9, tap0 = s0 - icc0 * 9;
        int icc1 = s1 / 9, tap1 = s1 - icc1 * 9;
        int toff0 = (tap0 / 3) * HP_ + (tap0 % 3);
        int toff1 = (tap1 / 3) * HP_ + (tap1 % 3);
        // A: 2 chunks/thread
        const bf16* gA = w1bf + (size_t)p * 8192 + (size_t)selX * 4096 + cin8;
        gload_lds16(gA + rA0 * 32,        &Abuf[bsel][(size_t)wbase * 8]);
        gload_lds16(gA + (rA0 + 64) * 32, &Abuf[bsel][(size_t)(512 + wbase) * 8]);
        // B: 4 chunks/thread
        int toffS = selX ? toff1 : toff0;
        int iccS  = selX ? icc1 : icc0;
        bool is8 = (iccS >= 8);
        const bf16* gb = is8 ? hb1 : (hb8 + (size_t)iccS * CHK);
        #pragma unroll
        for (int i = 0; i < 4; i++) {
            const bf16* g = is8 ? (gb + (size_t)(posB[i] + toffS) * 8)
                                : (gb + (size_t)(posB[i] + toffS) * 32 + cin8);
            gload_lds16(g, &Bbuf[bsel][(size_t)(i * 512 + wbase) * 8]);
        }
    };

    auto COMPUTE = [&](int bsel) {
        #pragma unroll
        for (int k = 0; k < 2; k++) {
            int swz = k ? swzE1 : swzE0;
            short8 a[4], bq[4];
            #pragma unroll
            for (int mt = 0; mt < 4; mt++)
                a[mt] = *reinterpret_cast<const short8*>(
                    &Abuf[bsel][(size_t)(wm * 64 + mt * 16 + l15) * 64 + swz]);
            #pragma unroll
            for (int nt = 0; nt < 4; nt++)
                bq[nt] = *reinterpret_cast<const short8*>(
                    &Bbuf[bsel][(size_t)(wn * 64 + nt * 16 + l15) * 64 + swz]);
            #pragma unroll
            for (int mt = 0; mt < 4; mt++)
                #pragma unroll
                for (int nt = 0; nt < 4; nt++)
                    acc[mt][nt] = __builtin_amdgcn_mfma_f32_16x16x32_bf16(
                        a[mt], bq[nt], acc[mt][nt], 0, 0, 0);
        }
    };

    STAGE(0, 0);
    __syncthreads();
    for (int p = 0; p < 41; ++p) {
        if (p < 40) STAGE(p + 1, (p + 1) & 1);
        COMPUTE(p & 1);
        __syncthreads();
    }

    bf16* hm = hmid + (size_t)b * C1O * HW_;
    #pragma unroll
    for (int mt = 0; mt < 4; mt++) {
        int ocb = wm * 64 + mt * 16 + lk * 4;
        float4 bias = *reinterpret_cast<const float4*>(b1 + ocb);
        const float* bp = reinterpret_cast<const float*>(&bias);
        #pragma unroll
        for (int nt = 0; nt < 4; nt++) {
            int px = p0 + wn * 64 + nt * 16 + l15;
            #pragma unroll
            for (int r = 0; r < 4; r++) {
                float v = fmaxf(acc[mt][nt][r] + bp[r], 0.f);
                hm[(size_t)(ocb + r) * HW_ + px] = __float2bfloat16(v);
            }
        }
    }
}

// ---------------------------------------------------------------- conv2 ----
__global__ __launch_bounds__(256)
void conv2_kernel(const bf16* __restrict__ hmid,
                  const float* __restrict__ W2,
                  const float* __restrict__ b2,
                  float* __restrict__ out)
{
    __shared__ float in_s[16][18 * 19];
    __shared__ float w2_s[2][128 * 9];
    int b = blockIdx.y;
    int tile = blockIdx.x;
    int y0 = (tile / 6) * 16, x0 = (tile % 6) * 16;
    int t = threadIdx.x;
    int r = t >> 4, c = t & 15;
    for (int f = t; f < 2 * 128 * 9; f += 256) w2_s[f / 1152][f % 1152] = W2[f];
    float acc0 = 0.f, acc1 = 0.f;
    const bf16* hb = hmid + (size_t)b * C1O * HW_;
    for (int ic0 = 0; ic0 < 128; ic0 += 16) {
        __syncthreads();
        for (int f = t; f < 16 * 18 * 18; f += 256) {
            int ic = f / 324; int rem = f % 324; int row = rem / 18, col = rem % 18;
            int gy = y0 - 1 + row, gxx = x0 - 1 + col;
            float v = 0.f;
            if (gy >= 0 && gy < H_ && gxx >= 0 && gxx < W_)
                v = __bfloat162float(hb[(size_t)(ic0 + ic) * HW_ + gy * W_ + gxx]);
            in_s[ic][row * 19 + col] = v;
        }
        __syncthreads();
        for (int ic = 0; ic < 16; ic++) {
            #pragma unroll
            for (int ky = 0; ky < 3; ky++) {
                #pragma unroll
                for (int kx = 0; kx < 3; kx++) {
                    float x = in_s[ic][(r + ky) * 19 + c + kx];
                    int wk = (ic0 + ic) * 9 + ky * 3 + kx;
                    acc0 += x * w2_s[0][wk];
                    acc1 += x * w2_s[1][wk];
                }
            }
        }
    }
    int py = (y0 + r) * W_ + x0 + c;
    out[((size_t)b * 2 + 0) * HW_ + py] = acc0 + b2[0];
    out[((size_t)b * 2 + 1) * HW_ + py] = acc1 + b2[1];
}

// ---------------------------------------------------------------- launch ----
extern "C" void kernel_launch(void* const* d_in, const int* in_sizes, int n_in,
                              void* d_out, int out_size, void* d_ws, size_t ws_size,
                              hipStream_t stream)
{
    const float* cur_embed  = (const float*)d_in[0];
    const float* cur_decode = (const float*)d_in[1];
    const float* init_embed = (const float*)d_in[2];
    const float* init_seg   = (const float*)d_in[3];
    const float* prev_embed = (const float*)d_in[4];
    const float* prev_seg   = (const float*)d_in[5];
    const float* W1 = (const float*)d_in[6];
    const float* b1 = (const float*)d_in[7];
    const float* W2 = (const float*)d_in[8];
    const float* b2 = (const float*)d_in[9];
    float* out = (float*)d_out;

    char* ws = (char*)d_ws;
    bf16* hcat8 = (bf16*)ws;                          // [8][8][9604][32]
    bf16* curbf = (bf16*)ws;                          // alias (dead at memset)
    bf16* hcat1 = (bf16*)(ws + 39337984);             // [8][9604][8]
    const size_t HCAT_REGION = 40567296;
    bf16* hmid   = (bf16*)(ws + HCAT_REGION);
    bf16* fibf   = (bf16*)(ws + HCAT_REGION);         // phase-1 alias
    bf16* prevbf = (bf16*)(ws + HCAT_REGION);         // phase-2 alias (4 batches)
    float* si  = (float*)(ws + HCAT_REGION + 2621440);
    bf16* w1bf = (bf16*)(ws + 59441664);              // 82 slabs -> 671,744 B
    float* gout = (float*)(ws + 60113408);
    float* lout = (float*)(ws + 60703232);

    { int total = 82 * 128 * 32;
      w1cvt_kernel<<<(total + 255) / 256, 256, 0, stream>>>(W1, w1bf); }
    { dim3 g(144, 4, B_);
      tcur_kernel<<<g, 256, 0, stream>>>(cur_embed, curbf); }
    { int total = B_ * (C_ + 2) * KPP;
      pool_kernel<<<(total + 255) / 256, 256, 0, stream>>>(init_embed, init_seg, fibf, si); }
    { dim3 g(144, B_);
      gmap_mfma<<<g, 128, 0, stream>>>(curbf, fibf, si, gout); }
    for (int g = 0; g < 2; g++) {
        dim3 gt(144, 4, 4);
        tcur_kernel<<<gt, 256, 0, stream>>>(prev_embed + (size_t)g * 4 * C_ * HW_, prevbf);
        dim3 gl(144, 4);
        lmap_mfma<<<gl, 256, 0, stream>>>(curbf, prevbf, prev_seg, lout, g * 4);
    }
    hipMemsetAsync(ws, 0, HCAT_REGION, stream);       // zero hcat8+hcat1; curbf dead
    { dim3 g(144, 4, B_);
      pack_dec_kernel<<<g, 256, 0, stream>>>(cur_decode, hcat8); }
    { int total = B_ * HW_;
      pack_small_kernel<<<(total + 255) / 256, 256, 0, stream>>>(gout, lout, init_seg, prev_seg, hcat1); }
    { conv1_mfma<<<288, 512, 0, stream>>>(hcat8, hcat1, w1bf, b1, hmid); }
    { dim3 g(36, B_);
      conv2_kernel<<<g, 256, 0, stream>>>(hmid, W2, b2, out); }
}

// Round 10
// 384.534 us; speedup vs baseline: 1.9350x; 1.1373x over previous
//
#include <hip/hip_runtime.h>
#include <hip/hip_bf16.h>

// Round 10: conv1 retiled to 128oc x 128px / 4 waves / 64KB LDS (2 blocks/CU
//           co-resident, balanced 576-grid); gmap rebuilt on the same LDS-GEMM
//           template (128kp x 128px, BK=64, per-chunk seg-max epilogue).
// ws layout (61.29 MB, aliased):
//   [0, 39,337,984)           hcat8 bf16 [8][8][9604][32]   -- ALSO curbf bf16 [8][9216][256] (dead at memset)
//   [39,337,984, 40,567,296)  hcat1 bf16 [8][9604][8] (tail ch 256..263)
//   [40,567,296, 59,441,664)  hmid bf16 [8][128][9216]
//       -- phase1 alias: fibf bf16 [8][640][256] @ +0, si f32 [8][2][640] @ +2,621,440
//       -- phase2 alias: prevbf bf16 [4][9216][256] (exactly 18,874,368 B)
//   [59,441,664, 60,113,408)  W1bf bf16 [82][128][32]  (slab s = icc*9+tap; slab 81 = zeros)
//   [60,113,408, 60,703,232)  gout f32 [8][2][9216]
//   [60,703,232, 61,293,056)  lout f32 [8][2][9216]

typedef __hip_bfloat16 bf16;
typedef __attribute__((ext_vector_type(8))) short short8;
typedef __attribute__((ext_vector_type(4))) float f32x4;

constexpr int B_  = 8;
constexpr int C_  = 256;
constexpr int H_  = 96;
constexpr int W_  = 96;
constexpr int HW_ = H_ * W_;       // 9216
constexpr int PW_ = 24;
constexpr int KP_ = 576;
constexpr int KPP = 640;
constexpr int HP_ = 98;
constexpr int HPW = HP_ * HP_;     // 9604
constexpr int C1O = 128;
constexpr int CHK = HPW * 32;      // per 32-ch chunk

__device__ __forceinline__ unsigned short bfb(float f) {
    bf16 h = __float2bfloat16(f);
    return *reinterpret_cast<unsigned short*>(&h);
}

__device__ __forceinline__ void gload_lds16(const bf16* g, bf16* l) {
    __builtin_amdgcn_global_load_lds((const void*)g, (void*)l, 16, 0, 0);
}

// ------------------------------------------------------------ W1 convert ----
__global__ __launch_bounds__(256)
void w1cvt_kernel(const float* __restrict__ W1, bf16* __restrict__ w1bf)
{
    int idx = blockIdx.x * 256 + threadIdx.x;
    if (idx >= 82 * 128 * 32) return;
    int ic = idx & 31;
    int oc = (idx >> 5) & 127;
    int ks = idx >> 12;
    int icc = ks / 9, tap = ks % 9;
    int icg = icc * 32 + ic;
    float v = (icg < 264) ? W1[((size_t)oc * 264 + icg) * 9 + tap] : 0.f;
    w1bf[idx] = __float2bfloat16(v);
}

// ------------------------------------------------------- NCHW->NHWC bf16 ----
__global__ __launch_bounds__(256)
void tcur_kernel(const float* __restrict__ cur, bf16* __restrict__ curbf)
{
    __shared__ float tile[64][68];
    int b = blockIdx.z, c0 = blockIdx.y * 64, p0 = blockIdx.x * 64;
    int t = threadIdx.x;
    const float* src = cur + ((size_t)b * C_ + c0) * HW_ + p0;
    #pragma unroll
    for (int it = 0; it < 4; it++) {
        int f = t + it * 256;
        int cl = f >> 4, p4 = (f & 15) * 4;
        float4 v = *reinterpret_cast<const float4*>(src + (size_t)cl * HW_ + p4);
        *reinterpret_cast<float4*>(&tile[cl][p4]) = v;
    }
    __syncthreads();
    bf16* dst = curbf + ((size_t)b * HW_ + p0) * 256 + c0;
    #pragma unroll
    for (int it = 0; it < 4; it++) {
        int f = t + it * 256;
        int pl = f >> 4, c4 = (f & 15) * 4;
        ushort4 u;
        u.x = bfb(tile[c4 + 0][pl]); u.y = bfb(tile[c4 + 1][pl]);
        u.z = bfb(tile[c4 + 2][pl]); u.w = bfb(tile[c4 + 3][pl]);
        *reinterpret_cast<ushort4*>(dst + (size_t)pl * 256 + c4) = u;
    }
}

// ---------------------------------------------------------------- pool ----
__global__ __launch_bounds__(256)
void pool_kernel(const float* __restrict__ init_embed,
                 const float* __restrict__ init_seg,
                 bf16* __restrict__ fibf, float* __restrict__ si)
{
    int idx = blockIdx.x * 256 + threadIdx.x;
    int total = B_ * (C_ + 2) * KPP;
    if (idx >= total) return;
    int k  = idx % KPP;
    int ch = (idx / KPP) % (C_ + 2);
    int b  = idx / (KPP * (C_ + 2));
    float s = 0.f;
    if (k < KP_) {
        int ph = k / PW_, pw = k % PW_;
        const float* src = (ch < C_)
            ? (init_embed + (((size_t)b * C_ + ch) * H_ + ph * 4) * W_ + pw * 4)
            : (init_seg   + (((size_t)b * 2 + (ch - C_)) * H_ + ph * 4) * W_ + pw * 4);
        #pragma unroll
        for (int r = 0; r < 4; r++) {
            float4 v = *reinterpret_cast<const float4*>(src + r * W_);
            s += v.x + v.y + v.z + v.w;
        }
        s *= (1.f / 16.f);
    }
    if (ch < C_) fibf[((size_t)b * KPP + k) * C_ + ch] = __float2bfloat16(s);
    else         si[(size_t)b * 2 * KPP + (ch - C_) * KPP + k] = s;
}

// ---------------------------------------------------------------- gmap ----
// LDS-GEMM template: tile 128kp x 128px, 4 waves, BK=64, 20 K-steps (5 chunks),
// per-chunk seg-max epilogue in registers, 1 batch/XCD.
__global__ __launch_bounds__(256)
void gmap_mfma(const bf16* __restrict__ curbf, const bf16* __restrict__ fibf,
               const float* __restrict__ si, float* __restrict__ gout)
{
    __shared__ bf16 Abuf[2][8192];    // [128 kp][64 ch]
    __shared__ bf16 Bbuf[2][8192];    // [128 px][64 ch]
    __shared__ float bred[2][2][2][64];   // [wm][wn][s][px]
    int gid = blockIdx.x;             // 576 = 8 b x 72 px-tiles
    int b = gid & 7;
    int p0 = (gid >> 3) * 128;
    int tid = threadIdx.x, lane = tid & 63;
    int w = tid >> 6, wm = w & 1, wn = w >> 1;
    int l15 = lane & 15, lk = lane >> 4;
    const bf16* fb = fibf + (size_t)b * KPP * 256;
    const bf16* cb = curbf + (size_t)b * HW_ * 256;
    const float* sib = si + (size_t)b * 2 * KPP;

    int wbase = tid & 192;
    int t3 = (tid >> 3) & 7;
    int cX = (tid & 7) ^ t3;          // inverse-swizzled true chunk
    int r0 = tid >> 3;
    int swzE0 = ((lk) ^ (l15 & 7)) * 8;
    int swzE1 = ((4 + lk) ^ (l15 & 7)) * 8;

    float best[2][4];
    #pragma unroll
    for (int s = 0; s < 2; s++)
        #pragma unroll
        for (int nt = 0; nt < 4; nt++) best[s][nt] = -INFINITY;
    f32x4 acc[4][4] = {};

    auto STAGE = [&](int q, int bsel) {
        int chunk = q >> 2, ks = q & 3;
        int koff = ks * 64 + cX * 8;
        #pragma unroll
        for (int i = 0; i < 4; i++) {
            int row = i * 32 + r0;
            gload_lds16(fb + (size_t)(chunk * 128 + row) * 256 + koff,
                        &Abuf[bsel][(size_t)(i * 256 + wbase) * 8]);
            gload_lds16(cb + (size_t)(p0 + row) * 256 + koff,
                        &Bbuf[bsel][(size_t)(i * 256 + wbase) * 8]);
        }
    };

    auto COMPUTE = [&](int bsel) {
        #pragma unroll
        for (int k = 0; k < 2; k++) {
            int swz = k ? swzE1 : swzE0;
            short8 a[4], bq[4];
            #pragma unroll
            for (int mt = 0; mt < 4; mt++)
                a[mt] = *reinterpret_cast<const short8*>(
                    &Abuf[bsel][(size_t)(wm * 64 + mt * 16 + l15) * 64 + swz]);
            #pragma unroll
            for (int nt = 0; nt < 4; nt++)
                bq[nt] = *reinterpret_cast<const short8*>(
                    &Bbuf[bsel][(size_t)(wn * 64 + nt * 16 + l15) * 64 + swz]);
            #pragma unroll
            for (int mt = 0; mt < 4; mt++)
                #pragma unroll
                for (int nt = 0; nt < 4; nt++)
                    acc[mt][nt] = __builtin_amdgcn_mfma_f32_16x16x32_bf16(
                        a[mt], bq[nt], acc[mt][nt], 0, 0, 0);
        }
    };

    STAGE(0, 0);
    __syncthreads();
    for (int q = 0; q < 20; ++q) {
        if (q < 19) STAGE(q + 1, (q + 1) & 1);
        COMPUTE(q & 1);
        if ((q & 3) == 3) {
            int kp0 = (q >> 2) * 128;
            #pragma unroll
            for (int mt = 0; mt < 4; mt++) {
                int rb = kp0 + wm * 64 + mt * 16 + lk * 4;
                float4 s0 = *reinterpret_cast<const float4*>(sib + rb);
                float4 s1 = *reinterpret_cast<const float4*>(sib + KPP + rb);
                const float* s0p = reinterpret_cast<const float*>(&s0);
                const float* s1p = reinterpret_cast<const float*>(&s1);
                #pragma unroll
                for (int nt = 0; nt < 4; nt++) {
                    #pragma unroll
                    for (int r = 0; r < 4; r++) {
                        float v = acc[mt][nt][r];
                        best[0][nt] = fmaxf(best[0][nt], v * s0p[r]);
                        best[1][nt] = fmaxf(best[1][nt], v * s1p[r]);
                    }
                    acc[mt][nt] = (f32x4){0.f, 0.f, 0.f, 0.f};
                }
            }
        }
        __syncthreads();
    }
    #pragma unroll
    for (int s = 0; s < 2; s++)
        #pragma unroll
        for (int nt = 0; nt < 4; nt++) {
            float v = best[s][nt];
            v = fmaxf(v, __shfl_xor(v, 16));
            v = fmaxf(v, __shfl_xor(v, 32));
            if (lk == 0) bred[wm][wn][s][nt * 16 + l15] = v;
        }
    __syncthreads();
    {
        int wn2 = tid >> 7, s2 = (tid >> 6) & 1, pxl = tid & 63;
        float v = fmaxf(bred[0][wn2][s2][pxl], bred[1][wn2][s2][pxl]);
        gout[((size_t)b * 2 + s2) * HW_ + p0 + wn2 * 64 + pxl] = v;
    }
}

// ---------------------------------------------------------------- lmap ----
__global__ __launch_bounds__(256)
void lmap_mfma(const bf16* __restrict__ curbf, const bf16* __restrict__ prevbf,
               const float* __restrict__ prev_seg, float* __restrict__ lout, int b0)
{
    constexpr int GSTR = 257;
    constexpr int SEGB = 64 * GSTR;
    constexpr int REDB = SEGB + 512;
    __shared__ float gl[REDB + 256];
    int b = b0 + blockIdx.y;
    const bf16* pb = prevbf + (size_t)blockIdx.y * HW_ * 256;
    const bf16* cb = curbf + (size_t)b * HW_ * 256;
    int tile = blockIdx.x;
    int ty0 = (tile / 12) * 8, tx0 = (tile % 12) * 8;
    int t = threadIdx.x, lane = t & 63, wq = t >> 6;
    int l15 = lane & 15, lk = lane >> 4;

    size_t aoff[4];
    #pragma unroll
    for (int mt = 0; mt < 4; mt++) {
        int m = mt * 16 + l15;
        int gpx = (ty0 + (m >> 3)) * W_ + tx0 + (m & 7);
        aoff[mt] = (size_t)gpx * 256 + lk * 8;
    }
    bool pred[4];
    size_t boff[4];
    int gx = tx0 - 4 + l15;
    bool colok = (gx >= 0) && (gx < W_);
    #pragma unroll
    for (int nt = 0; nt < 4; nt++) {
        int gy = ty0 - 4 + wq * 4 + nt;
        pred[nt] = colok && (gy >= 0) && (gy < H_);
        boff[nt] = pred[nt] ? ((size_t)(gy * W_ + gx) * 256 + lk * 8) : 0;
    }

    f32x4 acc[4][4] = {};
    const short8 Z8 = {0, 0, 0, 0, 0, 0, 0, 0};
    for (int kc = 0; kc < 8; kc++) {
        short8 a[4], bb[4];
        #pragma unroll
        for (int mt = 0; mt < 4; mt++)
            a[mt] = *reinterpret_cast<const short8*>(cb + aoff[mt] + kc * 32);
        #pragma unroll
        for (int nt = 0; nt < 4; nt++) {
            short8 v = Z8;
            if (pred[nt]) v = *reinterpret_cast<const short8*>(pb + boff[nt] + kc * 32);
            bb[nt] = v;
        }
        #pragma unroll
        for (int mt = 0; mt < 4; mt++)
            #pragma unroll
            for (int nt = 0; nt < 4; nt++)
                acc[mt][nt] = __builtin_amdgcn_mfma_f32_16x16x32_bf16(
                    a[mt], bb[nt], acc[mt][nt], 0, 0, 0);
    }
    #pragma unroll
    for (int mt = 0; mt < 4; mt++)
        #pragma unroll
        for (int nt = 0; nt < 4; nt++)
            #pragma unroll
            for (int r = 0; r < 4; r++)
                gl[(mt * 16 + lk * 4 + r) * GSTR + wq * 64 + nt * 16 + l15] = acc[mt][nt][r];
    #pragma unroll
    for (int it = 0; it < 2; it++) {
        int f = t + it * 256;
        int s = f >> 8, wp = f & 255;
        int wy = wp >> 4, wx = wp & 15;
        int gy = ty0 - 4 + wy, gxx = tx0 - 4 + wx;
        float v = 0.f;
        if (gy >= 0 && gy < H_ && gxx >= 0 && gxx < W_)
            v = prev_seg[((size_t)b * 2 + s) * HW_ + gy * W_ + gxx] * (1.f / 256.f);
        gl[SEGB + f] = v;
    }
    __syncthreads();
    {
        int m = t & 63;
        int sh = t >> 6;
        int s = sh >> 1, hh = sh & 1;
        int py = m >> 3, lx = m & 7;
        const float* gr = gl + m * GSTR;
        const float* sr = gl + SEGB + s * 256;
        float mx = -INFINITY;
        int wr0 = hh * 5, wr1 = hh ? 9 : 5;
        for (int wr = wr0; wr < wr1; ++wr) {
            int base = (py + wr) * 16 + lx;
            #pragma unroll
            for (int wc = 0; wc < 9; ++wc)
                mx = fmaxf(mx, gr[base + wc] * sr[base + wc]);
        }
        gl[REDB + sh * 64 + m] = mx;
    }
    __syncthreads();
    if (t < 128) {
        int s = t >> 6, m = t & 63;
        float v = fmaxf(gl[REDB + (s * 2 + 0) * 64 + m], gl[REDB + (s * 2 + 1) * 64 + m]);
        int gpx = (ty0 + (m >> 3)) * W_ + tx0 + (m & 7);
        lout[((size_t)b * 2 + s) * HW_ + gpx] = v;
    }
}

// ---------------------------------------------------------------- packs ----
__global__ __launch_bounds__(256)
void pack_dec_kernel(const float* __restrict__ dec, bf16* __restrict__ hcat8)
{
    __shared__ float tile[64][68];
    int b = blockIdx.z, c0 = blockIdx.y * 64, p0 = blockIdx.x * 64;
    int t = threadIdx.x;
    const float* src = dec + ((size_t)b * C_ + c0) * HW_ + p0;
    #pragma unroll
    for (int it = 0; it < 4; it++) {
        int f = t + it * 256;
        int cl = f >> 4, p4 = (f & 15) * 4;
        float4 v = *reinterpret_cast<const float4*>(src + (size_t)cl * HW_ + p4);
        *reinterpret_cast<float4*>(&tile[cl][p4]) = v;
    }
    __syncthreads();
    #pragma unroll
    for (int it = 0; it < 4; it++) {
        int f = t + it * 256;
        int pl = f >> 4, c4 = (f & 15) * 4;
        int p = p0 + pl;
        int y = p / 96, x = p % 96;
        int pos = (y + 1) * HP_ + x + 1;
        int ch = c0 + c4;
        ushort4 u;
        u.x = bfb(tile[c4 + 0][pl]); u.y = bfb(tile[c4 + 1][pl]);
        u.z = bfb(tile[c4 + 2][pl]); u.w = bfb(tile[c4 + 3][pl]);
        bf16* dst = hcat8 + ((size_t)b * 8 + (ch >> 5)) * CHK + (size_t)pos * 32 + (ch & 31);
        *reinterpret_cast<ushort4*>(dst) = u;
    }
}

__global__ __launch_bounds__(256)
void pack_small_kernel(const float* __restrict__ gout,
                       const float* __restrict__ lout,
                       const float* __restrict__ init_seg,
                       const float* __restrict__ prev_seg,
                       bf16* __restrict__ hcat1)
{
    int idx = blockIdx.x * 256 + threadIdx.x;
    if (idx >= B_ * HW_) return;
    int b = idx / HW_, p = idx % HW_;
    int y = p / 96, x = p % 96;
    int pos = (y + 1) * HP_ + x + 1;
    bf16* dst = hcat1 + ((size_t)b * HPW + pos) * 8;
    float g0 = gout[((size_t)b * 2 + 0) * HW_ + p];
    float g1 = gout[((size_t)b * 2 + 1) * HW_ + p];
    float i0 = init_seg[((size_t)b * 2 + 0) * HW_ + p];
    float i1 = init_seg[((size_t)b * 2 + 1) * HW_ + p];
    float l0 = lout[((size_t)b * 2 + 0) * HW_ + p];
    float l1 = lout[((size_t)b * 2 + 1) * HW_ + p];
    float q0 = prev_seg[((size_t)b * 2 + 0) * HW_ + p];
    float q1 = prev_seg[((size_t)b * 2 + 1) * HW_ + p];
    ushort4 u; u.x = bfb(g0); u.y = bfb(g1); u.z = bfb(i0); u.w = bfb(i1);
    *reinterpret_cast<ushort4*>(dst) = u;
    ushort4 u2; u2.x = bfb(l0); u2.y = bfb(l1); u2.z = bfb(q0); u2.w = bfb(q1);
    *reinterpret_cast<ushort4*>(dst + 4) = u2;
}

// ---------------------------------------------------------------- conv1 ----
// 128oc x 128px tile, 4 waves (2M x 2N), BK=64, double-buffered 64KB LDS,
// global_load_lds(16B) with inverse-swizzled source + swizzled ds_read.
__global__ __launch_bounds__(256)
void conv1_mfma(const bf16* __restrict__ hcat8, const bf16* __restrict__ hcat1,
                const bf16* __restrict__ w1bf, const float* __restrict__ b1,
                bf16* __restrict__ hmid)
{
    __shared__ bf16 Abuf[2][8192];    // [128 oc][64 ch]
    __shared__ bf16 Bbuf[2][8192];    // [128 px][64 ch]
    int gid = blockIdx.x;             // 576 = 8 b x 72 px-tiles
    int b = gid & 7;
    int p0 = (gid >> 3) * 128;
    int tid = threadIdx.x, lane = tid & 63;
    int w = tid >> 6, wm = w & 1, wn = w >> 1;
    int l15 = lane & 15, lk = lane >> 4;
    const bf16* hb8 = hcat8 + (size_t)b * 8 * CHK;
    const bf16* hb1 = hcat1 + (size_t)b * HPW * 8;

    int wbase = tid & 192;
    int t3 = (tid >> 3) & 7;
    int cX = (tid & 7) ^ t3;
    int selX = cX >> 2;
    int cin8 = (cX & 3) * 8;
    int r0 = tid >> 3;
    int posB[4];
    #pragma unroll
    for (int i = 0; i < 4; i++) {
        int px = p0 + i * 32 + r0;
        posB[i] = (px / 96) * HP_ + (px % 96);
    }
    int swzE0 = ((lk) ^ (l15 & 7)) * 8;
    int swzE1 = ((4 + lk) ^ (l15 & 7)) * 8;

    f32x4 acc[4][4] = {};

    auto STAGE = [&](int p, int bsel) {
        int s0 = 2 * p, s1 = s0 + 1;
        int icc0 = s0 / 9, tap0 = s0 - icc0 * 9;
        int icc1 = s1 / 9, tap1 = s1 - icc1 * 9;
        int toff0 = (tap0 / 3) * HP_ + (tap0 % 3);
        int toff1 = (tap1 / 3) * HP_ + (tap1 % 3);
        const bf16* gA = w1bf + (size_t)p * 8192 + (size_t)selX * 4096 + cin8;
        #pragma unroll
        for (int i = 0; i < 4; i++)
            gload_lds16(gA + (i * 32 + r0) * 32,
                        &Abuf[bsel][(size_t)(i * 256 + wbase) * 8]);
        int toffS = selX ? toff1 : toff0;
        int iccS  = selX ? icc1 : icc0;
        bool is8 = (iccS >= 8);
        const bf16* gb = is8 ? hb1 : (hb8 + (size_t)iccS * CHK);
        #pragma unroll
        for (int i = 0; i < 4; i++) {
            const bf16* g = is8 ? (gb + (size_t)(posB[i] + toffS) * 8)
                                : (gb + (size_t)(posB[i] + toffS) * 32 + cin8);
            gload_lds16(g, &Bbuf[bsel][(size_t)(i * 256 + wbase) * 8]);
        }
    };

    auto COMPUTE = [&](int bsel) {
        #pragma unroll
        for (int k = 0; k < 2; k++) {
            int swz = k ? swzE1 : swzE0;
            short8 a[4], bq[4];
            #pragma unroll
            for (int mt = 0; mt < 4; mt++)
                a[mt] = *reinterpret_cast<const short8*>(
                    &Abuf[bsel][(size_t)(wm * 64 + mt * 16 + l15) * 64 + swz]);
            #pragma unroll
            for (int nt = 0; nt < 4; nt++)
                bq[nt] = *reinterpret_cast<const short8*>(
                    &Bbuf[bsel][(size_t)(wn * 64 + nt * 16 + l15) * 64 + swz]);
            #pragma unroll
            for (int mt = 0; mt < 4; mt++)
                #pragma unroll
                for (int nt = 0; nt < 4; nt++)
                    acc[mt][nt] = __builtin_amdgcn_mfma_f32_16x16x32_bf16(
                        a[mt], bq[nt], acc[mt][nt], 0, 0, 0);
        }
    };

    STAGE(0, 0);
    __syncthreads();
    for (int p = 0; p < 41; ++p) {
        if (p < 40) STAGE(p + 1, (p + 1) & 1);
        COMPUTE(p & 1);
        __syncthreads();
    }

    bf16* hm = hmid + (size_t)b * C1O * HW_;
    #pragma unroll
    for (int mt = 0; mt < 4; mt++) {
        int ocb = wm * 64 + mt * 16 + lk * 4;
        float4 bias = *reinterpret_cast<const float4*>(b1 + ocb);
        const float* bp = reinterpret_cast<const float*>(&bias);
        #pragma unroll
        for (int nt = 0; nt < 4; nt++) {
            int px = p0 + wn * 64 + nt * 16 + l15;
            #pragma unroll
            for (int r = 0; r < 4; r++) {
                float v = fmaxf(acc[mt][nt][r] + bp[r], 0.f);
                hm[(size_t)(ocb + r) * HW_ + px] = __float2bfloat16(v);
            }
        }
    }
}

// ---------------------------------------------------------------- conv2 ----
__global__ __launch_bounds__(256)
void conv2_kernel(const bf16* __restrict__ hmid,
                  const float* __restrict__ W2,
                  const float* __restrict__ b2,
                  float* __restrict__ out)
{
    __shared__ float in_s[16][18 * 19];
    __shared__ float w2_s[2][128 * 9];
    int b = blockIdx.y;
    int tile = blockIdx.x;
    int y0 = (tile / 6) * 16, x0 = (tile % 6) * 16;
    int t = threadIdx.x;
    int r = t >> 4, c = t & 15;
    for (int f = t; f < 2 * 128 * 9; f += 256) w2_s[f / 1152][f % 1152] = W2[f];
    float acc0 = 0.f, acc1 = 0.f;
    const bf16* hb = hmid + (size_t)b * C1O * HW_;
    for (int ic0 = 0; ic0 < 128; ic0 += 16) {
        __syncthreads();
        for (int f = t; f < 16 * 18 * 18; f += 256) {
            int ic = f / 324; int rem = f % 324; int row = rem / 18, col = rem % 18;
            int gy = y0 - 1 + row, gxx = x0 - 1 + col;
            float v = 0.f;
            if (gy >= 0 && gy < H_ && gxx >= 0 && gxx < W_)
                v = __bfloat162float(hb[(size_t)(ic0 + ic) * HW_ + gy * W_ + gxx]);
            in_s[ic][row * 19 + col] = v;
        }
        __syncthreads();
        for (int ic = 0; ic < 16; ic++) {
            #pragma unroll
            for (int ky = 0; ky < 3; ky++) {
                #pragma unroll
                for (int kx = 0; kx < 3; kx++) {
                    float x = in_s[ic][(r + ky) * 19 + c + kx];
                    int wk = (ic0 + ic) * 9 + ky * 3 + kx;
                    acc0 += x * w2_s[0][wk];
                    acc1 += x * w2_s[1][wk];
                }
            }
        }
    }
    int py = (y0 + r) * W_ + x0 + c;
    out[((size_t)b * 2 + 0) * HW_ + py] = acc0 + b2[0];
    out[((size_t)b * 2 + 1) * HW_ + py] = acc1 + b2[1];
}

// ---------------------------------------------------------------- launch ----
extern "C" void kernel_launch(void* const* d_in, const int* in_sizes, int n_in,
                              void* d_out, int out_size, void* d_ws, size_t ws_size,
                              hipStream_t stream)
{
    const float* cur_embed  = (const float*)d_in[0];
    const float* cur_decode = (const float*)d_in[1];
    const float* init_embed = (const float*)d_in[2];
    const float* init_seg   = (const float*)d_in[3];
    const float* prev_embed = (const float*)d_in[4];
    const float* prev_seg   = (const float*)d_in[5];
    const float* W1 = (const float*)d_in[6];
    const float* b1 = (const float*)d_in[7];
    const float* W2 = (const float*)d_in[8];
    const float* b2 = (const float*)d_in[9];
    float* out = (float*)d_out;

    char* ws = (char*)d_ws;
    bf16* hcat8 = (bf16*)ws;                          // [8][8][9604][32]
    bf16* curbf = (bf16*)ws;                          // alias (dead at memset)
    bf16* hcat1 = (bf16*)(ws + 39337984);             // [8][9604][8]
    const size_t HCAT_REGION = 40567296;
    bf16* hmid   = (bf16*)(ws + HCAT_REGION);
    bf16* fibf   = (bf16*)(ws + HCAT_REGION);         // phase-1 alias
    bf16* prevbf = (bf16*)(ws + HCAT_REGION);         // phase-2 alias (4 batches)
    float* si  = (float*)(ws + HCAT_REGION + 2621440);
    bf16* w1bf = (bf16*)(ws + 59441664);              // 82 slabs
    float* gout = (float*)(ws + 60113408);
    float* lout = (float*)(ws + 60703232);

    { int total = 82 * 128 * 32;
      w1cvt_kernel<<<(total + 255) / 256, 256, 0, stream>>>(W1, w1bf); }
    { dim3 g(144, 4, B_);
      tcur_kernel<<<g, 256, 0, stream>>>(cur_embed, curbf); }
    { int total = B_ * (C_ + 2) * KPP;
      pool_kernel<<<(total + 255) / 256, 256, 0, stream>>>(init_embed, init_seg, fibf, si); }
    { gmap_mfma<<<576, 256, 0, stream>>>(curbf, fibf, si, gout); }
    for (int g = 0; g < 2; g++) {
        dim3 gt(144, 4, 4);
        tcur_kernel<<<gt, 256, 0, stream>>>(prev_embed + (size_t)g * 4 * C_ * HW_, prevbf);
        dim3 gl(144, 4);
        lmap_mfma<<<gl, 256, 0, stream>>>(curbf, prevbf, prev_seg, lout, g * 4);
    }
    hipMemsetAsync(ws, 0, HCAT_REGION, stream);       // zero hcat8+hcat1; curbf dead
    { dim3 g(144, 4, B_);
      pack_dec_kernel<<<g, 256, 0, stream>>>(cur_decode, hcat8); }
    { int total = B_ * HW_;
      pack_small_kernel<<<(total + 255) / 256, 256, 0, stream>>>(gout, lout, init_seg, prev_seg, hcat1); }
    { conv1_mfma<<<576, 256, 0, stream>>>(hcat8, hcat1, w1bf, b1, hmid); }
    { dim3 g(36, B_);
      conv2_kernel<<<g, 256, 0, stream>>>(hmid, W2, b2, out); }
}

// Round 11
// 359.921 us; speedup vs baseline: 2.0673x; 1.0684x over previous
//
#include <hip/hip_runtime.h>
#include <hip/hip_bf16.h>

// Round 11: conv1 + gmap -> SINGLE-buffered 32KB LDS, 2 barriers/K-step
//           (m97 config: 4 blocks/CU co-resident; inter-block overlap hides
//           the vmcnt drain that double-buffering couldn't at 1 block/CU).
// ws layout (61.29 MB, aliased):
//   [0, 39,337,984)           hcat8 bf16 [8][8][9604][32]   -- ALSO curbf bf16 [8][9216][256] (dead at memset)
//   [39,337,984, 40,567,296)  hcat1 bf16 [8][9604][8] (tail ch 256..263)
//   [40,567,296, 59,441,664)  hmid bf16 [8][128][9216]
//       -- phase1 alias: fibf bf16 [8][640][256] @ +0, si f32 [8][2][640] @ +2,621,440
//       -- phase2 alias: prevbf bf16 [4][9216][256] (exactly 18,874,368 B)
//   [59,441,664, 60,113,408)  W1bf bf16 [82][128][32]  (slab s = icc*9+tap; slab 81 = zeros)
//   [60,113,408, 60,703,232)  gout f32 [8][2][9216]
//   [60,703,232, 61,293,056)  lout f32 [8][2][9216]

typedef __hip_bfloat16 bf16;
typedef __attribute__((ext_vector_type(8))) short short8;
typedef __attribute__((ext_vector_type(4))) float f32x4;

constexpr int B_  = 8;
constexpr int C_  = 256;
constexpr int H_  = 96;
constexpr int W_  = 96;
constexpr int HW_ = H_ * W_;       // 9216
constexpr int PW_ = 24;
constexpr int KP_ = 576;
constexpr int KPP = 640;
constexpr int HP_ = 98;
constexpr int HPW = HP_ * HP_;     // 9604
constexpr int C1O = 128;
constexpr int CHK = HPW * 32;      // per 32-ch chunk

__device__ __forceinline__ unsigned short bfb(float f) {
    bf16 h = __float2bfloat16(f);
    return *reinterpret_cast<unsigned short*>(&h);
}

__device__ __forceinline__ void gload_lds16(const bf16* g, bf16* l) {
    __builtin_amdgcn_global_load_lds((const void*)g, (void*)l, 16, 0, 0);
}

// ------------------------------------------------------------ W1 convert ----
__global__ __launch_bounds__(256)
void w1cvt_kernel(const float* __restrict__ W1, bf16* __restrict__ w1bf)
{
    int idx = blockIdx.x * 256 + threadIdx.x;
    if (idx >= 82 * 128 * 32) return;
    int ic = idx & 31;
    int oc = (idx >> 5) & 127;
    int ks = idx >> 12;
    int icc = ks / 9, tap = ks % 9;
    int icg = icc * 32 + ic;
    float v = (icg < 264) ? W1[((size_t)oc * 264 + icg) * 9 + tap] : 0.f;
    w1bf[idx] = __float2bfloat16(v);
}

// ------------------------------------------------------- NCHW->NHWC bf16 ----
__global__ __launch_bounds__(256)
void tcur_kernel(const float* __restrict__ cur, bf16* __restrict__ curbf)
{
    __shared__ float tile[64][68];
    int b = blockIdx.z, c0 = blockIdx.y * 64, p0 = blockIdx.x * 64;
    int t = threadIdx.x;
    const float* src = cur + ((size_t)b * C_ + c0) * HW_ + p0;
    #pragma unroll
    for (int it = 0; it < 4; it++) {
        int f = t + it * 256;
        int cl = f >> 4, p4 = (f & 15) * 4;
        float4 v = *reinterpret_cast<const float4*>(src + (size_t)cl * HW_ + p4);
        *reinterpret_cast<float4*>(&tile[cl][p4]) = v;
    }
    __syncthreads();
    bf16* dst = curbf + ((size_t)b * HW_ + p0) * 256 + c0;
    #pragma unroll
    for (int it = 0; it < 4; it++) {
        int f = t + it * 256;
        int pl = f >> 4, c4 = (f & 15) * 4;
        ushort4 u;
        u.x = bfb(tile[c4 + 0][pl]); u.y = bfb(tile[c4 + 1][pl]);
        u.z = bfb(tile[c4 + 2][pl]); u.w = bfb(tile[c4 + 3][pl]);
        *reinterpret_cast<ushort4*>(dst + (size_t)pl * 256 + c4) = u;
    }
}

// ---------------------------------------------------------------- pool ----
__global__ __launch_bounds__(256)
void pool_kernel(const float* __restrict__ init_embed,
                 const float* __restrict__ init_seg,
                 bf16* __restrict__ fibf, float* __restrict__ si)
{
    int idx = blockIdx.x * 256 + threadIdx.x;
    int total = B_ * (C_ + 2) * KPP;
    if (idx >= total) return;
    int k  = idx % KPP;
    int ch = (idx / KPP) % (C_ + 2);
    int b  = idx / (KPP * (C_ + 2));
    float s = 0.f;
    if (k < KP_) {
        int ph = k / PW_, pw = k % PW_;
        const float* src = (ch < C_)
            ? (init_embed + (((size_t)b * C_ + ch) * H_ + ph * 4) * W_ + pw * 4)
            : (init_seg   + (((size_t)b * 2 + (ch - C_)) * H_ + ph * 4) * W_ + pw * 4);
        #pragma unroll
        for (int r = 0; r < 4; r++) {
            float4 v = *reinterpret_cast<const float4*>(src + r * W_);
            s += v.x + v.y + v.z + v.w;
        }
        s *= (1.f / 16.f);
    }
    if (ch < C_) fibf[((size_t)b * KPP + k) * C_ + ch] = __float2bfloat16(s);
    else         si[(size_t)b * 2 * KPP + (ch - C_) * KPP + k] = s;
}

// ---------------------------------------------------------------- gmap ----
// Single-buffered LDS-GEMM: 128kp x 128px, 4 waves, BK=64, 20 K-steps,
// 2 barriers/step, per-chunk seg-max epilogue, 1 batch/XCD.
__global__ __launch_bounds__(256)
void gmap_mfma(const bf16* __restrict__ curbf, const bf16* __restrict__ fibf,
               const float* __restrict__ si, float* __restrict__ gout)
{
    __shared__ bf16 Abuf[8192];       // [128 kp][64 ch]  16 KB
    __shared__ bf16 Bbuf[8192];       // [128 px][64 ch]  16 KB
    __shared__ float bred[2][2][2][64];
    int gid = blockIdx.x;             // 576 = 8 b x 72 px-tiles
    int b = gid & 7;
    int p0 = (gid >> 3) * 128;
    int tid = threadIdx.x, lane = tid & 63;
    int w = tid >> 6, wm = w & 1, wn = w >> 1;
    int l15 = lane & 15, lk = lane >> 4;
    const bf16* fb = fibf + (size_t)b * KPP * 256;
    const bf16* cb = curbf + (size_t)b * HW_ * 256;
    const float* sib = si + (size_t)b * 2 * KPP;

    int wbase = tid & 192;
    int t3 = (tid >> 3) & 7;
    int cX = (tid & 7) ^ t3;          // inverse-swizzled true chunk
    int r0 = tid >> 3;
    int swzE0 = ((lk) ^ (l15 & 7)) * 8;
    int swzE1 = ((4 + lk) ^ (l15 & 7)) * 8;

    float best[2][4];
    #pragma unroll
    for (int s = 0; s < 2; s++)
        #pragma unroll
        for (int nt = 0; nt < 4; nt++) best[s][nt] = -INFINITY;
    f32x4 acc[4][4] = {};

    auto STAGE = [&](int q) {
        int chunk = q >> 2, ks = q & 3;
        int koff = ks * 64 + cX * 8;
        #pragma unroll
        for (int i = 0; i < 4; i++) {
            int row = i * 32 + r0;
            gload_lds16(fb + (size_t)(chunk * 128 + row) * 256 + koff,
                        &Abuf[(size_t)(i * 256 + wbase) * 8]);
            gload_lds16(cb + (size_t)(p0 + row) * 256 + koff,
                        &Bbuf[(size_t)(i * 256 + wbase) * 8]);
        }
    };

    auto COMPUTE = [&]() {
        #pragma unroll
        for (int k = 0; k < 2; k++) {
            int swz = k ? swzE1 : swzE0;
            short8 a[4], bq[4];
            #pragma unroll
            for (int mt = 0; mt < 4; mt++)
                a[mt] = *reinterpret_cast<const short8*>(
                    &Abuf[(size_t)(wm * 64 + mt * 16 + l15) * 64 + swz]);
            #pragma unroll
            for (int nt = 0; nt < 4; nt++)
                bq[nt] = *reinterpret_cast<const short8*>(
                    &Bbuf[(size_t)(wn * 64 + nt * 16 + l15) * 64 + swz]);
            #pragma unroll
            for (int mt = 0; mt < 4; mt++)
                #pragma unroll
                for (int nt = 0; nt < 4; nt++)
                    acc[mt][nt] = __builtin_amdgcn_mfma_f32_16x16x32_bf16(
                        a[mt], bq[nt], acc[mt][nt], 0, 0, 0);
        }
    };

    for (int q = 0; q < 20; ++q) {
        STAGE(q);
        __syncthreads();
        COMPUTE();
        if ((q & 3) == 3) {
            int kp0 = (q >> 2) * 128;
            #pragma unroll
            for (int mt = 0; mt < 4; mt++) {
                int rb = kp0 + wm * 64 + mt * 16 + lk * 4;
                float4 s0 = *reinterpret_cast<const float4*>(sib + rb);
                float4 s1 = *reinterpret_cast<const float4*>(sib + KPP + rb);
                const float* s0p = reinterpret_cast<const float*>(&s0);
                const float* s1p = reinterpret_cast<const float*>(&s1);
                #pragma unroll
                for (int nt = 0; nt < 4; nt++) {
                    #pragma unroll
                    for (int r = 0; r < 4; r++) {
                        float v = acc[mt][nt][r];
                        best[0][nt] = fmaxf(best[0][nt], v * s0p[r]);
                        best[1][nt] = fmaxf(best[1][nt], v * s1p[r]);
                    }
                    acc[mt][nt] = (f32x4){0.f, 0.f, 0.f, 0.f};
                }
            }
        }
        __syncthreads();
    }
    #pragma unroll
    for (int s = 0; s < 2; s++)
        #pragma unroll
        for (int nt = 0; nt < 4; nt++) {
            float v = best[s][nt];
            v = fmaxf(v, __shfl_xor(v, 16));
            v = fmaxf(v, __shfl_xor(v, 32));
            if (lk == 0) bred[wm][wn][s][nt * 16 + l15] = v;
        }
    __syncthreads();
    {
        int wn2 = tid >> 7, s2 = (tid >> 6) & 1, pxl = tid & 63;
        float v = fmaxf(bred[0][wn2][s2][pxl], bred[1][wn2][s2][pxl]);
        gout[((size_t)b * 2 + s2) * HW_ + p0 + wn2 * 64 + pxl] = v;
    }
}

// ---------------------------------------------------------------- lmap ----
__global__ __launch_bounds__(256)
void lmap_mfma(const bf16* __restrict__ curbf, const bf16* __restrict__ prevbf,
               const float* __restrict__ prev_seg, float* __restrict__ lout, int b0)
{
    constexpr int GSTR = 257;
    constexpr int SEGB = 64 * GSTR;
    constexpr int REDB = SEGB + 512;
    __shared__ float gl[REDB + 256];
    int b = b0 + blockIdx.y;
    const bf16* pb = prevbf + (size_t)blockIdx.y * HW_ * 256;
    const bf16* cb = curbf + (size_t)b * HW_ * 256;
    int tile = blockIdx.x;
    int ty0 = (tile / 12) * 8, tx0 = (tile % 12) * 8;
    int t = threadIdx.x, lane = t & 63, wq = t >> 6;
    int l15 = lane & 15, lk = lane >> 4;

    size_t aoff[4];
    #pragma unroll
    for (int mt = 0; mt < 4; mt++) {
        int m = mt * 16 + l15;
        int gpx = (ty0 + (m >> 3)) * W_ + tx0 + (m & 7);
        aoff[mt] = (size_t)gpx * 256 + lk * 8;
    }
    bool pred[4];
    size_t boff[4];
    int gx = tx0 - 4 + l15;
    bool colok = (gx >= 0) && (gx < W_);
    #pragma unroll
    for (int nt = 0; nt < 4; nt++) {
        int gy = ty0 - 4 + wq * 4 + nt;
        pred[nt] = colok && (gy >= 0) && (gy < H_);
        boff[nt] = pred[nt] ? ((size_t)(gy * W_ + gx) * 256 + lk * 8) : 0;
    }

    f32x4 acc[4][4] = {};
    const short8 Z8 = {0, 0, 0, 0, 0, 0, 0, 0};
    for (int kc = 0; kc < 8; kc++) {
        short8 a[4], bb[4];
        #pragma unroll
        for (int mt = 0; mt < 4; mt++)
            a[mt] = *reinterpret_cast<const short8*>(cb + aoff[mt] + kc * 32);
        #pragma unroll
        for (int nt = 0; nt < 4; nt++) {
            short8 v = Z8;
            if (pred[nt]) v = *reinterpret_cast<const short8*>(pb + boff[nt] + kc * 32);
            bb[nt] = v;
        }
        #pragma unroll
        for (int mt = 0; mt < 4; mt++)
            #pragma unroll
            for (int nt = 0; nt < 4; nt++)
                acc[mt][nt] = __builtin_amdgcn_mfma_f32_16x16x32_bf16(
                    a[mt], bb[nt], acc[mt][nt], 0, 0, 0);
    }
    #pragma unroll
    for (int mt = 0; mt < 4; mt++)
        #pragma unroll
        for (int nt = 0; nt < 4; nt++)
            #pragma unroll
            for (int r = 0; r < 4; r++)
                gl[(mt * 16 + lk * 4 + r) * GSTR + wq * 64 + nt * 16 + l15] = acc[mt][nt][r];
    #pragma unroll
    for (int it = 0; it < 2; it++) {
        int f = t + it * 256;
        int s = f >> 8, wp = f & 255;
        int wy = wp >> 4, wx = wp & 15;
        int gy = ty0 - 4 + wy, gxx = tx0 - 4 + wx;
        float v = 0.f;
        if (gy >= 0 && gy < H_ && gxx >= 0 && gxx < W_)
            v = prev_seg[((size_t)b * 2 + s) * HW_ + gy * W_ + gxx] * (1.f / 256.f);
        gl[SEGB + f] = v;
    }
    __syncthreads();
    {
        int m = t & 63;
        int sh = t >> 6;
        int s = sh >> 1, hh = sh & 1;
        int py = m >> 3, lx = m & 7;
        const float* gr = gl + m * GSTR;
        const float* sr = gl + SEGB + s * 256;
        float mx = -INFINITY;
        int wr0 = hh * 5, wr1 = hh ? 9 : 5;
        for (int wr = wr0; wr < wr1; ++wr) {
            int base = (py + wr) * 16 + lx;
            #pragma unroll
            for (int wc = 0; wc < 9; ++wc)
                mx = fmaxf(mx, gr[base + wc] * sr[base + wc]);
        }
        gl[REDB + sh * 64 + m] = mx;
    }
    __syncthreads();
    if (t < 128) {
        int s = t >> 6, m = t & 63;
        float v = fmaxf(gl[REDB + (s * 2 + 0) * 64 + m], gl[REDB + (s * 2 + 1) * 64 + m]);
        int gpx = (ty0 + (m >> 3)) * W_ + tx0 + (m & 7);
        lout[((size_t)b * 2 + s) * HW_ + gpx] = v;
    }
}

// ---------------------------------------------------------------- packs ----
__global__ __launch_bounds__(256)
void pack_dec_kernel(const float* __restrict__ dec, bf16* __restrict__ hcat8)
{
    __shared__ float tile[64][68];
    int b = blockIdx.z, c0 = blockIdx.y * 64, p0 = blockIdx.x * 64;
    int t = threadIdx.x;
    const float* src = dec + ((size_t)b * C_ + c0) * HW_ + p0;
    #pragma unroll
    for (int it = 0; it < 4; it++) {
        int f = t + it * 256;
        int cl = f >> 4, p4 = (f & 15) * 4;
        float4 v = *reinterpret_cast<const float4*>(src + (size_t)cl * HW_ + p4);
        *reinterpret_cast<float4*>(&tile[cl][p4]) = v;
    }
    __syncthreads();
    #pragma unroll
    for (int it = 0; it < 4; it++) {
        int f = t + it * 256;
        int pl = f >> 4, c4 = (f & 15) * 4;
        int p = p0 + pl;
        int y = p / 96, x = p % 96;
        int pos = (y + 1) * HP_ + x + 1;
        int ch = c0 + c4;
        ushort4 u;
        u.x = bfb(tile[c4 + 0][pl]); u.y = bfb(tile[c4 + 1][pl]);
        u.z = bfb(tile[c4 + 2][pl]); u.w = bfb(tile[c4 + 3][pl]);
        bf16* dst = hcat8 + ((size_t)b * 8 + (ch >> 5)) * CHK + (size_t)pos * 32 + (ch & 31);
        *reinterpret_cast<ushort4*>(dst) = u;
    }
}

__global__ __launch_bounds__(256)
void pack_small_kernel(const float* __restrict__ gout,
                       const float* __restrict__ lout,
                       const float* __restrict__ init_seg,
                       const float* __restrict__ prev_seg,
                       bf16* __restrict__ hcat1)
{
    int idx = blockIdx.x * 256 + threadIdx.x;
    if (idx >= B_ * HW_) return;
    int b = idx / HW_, p = idx % HW_;
    int y = p / 96, x = p % 96;
    int pos = (y + 1) * HP_ + x + 1;
    bf16* dst = hcat1 + ((size_t)b * HPW + pos) * 8;
    float g0 = gout[((size_t)b * 2 + 0) * HW_ + p];
    float g1 = gout[((size_t)b * 2 + 1) * HW_ + p];
    float i0 = init_seg[((size_t)b * 2 + 0) * HW_ + p];
    float i1 = init_seg[((size_t)b * 2 + 1) * HW_ + p];
    float l0 = lout[((size_t)b * 2 + 0) * HW_ + p];
    float l1 = lout[((size_t)b * 2 + 1) * HW_ + p];
    float q0 = prev_seg[((size_t)b * 2 + 0) * HW_ + p];
    float q1 = prev_seg[((size_t)b * 2 + 1) * HW_ + p];
    ushort4 u; u.x = bfb(g0); u.y = bfb(g1); u.z = bfb(i0); u.w = bfb(i1);
    *reinterpret_cast<ushort4*>(dst) = u;
    ushort4 u2; u2.x = bfb(l0); u2.y = bfb(l1); u2.z = bfb(q0); u2.w = bfb(q1);
    *reinterpret_cast<ushort4*>(dst + 4) = u2;
}

// ---------------------------------------------------------------- conv1 ----
// 128oc x 128px tile, 4 waves, BK=64, SINGLE-buffered 32KB LDS, 2 barriers/step,
// global_load_lds(16B) with inverse-swizzled source + swizzled ds_read.
__global__ __launch_bounds__(256)
void conv1_mfma(const bf16* __restrict__ hcat8, const bf16* __restrict__ hcat1,
                const bf16* __restrict__ w1bf, const float* __restrict__ b1,
                bf16* __restrict__ hmid)
{
    __shared__ bf16 Abuf[8192];       // [128 oc][64 ch]  16 KB
    __shared__ bf16 Bbuf[8192];       // [128 px][64 ch]  16 KB
    int gid = blockIdx.x;             // 576 = 8 b x 72 px-tiles
    int b = gid & 7;
    int p0 = (gid >> 3) * 128;
    int tid = threadIdx.x, lane = tid & 63;
    int w = tid >> 6, wm = w & 1, wn = w >> 1;
    int l15 = lane & 15, lk = lane >> 4;
    const bf16* hb8 = hcat8 + (size_t)b * 8 * CHK;
    const bf16* hb1 = hcat1 + (size_t)b * HPW * 8;

    int wbase = tid & 192;
    int t3 = (tid >> 3) & 7;
    int cX = (tid & 7) ^ t3;
    int selX = cX >> 2;
    int cin8 = (cX & 3) * 8;
    int r0 = tid >> 3;
    int posB[4];
    #pragma unroll
    for (int i = 0; i < 4; i++) {
        int px = p0 + i * 32 + r0;
        posB[i] = (px / 96) * HP_ + (px % 96);
    }
    int swzE0 = ((lk) ^ (l15 & 7)) * 8;
    int swzE1 = ((4 + lk) ^ (l15 & 7)) * 8;

    f32x4 acc[4][4] = {};

    auto STAGE = [&](int p) {
        int s0 = 2 * p, s1 = s0 + 1;
        int icc0 = s0 / 9, tap0 = s0 - icc0 * 9;
        int icc1 = s1 / 9, tap1 = s1 - icc1 * 9;
        int toff0 = (tap0 / 3) * HP_ + (tap0 % 3);
        int toff1 = (tap1 / 3) * HP_ + (tap1 % 3);
        const bf16* gA = w1bf + (size_t)p * 8192 + (size_t)selX * 4096 + cin8;
        #pragma unroll
        for (int i = 0; i < 4; i++)
            gload_lds16(gA + (i * 32 + r0) * 32,
                        &Abuf[(size_t)(i * 256 + wbase) * 8]);
        int toffS = selX ? toff1 : toff0;
        int iccS  = selX ? icc1 : icc0;
        bool is8 = (iccS >= 8);
        const bf16* gb = is8 ? hb1 : (hb8 + (size_t)iccS * CHK);
        #pragma unroll
        for (int i = 0; i < 4; i++) {
            const bf16* g = is8 ? (gb + (size_t)(posB[i] + toffS) * 8)
                                : (gb + (size_t)(posB[i] + toffS) * 32 + cin8);
            gload_lds16(g, &Bbuf[(size_t)(i * 256 + wbase) * 8]);
        }
    };

    auto COMPUTE = [&]() {
        #pragma unroll
        for (int k = 0; k < 2; k++) {
            int swz = k ? swzE1 : swzE0;
            short8 a[4], bq[4];
            #pragma unroll
            for (int mt = 0; mt < 4; mt++)
                a[mt] = *reinterpret_cast<const short8*>(
                    &Abuf[(size_t)(wm * 64 + mt * 16 + l15) * 64 + swz]);
            #pragma unroll
            for (int nt = 0; nt < 4; nt++)
                bq[nt] = *reinterpret_cast<const short8*>(
                    &Bbuf[(size_t)(wn * 64 + nt * 16 + l15) * 64 + swz]);
            #pragma unroll
            for (int mt = 0; mt < 4; mt++)
                #pragma unroll
                for (int nt = 0; nt < 4; nt++)
                    acc[mt][nt] = __builtin_amdgcn_mfma_f32_16x16x32_bf16(
                        a[mt], bq[nt], acc[mt][nt], 0, 0, 0);
        }
    };

    for (int p = 0; p < 41; ++p) {
        STAGE(p);
        __syncthreads();
        COMPUTE();
        __syncthreads();
    }

    bf16* hm = hmid + (size_t)b * C1O * HW_;
    #pragma unroll
    for (int mt = 0; mt < 4; mt++) {
        int ocb = wm * 64 + mt * 16 + lk * 4;
        float4 bias = *reinterpret_cast<const float4*>(b1 + ocb);
        const float* bp = reinterpret_cast<const float*>(&bias);
        #pragma unroll
        for (int nt = 0; nt < 4; nt++) {
            int px = p0 + wn * 64 + nt * 16 + l15;
            #pragma unroll
            for (int r = 0; r < 4; r++) {
                float v = fmaxf(acc[mt][nt][r] + bp[r], 0.f);
                hm[(size_t)(ocb + r) * HW_ + px] = __float2bfloat16(v);
            }
        }
    }
}

// ---------------------------------------------------------------- conv2 ----
__global__ __launch_bounds__(256)
void conv2_kernel(const bf16* __restrict__ hmid,
                  const float* __restrict__ W2,
                  const float* __restrict__ b2,
                  float* __restrict__ out)
{
    __shared__ float in_s[16][18 * 19];
    __shared__ float w2_s[2][128 * 9];
    int b = blockIdx.y;
    int tile = blockIdx.x;
    int y0 = (tile / 6) * 16, x0 = (tile % 6) * 16;
    int t = threadIdx.x;
    int r = t >> 4, c = t & 15;
    for (int f = t; f < 2 * 128 * 9; f += 256) w2_s[f / 1152][f % 1152] = W2[f];
    float acc0 = 0.f, acc1 = 0.f;
    const bf16* hb = hmid + (size_t)b * C1O * HW_;
    for (int ic0 = 0; ic0 < 128; ic0 += 16) {
        __syncthreads();
        for (int f = t; f < 16 * 18 * 18; f += 256) {
            int ic = f / 324; int rem = f % 324; int row = rem / 18, col = rem % 18;
            int gy = y0 - 1 + row, gxx = x0 - 1 + col;
            float v = 0.f;
            if (gy >= 0 && gy < H_ && gxx >= 0 && gxx < W_)
                v = __bfloat162float(hb[(size_t)(ic0 + ic) * HW_ + gy * W_ + gxx]);
            in_s[ic][row * 19 + col] = v;
        }
        __syncthreads();
        for (int ic = 0; ic < 16; ic++) {
            #pragma unroll
            for (int ky = 0; ky < 3; ky++) {
                #pragma unroll
                for (int kx = 0; kx < 3; kx++) {
                    float x = in_s[ic][(r + ky) * 19 + c + kx];
                    int wk = (ic0 + ic) * 9 + ky * 3 + kx;
                    acc0 += x * w2_s[0][wk];
                    acc1 += x * w2_s[1][wk];
                }
            }
        }
    }
    int py = (y0 + r) * W_ + x0 + c;
    out[((size_t)b * 2 + 0) * HW_ + py] = acc0 + b2[0];
    out[((size_t)b * 2 + 1) * HW_ + py] = acc1 + b2[1];
}

// ---------------------------------------------------------------- launch ----
extern "C" void kernel_launch(void* const* d_in, const int* in_sizes, int n_in,
                              void* d_out, int out_size, void* d_ws, size_t ws_size,
                              hipStream_t stream)
{
    const float* cur_embed  = (const float*)d_in[0];
    const float* cur_decode = (const float*)d_in[1];
    const float* init_embed = (const float*)d_in[2];
    const float* init_seg   = (const float*)d_in[3];
    const float* prev_embed = (const float*)d_in[4];
    const float* prev_seg   = (const float*)d_in[5];
    const float* W1 = (const float*)d_in[6];
    const float* b1 = (const float*)d_in[7];
    const float* W2 = (const float*)d_in[8];
    const float* b2 = (const float*)d_in[9];
    float* out = (float*)d_out;

    char* ws = (char*)d_ws;
    bf16* hcat8 = (bf16*)ws;                          // [8][8][9604][32]
    bf16* curbf = (bf16*)ws;                          // alias (dead at memset)
    bf16* hcat1 = (bf16*)(ws + 39337984);             // [8][9604][8]
    const size_t HCAT_REGION = 40567296;
    bf16* hmid   = (bf16*)(ws + HCAT_REGION);
    bf16* fibf   = (bf16*)(ws + HCAT_REGION);         // phase-1 alias
    bf16* prevbf = (bf16*)(ws + HCAT_REGION);         // phase-2 alias (4 batches)
    float* si  = (float*)(ws + HCAT_REGION + 2621440);
    bf16* w1bf = (bf16*)(ws + 59441664);              // 82 slabs
    float* gout = (float*)(ws + 60113408);
    float* lout = (float*)(ws + 60703232);

    { int total = 82 * 128 * 32;
      w1cvt_kernel<<<(total + 255) / 256, 256, 0, stream>>>(W1, w1bf); }
    { dim3 g(144, 4, B_);
      tcur_kernel<<<g, 256, 0, stream>>>(cur_embed, curbf); }
    { int total = B_ * (C_ + 2) * KPP;
      pool_kernel<<<(total + 255) / 256, 256, 0, stream>>>(init_embed, init_seg, fibf, si); }
    { gmap_mfma<<<576, 256, 0, stream>>>(curbf, fibf, si, gout); }
    for (int g = 0; g < 2; g++) {
        dim3 gt(144, 4, 4);
        tcur_kernel<<<gt, 256, 0, stream>>>(prev_embed + (size_t)g * 4 * C_ * HW_, prevbf);
        dim3 gl(144, 4);
        lmap_mfma<<<gl, 256, 0, stream>>>(curbf, prevbf, prev_seg, lout, g * 4);
    }
    hipMemsetAsync(ws, 0, HCAT_REGION, stream);       // zero hcat8+hcat1; curbf dead
    { dim3 g(144, 4, B_);
      pack_dec_kernel<<<g, 256, 0, stream>>>(cur_decode, hcat8); }
    { int total = B_ * HW_;
      pack_small_kernel<<<(total + 255) / 256, 256, 0, stream>>>(gout, lout, init_seg, prev_seg, hcat1); }
    { conv1_mfma<<<576, 256, 0, stream>>>(hcat8, hcat1, w1bf, b1, hmid); }
    { dim3 g(36, B_);
      conv2_kernel<<<g, 256, 0, stream>>>(hmid, W2, b2, out); }
}

// Round 12
// 322.395 us; speedup vs baseline: 2.3080x; 1.1164x over previous
//
#include <hip/hip_runtime.h>
#include <hip/hip_bf16.h>

// Round 12: conv2 -> MFMA implicit GEMM on the conv1 template (16oc_pad x 128px,
//           BK=64 x 18 steps, single-buffer LDS, 1 batch/XCD); conv1 epilogue
//           now writes hmid as padded NHWC [B][98][98][128] (contiguous stores).
// ws layout (62.12 MB, aliased; proven budget 62.56 MB):
//   [0, 39,337,984)           hcat8 bf16 [8][8][9604][32]   -- ALSO curbf bf16 [8][9216][256] (dead at memset)
//   [39,337,984, 40,567,296)  hcat1 bf16 [8][9604][8]
//   [40,567,296, 60,236,288)  hmid_pad bf16 [8][9604][128]
//       -- phase1 alias: fibf bf16 [8][640][256] @ +0, si f32 [8][2][640] @ +2,621,440
//       -- phase2 alias: prevbf bf16 [4][9216][256]
//   [60,236,288, 60,908,032)  W1bf bf16 [82][128][32]  (slab s = icc*9+tap; slab 81 zeros)
//   [60,908,032, 60,944,896)  W2bf bf16 [18][16][64]   (s = tap*2+half; oc>=2 zeros)
//   [60,944,896, 61,534,720)  gout f32 [8][2][9216]
//   [61,534,720, 62,124,544)  lout f32 [8][2][9216]

typedef __hip_bfloat16 bf16;
typedef __attribute__((ext_vector_type(8))) short short8;
typedef __attribute__((ext_vector_type(4))) float f32x4;

constexpr int B_  = 8;
constexpr int C_  = 256;
constexpr int H_  = 96;
constexpr int W_  = 96;
constexpr int HW_ = H_ * W_;       // 9216
constexpr int PW_ = 24;
constexpr int KP_ = 576;
constexpr int KPP = 640;
constexpr int HP_ = 98;
constexpr int HPW = HP_ * HP_;     // 9604
constexpr int C1O = 128;
constexpr int CHK = HPW * 32;      // per 32-ch chunk

__device__ __forceinline__ unsigned short bfb(float f) {
    bf16 h = __float2bfloat16(f);
    return *reinterpret_cast<unsigned short*>(&h);
}

__device__ __forceinline__ void gload_lds16(const bf16* g, bf16* l) {
    __builtin_amdgcn_global_load_lds((const void*)g, (void*)l, 16, 0, 0);
}

// ------------------------------------------------------------ W1 convert ----
__global__ __launch_bounds__(256)
void w1cvt_kernel(const float* __restrict__ W1, bf16* __restrict__ w1bf)
{
    int idx = blockIdx.x * 256 + threadIdx.x;
    if (idx >= 82 * 128 * 32) return;
    int ic = idx & 31;
    int oc = (idx >> 5) & 127;
    int ks = idx >> 12;
    int icc = ks / 9, tap = ks % 9;
    int icg = icc * 32 + ic;
    float v = (icg < 264) ? W1[((size_t)oc * 264 + icg) * 9 + tap] : 0.f;
    w1bf[idx] = __float2bfloat16(v);
}

// ------------------------------------------------------------ W2 convert ----
// W2bf[s=tap*2+half][16 oc][64 ch]; oc>=2 -> 0
__global__ __launch_bounds__(256)
void w2cvt_kernel(const float* __restrict__ W2, bf16* __restrict__ w2bf)
{
    int idx = blockIdx.x * 256 + threadIdx.x;
    if (idx >= 18 * 16 * 64) return;
    int c  = idx & 63;
    int oc = (idx >> 6) & 15;
    int s  = idx >> 10;
    int tap = s >> 1, half = s & 1;
    float v = (oc < 2) ? W2[((size_t)oc * 128 + half * 64 + c) * 9 + tap] : 0.f;
    w2bf[idx] = __float2bfloat16(v);
}

// ------------------------------------------------------- NCHW->NHWC bf16 ----
__global__ __launch_bounds__(256)
void tcur_kernel(const float* __restrict__ cur, bf16* __restrict__ curbf)
{
    __shared__ float tile[64][68];
    int b = blockIdx.z, c0 = blockIdx.y * 64, p0 = blockIdx.x * 64;
    int t = threadIdx.x;
    const float* src = cur + ((size_t)b * C_ + c0) * HW_ + p0;
    #pragma unroll
    for (int it = 0; it < 4; it++) {
        int f = t + it * 256;
        int cl = f >> 4, p4 = (f & 15) * 4;
        float4 v = *reinterpret_cast<const float4*>(src + (size_t)cl * HW_ + p4);
        *reinterpret_cast<float4*>(&tile[cl][p4]) = v;
    }
    __syncthreads();
    bf16* dst = curbf + ((size_t)b * HW_ + p0) * 256 + c0;
    #pragma unroll
    for (int it = 0; it < 4; it++) {
        int f = t + it * 256;
        int pl = f >> 4, c4 = (f & 15) * 4;
        ushort4 u;
        u.x = bfb(tile[c4 + 0][pl]); u.y = bfb(tile[c4 + 1][pl]);
        u.z = bfb(tile[c4 + 2][pl]); u.w = bfb(tile[c4 + 3][pl]);
        *reinterpret_cast<ushort4*>(dst + (size_t)pl * 256 + c4) = u;
    }
}

// ---------------------------------------------------------------- pool ----
__global__ __launch_bounds__(256)
void pool_kernel(const float* __restrict__ init_embed,
                 const float* __restrict__ init_seg,
                 bf16* __restrict__ fibf, float* __restrict__ si)
{
    int idx = blockIdx.x * 256 + threadIdx.x;
    int total = B_ * (C_ + 2) * KPP;
    if (idx >= total) return;
    int k  = idx % KPP;
    int ch = (idx / KPP) % (C_ + 2);
    int b  = idx / (KPP * (C_ + 2));
    float s = 0.f;
    if (k < KP_) {
        int ph = k / PW_, pw = k % PW_;
        const float* src = (ch < C_)
            ? (init_embed + (((size_t)b * C_ + ch) * H_ + ph * 4) * W_ + pw * 4)
            : (init_seg   + (((size_t)b * 2 + (ch - C_)) * H_ + ph * 4) * W_ + pw * 4);
        #pragma unroll
        for (int r = 0; r < 4; r++) {
            float4 v = *reinterpret_cast<const float4*>(src + r * W_);
            s += v.x + v.y + v.z + v.w;
        }
        s *= (1.f / 16.f);
    }
    if (ch < C_) fibf[((size_t)b * KPP + k) * C_ + ch] = __float2bfloat16(s);
    else         si[(size_t)b * 2 * KPP + (ch - C_) * KPP + k] = s;
}

// ---------------------------------------------------------------- gmap ----
__global__ __launch_bounds__(256)
void gmap_mfma(const bf16* __restrict__ curbf, const bf16* __restrict__ fibf,
               const float* __restrict__ si, float* __restrict__ gout)
{
    __shared__ bf16 Abuf[8192];
    __shared__ bf16 Bbuf[8192];
    __shared__ float bred[2][2][2][64];
    int gid = blockIdx.x;             // 576 = 8 b x 72 px-tiles
    int b = gid & 7;
    int p0 = (gid >> 3) * 128;
    int tid = threadIdx.x, lane = tid & 63;
    int w = tid >> 6, wm = w & 1, wn = w >> 1;
    int l15 = lane & 15, lk = lane >> 4;
    const bf16* fb = fibf + (size_t)b * KPP * 256;
    const bf16* cb = curbf + (size_t)b * HW_ * 256;
    const float* sib = si + (size_t)b * 2 * KPP;

    int wbase = tid & 192;
    int t3 = (tid >> 3) & 7;
    int cX = (tid & 7) ^ t3;
    int r0 = tid >> 3;
    int swzE0 = ((lk) ^ (l15 & 7)) * 8;
    int swzE1 = ((4 + lk) ^ (l15 & 7)) * 8;

    float best[2][4];
    #pragma unroll
    for (int s = 0; s < 2; s++)
        #pragma unroll
        for (int nt = 0; nt < 4; nt++) best[s][nt] = -INFINITY;
    f32x4 acc[4][4] = {};

    auto STAGE = [&](int q) {
        int chunk = q >> 2, ks = q & 3;
        int koff = ks * 64 + cX * 8;
        #pragma unroll
        for (int i = 0; i < 4; i++) {
            int row = i * 32 + r0;
            gload_lds16(fb + (size_t)(chunk * 128 + row) * 256 + koff,
                        &Abuf[(size_t)(i * 256 + wbase) * 8]);
            gload_lds16(cb + (size_t)(p0 + row) * 256 + koff,
                        &Bbuf[(size_t)(i * 256 + wbase) * 8]);
        }
    };

    auto COMPUTE = [&]() {
        #pragma unroll
        for (int k = 0; k < 2; k++) {
            int swz = k ? swzE1 : swzE0;
            short8 a[4], bq[4];
            #pragma unroll
            for (int mt = 0; mt < 4; mt++)
                a[mt] = *reinterpret_cast<const short8*>(
                    &Abuf[(size_t)(wm * 64 + mt * 16 + l15) * 64 + swz]);
            #pragma unroll
            for (int nt = 0; nt < 4; nt++)
                bq[nt] = *reinterpret_cast<const short8*>(
                    &Bbuf[(size_t)(wn * 64 + nt * 16 + l15) * 64 + swz]);
            #pragma unroll
            for (int mt = 0; mt < 4; mt++)
                #pragma unroll
                for (int nt = 0; nt < 4; nt++)
                    acc[mt][nt] = __builtin_amdgcn_mfma_f32_16x16x32_bf16(
                        a[mt], bq[nt], acc[mt][nt], 0, 0, 0);
        }
    };

    for (int q = 0; q < 20; ++q) {
        STAGE(q);
        __syncthreads();
        COMPUTE();
        if ((q & 3) == 3) {
            int kp0 = (q >> 2) * 128;
            #pragma unroll
            for (int mt = 0; mt < 4; mt++) {
                int rb = kp0 + wm * 64 + mt * 16 + lk * 4;
                float4 s0 = *reinterpret_cast<const float4*>(sib + rb);
                float4 s1 = *reinterpret_cast<const float4*>(sib + KPP + rb);
                const float* s0p = reinterpret_cast<const float*>(&s0);
                const float* s1p = reinterpret_cast<const float*>(&s1);
                #pragma unroll
                for (int nt = 0; nt < 4; nt++) {
                    #pragma unroll
                    for (int r = 0; r < 4; r++) {
                        float v = acc[mt][nt][r];
                        best[0][nt] = fmaxf(best[0][nt], v * s0p[r]);
                        best[1][nt] = fmaxf(best[1][nt], v * s1p[r]);
                    }
                    acc[mt][nt] = (f32x4){0.f, 0.f, 0.f, 0.f};
                }
            }
        }
        __syncthreads();
    }
    #pragma unroll
    for (int s = 0; s < 2; s++)
        #pragma unroll
        for (int nt = 0; nt < 4; nt++) {
            float v = best[s][nt];
            v = fmaxf(v, __shfl_xor(v, 16));
            v = fmaxf(v, __shfl_xor(v, 32));
            if (lk == 0) bred[wm][wn][s][nt * 16 + l15] = v;
        }
    __syncthreads();
    {
        int wn2 = tid >> 7, s2 = (tid >> 6) & 1, pxl = tid & 63;
        float v = fmaxf(bred[0][wn2][s2][pxl], bred[1][wn2][s2][pxl]);
        gout[((size_t)b * 2 + s2) * HW_ + p0 + wn2 * 64 + pxl] = v;
    }
}

// ---------------------------------------------------------------- lmap ----
__global__ __launch_bounds__(256)
void lmap_mfma(const bf16* __restrict__ curbf, const bf16* __restrict__ prevbf,
               const float* __restrict__ prev_seg, float* __restrict__ lout, int b0)
{
    constexpr int GSTR = 257;
    constexpr int SEGB = 64 * GSTR;
    constexpr int REDB = SEGB + 512;
    __shared__ float gl[REDB + 256];
    int b = b0 + blockIdx.y;
    const bf16* pb = prevbf + (size_t)blockIdx.y * HW_ * 256;
    const bf16* cb = curbf + (size_t)b * HW_ * 256;
    int tile = blockIdx.x;
    int ty0 = (tile / 12) * 8, tx0 = (tile % 12) * 8;
    int t = threadIdx.x, lane = t & 63, wq = t >> 6;
    int l15 = lane & 15, lk = lane >> 4;

    size_t aoff[4];
    #pragma unroll
    for (int mt = 0; mt < 4; mt++) {
        int m = mt * 16 + l15;
        int gpx = (ty0 + (m >> 3)) * W_ + tx0 + (m & 7);
        aoff[mt] = (size_t)gpx * 256 + lk * 8;
    }
    bool pred[4];
    size_t boff[4];
    int gx = tx0 - 4 + l15;
    bool colok = (gx >= 0) && (gx < W_);
    #pragma unroll
    for (int nt = 0; nt < 4; nt++) {
        int gy = ty0 - 4 + wq * 4 + nt;
        pred[nt] = colok && (gy >= 0) && (gy < H_);
        boff[nt] = pred[nt] ? ((size_t)(gy * W_ + gx) * 256 + lk * 8) : 0;
    }

    f32x4 acc[4][4] = {};
    const short8 Z8 = {0, 0, 0, 0, 0, 0, 0, 0};
    for (int kc = 0; kc < 8; kc++) {
        short8 a[4], bb[4];
        #pragma unroll
        for (int mt = 0; mt < 4; mt++)
            a[mt] = *reinterpret_cast<const short8*>(cb + aoff[mt] + kc * 32);
        #pragma unroll
        for (int nt = 0; nt < 4; nt++) {
            short8 v = Z8;
            if (pred[nt]) v = *reinterpret_cast<const short8*>(pb + boff[nt] + kc * 32);
            bb[nt] = v;
        }
        #pragma unroll
        for (int mt = 0; mt < 4; mt++)
            #pragma unroll
            for (int nt = 0; nt < 4; nt++)
                acc[mt][nt] = __builtin_amdgcn_mfma_f32_16x16x32_bf16(
                    a[mt], bb[nt], acc[mt][nt], 0, 0, 0);
    }
    #pragma unroll
    for (int mt = 0; mt < 4; mt++)
        #pragma unroll
        for (int nt = 0; nt < 4; nt++)
            #pragma unroll
            for (int r = 0; r < 4; r++)
                gl[(mt * 16 + lk * 4 + r) * GSTR + wq * 64 + nt * 16 + l15] = acc[mt][nt][r];
    #pragma unroll
    for (int it = 0; it < 2; it++) {
        int f = t + it * 256;
        int s = f >> 8, wp = f & 255;
        int wy = wp >> 4, wx = wp & 15;
        int gy = ty0 - 4 + wy, gxx = tx0 - 4 + wx;
        float v = 0.f;
        if (gy >= 0 && gy < H_ && gxx >= 0 && gxx < W_)
            v = prev_seg[((size_t)b * 2 + s) * HW_ + gy * W_ + gxx] * (1.f / 256.f);
        gl[SEGB + f] = v;
    }
    __syncthreads();
    {
        int m = t & 63;
        int sh = t >> 6;
        int s = sh >> 1, hh = sh & 1;
        int py = m >> 3, lx = m & 7;
        const float* gr = gl + m * GSTR;
        const float* sr = gl + SEGB + s * 256;
        float mx = -INFINITY;
        int wr0 = hh * 5, wr1 = hh ? 9 : 5;
        for (int wr = wr0; wr < wr1; ++wr) {
            int base = (py + wr) * 16 + lx;
            #pragma unroll
            for (int wc = 0; wc < 9; ++wc)
                mx = fmaxf(mx, gr[base + wc] * sr[base + wc]);
        }
        gl[REDB + sh * 64 + m] = mx;
    }
    __syncthreads();
    if (t < 128) {
        int s = t >> 6, m = t & 63;
        float v = fmaxf(gl[REDB + (s * 2 + 0) * 64 + m], gl[REDB + (s * 2 + 1) * 64 + m]);
        int gpx = (ty0 + (m >> 3)) * W_ + tx0 + (m & 7);
        lout[((size_t)b * 2 + s) * HW_ + gpx] = v;
    }
}

// ---------------------------------------------------------------- packs ----
__global__ __launch_bounds__(256)
void pack_dec_kernel(const float* __restrict__ dec, bf16* __restrict__ hcat8)
{
    __shared__ float tile[64][68];
    int b = blockIdx.z, c0 = blockIdx.y * 64, p0 = blockIdx.x * 64;
    int t = threadIdx.x;
    const float* src = dec + ((size_t)b * C_ + c0) * HW_ + p0;
    #pragma unroll
    for (int it = 0; it < 4; it++) {
        int f = t + it * 256;
        int cl = f >> 4, p4 = (f & 15) * 4;
        float4 v = *reinterpret_cast<const float4*>(src + (size_t)cl * HW_ + p4);
        *reinterpret_cast<float4*>(&tile[cl][p4]) = v;
    }
    __syncthreads();
    #pragma unroll
    for (int it = 0; it < 4; it++) {
        int f = t + it * 256;
        int pl = f >> 4, c4 = (f & 15) * 4;
        int p = p0 + pl;
        int y = p / 96, x = p % 96;
        int pos = (y + 1) * HP_ + x + 1;
        int ch = c0 + c4;
        ushort4 u;
        u.x = bfb(tile[c4 + 0][pl]); u.y = bfb(tile[c4 + 1][pl]);
        u.z = bfb(tile[c4 + 2][pl]); u.w = bfb(tile[c4 + 3][pl]);
        bf16* dst = hcat8 + ((size_t)b * 8 + (ch >> 5)) * CHK + (size_t)pos * 32 + (ch & 31);
        *reinterpret_cast<ushort4*>(dst) = u;
    }
}

__global__ __launch_bounds__(256)
void pack_small_kernel(const float* __restrict__ gout,
                       const float* __restrict__ lout,
                       const float* __restrict__ init_seg,
                       const float* __restrict__ prev_seg,
                       bf16* __restrict__ hcat1)
{
    int idx = blockIdx.x * 256 + threadIdx.x;
    if (idx >= B_ * HW_) return;
    int b = idx / HW_, p = idx % HW_;
    int y = p / 96, x = p % 96;
    int pos = (y + 1) * HP_ + x + 1;
    bf16* dst = hcat1 + ((size_t)b * HPW + pos) * 8;
    float g0 = gout[((size_t)b * 2 + 0) * HW_ + p];
    float g1 = gout[((size_t)b * 2 + 1) * HW_ + p];
    float i0 = init_seg[((size_t)b * 2 + 0) * HW_ + p];
    float i1 = init_seg[((size_t)b * 2 + 1) * HW_ + p];
    float l0 = lout[((size_t)b * 2 + 0) * HW_ + p];
    float l1 = lout[((size_t)b * 2 + 1) * HW_ + p];
    float q0 = prev_seg[((size_t)b * 2 + 0) * HW_ + p];
    float q1 = prev_seg[((size_t)b * 2 + 1) * HW_ + p];
    ushort4 u; u.x = bfb(g0); u.y = bfb(g1); u.z = bfb(i0); u.w = bfb(i1);
    *reinterpret_cast<ushort4*>(dst) = u;
    ushort4 u2; u2.x = bfb(l0); u2.y = bfb(l1); u2.z = bfb(q0); u2.w = bfb(q1);
    *reinterpret_cast<ushort4*>(dst + 4) = u2;
}

// ---------------------------------------------------------------- conv1 ----
// 128oc x 128px tile, 4 waves, BK=64, single-buffered 32KB LDS, 2 barriers/step.
// Epilogue writes padded-NHWC hmid [B][9604][128].
__global__ __launch_bounds__(256)
void conv1_mfma(const bf16* __restrict__ hcat8, const bf16* __restrict__ hcat1,
                const bf16* __restrict__ w1bf, const float* __restrict__ b1,
                bf16* __restrict__ hmidp)
{
    __shared__ bf16 Abuf[8192];
    __shared__ bf16 Bbuf[8192];
    int gid = blockIdx.x;             // 576 = 8 b x 72 px-tiles
    int b = gid & 7;
    int p0 = (gid >> 3) * 128;
    int tid = threadIdx.x, lane = tid & 63;
    int w = tid >> 6, wm = w & 1, wn = w >> 1;
    int l15 = lane & 15, lk = lane >> 4;
    const bf16* hb8 = hcat8 + (size_t)b * 8 * CHK;
    const bf16* hb1 = hcat1 + (size_t)b * HPW * 8;

    int wbase = tid & 192;
    int t3 = (tid >> 3) & 7;
    int cX = (tid & 7) ^ t3;
    int selX = cX >> 2;
    int cin8 = (cX & 3) * 8;
    int r0 = tid >> 3;
    int posB[4];
    #pragma unroll
    for (int i = 0; i < 4; i++) {
        int px = p0 + i * 32 + r0;
        posB[i] = (px / 96) * HP_ + (px % 96);
    }
    int swzE0 = ((lk) ^ (l15 & 7)) * 8;
    int swzE1 = ((4 + lk) ^ (l15 & 7)) * 8;

    f32x4 acc[4][4] = {};

    auto STAGE = [&](int p) {
        int s0 = 2 * p, s1 = s0 + 1;
        int icc0 = s0 / 9, tap0 = s0 - icc0 * 9;
        int icc1 = s1 / 9, tap1 = s1 - icc1 * 9;
        int toff0 = (tap0 / 3) * HP_ + (tap0 % 3);
        int toff1 = (tap1 / 3) * HP_ + (tap1 % 3);
        const bf16* gA = w1bf + (size_t)p * 8192 + (size_t)selX * 4096 + cin8;
        #pragma unroll
        for (int i = 0; i < 4; i++)
            gload_lds16(gA + (i * 32 + r0) * 32,
                        &Abuf[(size_t)(i * 256 + wbase) * 8]);
        int toffS = selX ? toff1 : toff0;
        int iccS  = selX ? icc1 : icc0;
        bool is8 = (iccS >= 8);
        const bf16* gb = is8 ? hb1 : (hb8 + (size_t)iccS * CHK);
        #pragma unroll
        for (int i = 0; i < 4; i++) {
            const bf16* g = is8 ? (gb + (size_t)(posB[i] + toffS) * 8)
                                : (gb + (size_t)(posB[i] + toffS) * 32 + cin8);
            gload_lds16(g, &Bbuf[(size_t)(i * 256 + wbase) * 8]);
        }
    };

    auto COMPUTE = [&]() {
        #pragma unroll
        for (int k = 0; k < 2; k++) {
            int swz = k ? swzE1 : swzE0;
            short8 a[4], bq[4];
            #pragma unroll
            for (int mt = 0; mt < 4; mt++)
                a[mt] = *reinterpret_cast<const short8*>(
                    &Abuf[(size_t)(wm * 64 + mt * 16 + l15) * 64 + swz]);
            #pragma unroll
            for (int nt = 0; nt < 4; nt++)
                bq[nt] = *reinterpret_cast<const short8*>(
                    &Bbuf[(size_t)(wn * 64 + nt * 16 + l15) * 64 + swz]);
            #pragma unroll
            for (int mt = 0; mt < 4; mt++)
                #pragma unroll
                for (int nt = 0; nt < 4; nt++)
                    acc[mt][nt] = __builtin_amdgcn_mfma_f32_16x16x32_bf16(
                        a[mt], bq[nt], acc[mt][nt], 0, 0, 0);
        }
    };

    for (int p = 0; p < 41; ++p) {
        STAGE(p);
        __syncthreads();
        COMPUTE();
        __syncthreads();
    }

    bf16* hm = hmidp + (size_t)b * HPW * 128;
    #pragma unroll
    for (int nt = 0; nt < 4; nt++) {
        int px = p0 + wn * 64 + nt * 16 + l15;
        size_t pos = (size_t)((px / 96 + 1) * HP_ + (px % 96) + 1) * 128;
        #pragma unroll
        for (int mt = 0; mt < 4; mt++) {
            int ocb = wm * 64 + mt * 16 + lk * 4;
            float4 bias = *reinterpret_cast<const float4*>(b1 + ocb);
            const float* bp = reinterpret_cast<const float*>(&bias);
            ushort4 u;
            u.x = bfb(fmaxf(acc[mt][nt][0] + bp[0], 0.f));
            u.y = bfb(fmaxf(acc[mt][nt][1] + bp[1], 0.f));
            u.z = bfb(fmaxf(acc[mt][nt][2] + bp[2], 0.f));
            u.w = bfb(fmaxf(acc[mt][nt][3] + bp[3], 0.f));
            *reinterpret_cast<ushort4*>(hm + pos + ocb) = u;
        }
    }
}

// ---------------------------------------------------------------- conv2 ----
// Implicit GEMM on the conv1 template: D[16oc_pad][128px], K=1152 (9 taps x 128ch),
// 18 BK=64 steps, single-buffer LDS, 1 batch/XCD.
__global__ __launch_bounds__(256)
void conv2_mfma(const bf16* __restrict__ hmidp, const bf16* __restrict__ w2bf,
                const float* __restrict__ b2, float* __restrict__ out)
{
    __shared__ bf16 Abuf[1024];       // [16 oc][64]   2 KB
    __shared__ bf16 Bbuf[8192];       // [128 px][64] 16 KB
    int gid = blockIdx.x;             // 576 = 8 b x 72 px-tiles
    int b = gid & 7;
    int p0 = (gid >> 3) * 128;
    int tid = threadIdx.x, lane = tid & 63;
    int wn = tid >> 6;                // wave owns 32 px (2 nt)
    int l15 = lane & 15, lk = lane >> 4;
    const bf16* hb = hmidp + (size_t)b * HPW * 128;

    int wbase = tid & 192;
    int t3 = (tid >> 3) & 7;
    int cX = (tid & 7) ^ t3;
    int r0 = tid >> 3;
    int posB[4];
    #pragma unroll
    for (int i = 0; i < 4; i++) {
        int px = p0 + i * 32 + r0;
        posB[i] = (px / 96) * HP_ + (px % 96);
    }
    int swzE0 = ((lk) ^ (l15 & 7)) * 8;
    int swzE1 = ((4 + lk) ^ (l15 & 7)) * 8;

    f32x4 acc[2] = {};

    auto STAGE = [&](int s) {
        int tap = s >> 1, half = s & 1;
        int toff = (tap / 3) * HP_ + (tap % 3);
        if (tid < 128)    // A: 16 rows x 8 chunks (waves 0,1)
            gload_lds16(w2bf + ((size_t)s * 16 + r0) * 64 + cX * 8,
                        &Abuf[(size_t)(tid & 192) * 8]);
        #pragma unroll
        for (int i = 0; i < 4; i++)
            gload_lds16(hb + (size_t)(posB[i] + toff) * 128 + half * 64 + cX * 8,
                        &Bbuf[(size_t)(i * 256 + wbase) * 8]);
    };

    auto COMPUTE = [&]() {
        #pragma unroll
        for (int k = 0; k < 2; k++) {
            int swz = k ? swzE1 : swzE0;
            short8 a = *reinterpret_cast<const short8*>(&Abuf[(size_t)l15 * 64 + swz]);
            #pragma unroll
            for (int nt = 0; nt < 2; nt++) {
                short8 bq = *reinterpret_cast<const short8*>(
                    &Bbuf[(size_t)(wn * 32 + nt * 16 + l15) * 64 + swz]);
                acc[nt] = __builtin_amdgcn_mfma_f32_16x16x32_bf16(a, bq, acc[nt], 0, 0, 0);
            }
        }
    };

    for (int s = 0; s < 18; ++s) {
        STAGE(s);
        __syncthreads();
        COMPUTE();
        __syncthreads();
    }

    if (lk == 0) {                    // rows 0..3; only 0,1 real
        float bb0 = b2[0], bb1 = b2[1];
        #pragma unroll
        for (int nt = 0; nt < 2; nt++) {
            int px = p0 + wn * 32 + nt * 16 + l15;
            out[((size_t)b * 2 + 0) * HW_ + px] = acc[nt][0] + bb0;
            out[((size_t)b * 2 + 1) * HW_ + px] = acc[nt][1] + bb1;
        }
    }
}

// ---------------------------------------------------------------- launch ----
extern "C" void kernel_launch(void* const* d_in, const int* in_sizes, int n_in,
                              void* d_out, int out_size, void* d_ws, size_t ws_size,
                              hipStream_t stream)
{
    const float* cur_embed  = (const float*)d_in[0];
    const float* cur_decode = (const float*)d_in[1];
    const float* init_embed = (const float*)d_in[2];
    const float* init_seg   = (const float*)d_in[3];
    const float* prev_embed = (const float*)d_in[4];
    const float* prev_seg   = (const float*)d_in[5];
    const float* W1 = (const float*)d_in[6];
    const float* b1 = (const float*)d_in[7];
    const float* W2 = (const float*)d_in[8];
    const float* b2 = (const float*)d_in[9];
    float* out = (float*)d_out;

    char* ws = (char*)d_ws;
    bf16* hcat8 = (bf16*)ws;                          // [8][8][9604][32]
    bf16* curbf = (bf16*)ws;                          // alias (dead at memset)
    bf16* hcat1 = (bf16*)(ws + 39337984);             // [8][9604][8]
    const size_t HCAT_REGION = 40567296;
    const size_t HMID_SIZE   = 19668992;              // 8*9604*128*2
    bf16* hmidp  = (bf16*)(ws + HCAT_REGION);         // [8][9604][128] padded NHWC
    bf16* fibf   = (bf16*)(ws + HCAT_REGION);         // phase-1 alias
    bf16* prevbf = (bf16*)(ws + HCAT_REGION);         // phase-2 alias (4 batches)
    float* si  = (float*)(ws + HCAT_REGION + 2621440);
    bf16* w1bf = (bf16*)(ws + 60236288);
    bf16* w2bf = (bf16*)(ws + 60908032);
    float* gout = (float*)(ws + 60944896);
    float* lout = (float*)(ws + 61534720);

    { int total = 82 * 128 * 32;
      w1cvt_kernel<<<(total + 255) / 256, 256, 0, stream>>>(W1, w1bf); }
    { int total = 18 * 16 * 64;
      w2cvt_kernel<<<(total + 255) / 256, 256, 0, stream>>>(W2, w2bf); }
    { dim3 g(144, 4, B_);
      tcur_kernel<<<g, 256, 0, stream>>>(cur_embed, curbf); }
    { int total = B_ * (C_ + 2) * KPP;
      pool_kernel<<<(total + 255) / 256, 256, 0, stream>>>(init_embed, init_seg, fibf, si); }
    { gmap_mfma<<<576, 256, 0, stream>>>(curbf, fibf, si, gout); }
    for (int g = 0; g < 2; g++) {
        dim3 gt(144, 4, 4);
        tcur_kernel<<<gt, 256, 0, stream>>>(prev_embed + (size_t)g * 4 * C_ * HW_, prevbf);
        dim3 gl(144, 4);
        lmap_mfma<<<gl, 256, 0, stream>>>(curbf, prevbf, prev_seg, lout, g * 4);
    }
    // zero hcat8+hcat1+hmid_pad (borders); curbf/fibf/prevbf dead by here
    hipMemsetAsync(ws, 0, HCAT_REGION + HMID_SIZE, stream);
    { dim3 g(144, 4, B_);
      pack_dec_kernel<<<g, 256, 0, stream>>>(cur_decode, hcat8); }
    { int total = B_ * HW_;
      pack_small_kernel<<<(total + 255) / 256, 256, 0, stream>>>(gout, lout, init_seg, prev_seg, hcat1); }
    { conv1_mfma<<<576, 256, 0, stream>>>(hcat8, hcat1, w1bf, b1, hmidp); }
    { conv2_mfma<<<576, 256, 0, stream>>>(hmidp, w2bf, b2, out); }
}

// Round 13
// 287.731 us; speedup vs baseline: 2.5860x; 1.1205x over previous
//
#include <hip/hip_runtime.h>
#include <hip/hip_bf16.h>

// Round 13: conv1 retiled to row-aligned 128oc x 96px (grid 768 = 3.0 blocks/CU
//           balanced), 28KB single-buffer LDS, coalesced LDS-transposed epilogue.
//           All other kernels identical to r12 (passing).
// ws layout (62.12 MB, aliased):
//   [0, 39,337,984)           hcat8 bf16 [8][8][9604][32]   -- ALSO curbf bf16 [8][9216][256] (dead at memset)
//   [39,337,984, 40,567,296)  hcat1 bf16 [8][9604][8]
//   [40,567,296, 60,236,288)  hmid_pad bf16 [8][9604][128]
//       -- phase1 alias: fibf bf16 [8][640][256] @ +0, si f32 [8][2][640] @ +2,621,440
//       -- phase2 alias: prevbf bf16 [4][9216][256]
//   [60,236,288, 60,908,032)  W1bf bf16 [82][128][32]  (slab s = icc*9+tap; slab 81 zeros)
//   [60,908,032, 60,944,896)  W2bf bf16 [18][16][64]
//   [60,944,896, 61,534,720)  gout f32 [8][2][9216]
//   [61,534,720, 62,124,544)  lout f32 [8][2][9216]

typedef __hip_bfloat16 bf16;
typedef __attribute__((ext_vector_type(8))) short short8;
typedef __attribute__((ext_vector_type(4))) float f32x4;

constexpr int B_  = 8;
constexpr int C_  = 256;
constexpr int H_  = 96;
constexpr int W_  = 96;
constexpr int HW_ = H_ * W_;       // 9216
constexpr int PW_ = 24;
constexpr int KP_ = 576;
constexpr int KPP = 640;
constexpr int HP_ = 98;
constexpr int HPW = HP_ * HP_;     // 9604
constexpr int C1O = 128;
constexpr int CHK = HPW * 32;      // per 32-ch chunk

__device__ __forceinline__ unsigned short bfb(float f) {
    bf16 h = __float2bfloat16(f);
    return *reinterpret_cast<unsigned short*>(&h);
}

__device__ __forceinline__ void gload_lds16(const bf16* g, bf16* l) {
    __builtin_amdgcn_global_load_lds((const void*)g, (void*)l, 16, 0, 0);
}

// ------------------------------------------------------------ W1 convert ----
__global__ __launch_bounds__(256)
void w1cvt_kernel(const float* __restrict__ W1, bf16* __restrict__ w1bf)
{
    int idx = blockIdx.x * 256 + threadIdx.x;
    if (idx >= 82 * 128 * 32) return;
    int ic = idx & 31;
    int oc = (idx >> 5) & 127;
    int ks = idx >> 12;
    int icc = ks / 9, tap = ks % 9;
    int icg = icc * 32 + ic;
    float v = (icg < 264) ? W1[((size_t)oc * 264 + icg) * 9 + tap] : 0.f;
    w1bf[idx] = __float2bfloat16(v);
}

// ------------------------------------------------------------ W2 convert ----
__global__ __launch_bounds__(256)
void w2cvt_kernel(const float* __restrict__ W2, bf16* __restrict__ w2bf)
{
    int idx = blockIdx.x * 256 + threadIdx.x;
    if (idx >= 18 * 16 * 64) return;
    int c  = idx & 63;
    int oc = (idx >> 6) & 15;
    int s  = idx >> 10;
    int tap = s >> 1, half = s & 1;
    float v = (oc < 2) ? W2[((size_t)oc * 128 + half * 64 + c) * 9 + tap] : 0.f;
    w2bf[idx] = __float2bfloat16(v);
}

// ------------------------------------------------------- NCHW->NHWC bf16 ----
__global__ __launch_bounds__(256)
void tcur_kernel(const float* __restrict__ cur, bf16* __restrict__ curbf)
{
    __shared__ float tile[64][68];
    int b = blockIdx.z, c0 = blockIdx.y * 64, p0 = blockIdx.x * 64;
    int t = threadIdx.x;
    const float* src = cur + ((size_t)b * C_ + c0) * HW_ + p0;
    #pragma unroll
    for (int it = 0; it < 4; it++) {
        int f = t + it * 256;
        int cl = f >> 4, p4 = (f & 15) * 4;
        float4 v = *reinterpret_cast<const float4*>(src + (size_t)cl * HW_ + p4);
        *reinterpret_cast<float4*>(&tile[cl][p4]) = v;
    }
    __syncthreads();
    bf16* dst = curbf + ((size_t)b * HW_ + p0) * 256 + c0;
    #pragma unroll
    for (int it = 0; it < 4; it++) {
        int f = t + it * 256;
        int pl = f >> 4, c4 = (f & 15) * 4;
        ushort4 u;
        u.x = bfb(tile[c4 + 0][pl]); u.y = bfb(tile[c4 + 1][pl]);
        u.z = bfb(tile[c4 + 2][pl]); u.w = bfb(tile[c4 + 3][pl]);
        *reinterpret_cast<ushort4*>(dst + (size_t)pl * 256 + c4) = u;
    }
}

// ---------------------------------------------------------------- pool ----
__global__ __launch_bounds__(256)
void pool_kernel(const float* __restrict__ init_embed,
                 const float* __restrict__ init_seg,
                 bf16* __restrict__ fibf, float* __restrict__ si)
{
    int idx = blockIdx.x * 256 + threadIdx.x;
    int total = B_ * (C_ + 2) * KPP;
    if (idx >= total) return;
    int k  = idx % KPP;
    int ch = (idx / KPP) % (C_ + 2);
    int b  = idx / (KPP * (C_ + 2));
    float s = 0.f;
    if (k < KP_) {
        int ph = k / PW_, pw = k % PW_;
        const float* src = (ch < C_)
            ? (init_embed + (((size_t)b * C_ + ch) * H_ + ph * 4) * W_ + pw * 4)
            : (init_seg   + (((size_t)b * 2 + (ch - C_)) * H_ + ph * 4) * W_ + pw * 4);
        #pragma unroll
        for (int r = 0; r < 4; r++) {
            float4 v = *reinterpret_cast<const float4*>(src + r * W_);
            s += v.x + v.y + v.z + v.w;
        }
        s *= (1.f / 16.f);
    }
    if (ch < C_) fibf[((size_t)b * KPP + k) * C_ + ch] = __float2bfloat16(s);
    else         si[(size_t)b * 2 * KPP + (ch - C_) * KPP + k] = s;
}

// ---------------------------------------------------------------- gmap ----
__global__ __launch_bounds__(256)
void gmap_mfma(const bf16* __restrict__ curbf, const bf16* __restrict__ fibf,
               const float* __restrict__ si, float* __restrict__ gout)
{
    __shared__ bf16 Abuf[8192];
    __shared__ bf16 Bbuf[8192];
    __shared__ float bred[2][2][2][64];
    int gid = blockIdx.x;             // 576 = 8 b x 72 px-tiles
    int b = gid & 7;
    int p0 = (gid >> 3) * 128;
    int tid = threadIdx.x, lane = tid & 63;
    int w = tid >> 6, wm = w & 1, wn = w >> 1;
    int l15 = lane & 15, lk = lane >> 4;
    const bf16* fb = fibf + (size_t)b * KPP * 256;
    const bf16* cb = curbf + (size_t)b * HW_ * 256;
    const float* sib = si + (size_t)b * 2 * KPP;

    int wbase = tid & 192;
    int t3 = (tid >> 3) & 7;
    int cX = (tid & 7) ^ t3;
    int r0 = tid >> 3;
    int swzE0 = ((lk) ^ (l15 & 7)) * 8;
    int swzE1 = ((4 + lk) ^ (l15 & 7)) * 8;

    float best[2][4];
    #pragma unroll
    for (int s = 0; s < 2; s++)
        #pragma unroll
        for (int nt = 0; nt < 4; nt++) best[s][nt] = -INFINITY;
    f32x4 acc[4][4] = {};

    auto STAGE = [&](int q) {
        int chunk = q >> 2, ks = q & 3;
        int koff = ks * 64 + cX * 8;
        #pragma unroll
        for (int i = 0; i < 4; i++) {
            int row = i * 32 + r0;
            gload_lds16(fb + (size_t)(chunk * 128 + row) * 256 + koff,
                        &Abuf[(size_t)(i * 256 + wbase) * 8]);
            gload_lds16(cb + (size_t)(p0 + row) * 256 + koff,
                        &Bbuf[(size_t)(i * 256 + wbase) * 8]);
        }
    };

    auto COMPUTE = [&]() {
        #pragma unroll
        for (int k = 0; k < 2; k++) {
            int swz = k ? swzE1 : swzE0;
            short8 a[4], bq[4];
            #pragma unroll
            for (int mt = 0; mt < 4; mt++)
                a[mt] = *reinterpret_cast<const short8*>(
                    &Abuf[(size_t)(wm * 64 + mt * 16 + l15) * 64 + swz]);
            #pragma unroll
            for (int nt = 0; nt < 4; nt++)
                bq[nt] = *reinterpret_cast<const short8*>(
                    &Bbuf[(size_t)(wn * 64 + nt * 16 + l15) * 64 + swz]);
            #pragma unroll
            for (int mt = 0; mt < 4; mt++)
                #pragma unroll
                for (int nt = 0; nt < 4; nt++)
                    acc[mt][nt] = __builtin_amdgcn_mfma_f32_16x16x32_bf16(
                        a[mt], bq[nt], acc[mt][nt], 0, 0, 0);
        }
    };

    for (int q = 0; q < 20; ++q) {
        STAGE(q);
        __syncthreads();
        COMPUTE();
        if ((q & 3) == 3) {
            int kp0 = (q >> 2) * 128;
            #pragma unroll
            for (int mt = 0; mt < 4; mt++) {
                int rb = kp0 + wm * 64 + mt * 16 + lk * 4;
                float4 s0 = *reinterpret_cast<const float4*>(sib + rb);
                float4 s1 = *reinterpret_cast<const float4*>(sib + KPP + rb);
                const float* s0p = reinterpret_cast<const float*>(&s0);
                const float* s1p = reinterpret_cast<const float*>(&s1);
                #pragma unroll
                for (int nt = 0; nt < 4; nt++) {
                    #pragma unroll
                    for (int r = 0; r < 4; r++) {
                        float v = acc[mt][nt][r];
                        best[0][nt] = fmaxf(best[0][nt], v * s0p[r]);
                        best[1][nt] = fmaxf(best[1][nt], v * s1p[r]);
                    }
                    acc[mt][nt] = (f32x4){0.f, 0.f, 0.f, 0.f};
                }
            }
        }
        __syncthreads();
    }
    #pragma unroll
    for (int s = 0; s < 2; s++)
        #pragma unroll
        for (int nt = 0; nt < 4; nt++) {
            float v = best[s][nt];
            v = fmaxf(v, __shfl_xor(v, 16));
            v = fmaxf(v, __shfl_xor(v, 32));
            if (lk == 0) bred[wm][wn][s][nt * 16 + l15] = v;
        }
    __syncthreads();
    {
        int wn2 = tid >> 7, s2 = (tid >> 6) & 1, pxl = tid & 63;
        float v = fmaxf(bred[0][wn2][s2][pxl], bred[1][wn2][s2][pxl]);
        gout[((size_t)b * 2 + s2) * HW_ + p0 + wn2 * 64 + pxl] = v;
    }
}

// ---------------------------------------------------------------- lmap ----
__global__ __launch_bounds__(256)
void lmap_mfma(const bf16* __restrict__ curbf, const bf16* __restrict__ prevbf,
               const float* __restrict__ prev_seg, float* __restrict__ lout, int b0)
{
    constexpr int GSTR = 257;
    constexpr int SEGB = 64 * GSTR;
    constexpr int REDB = SEGB + 512;
    __shared__ float gl[REDB + 256];
    int b = b0 + blockIdx.y;
    const bf16* pb = prevbf + (size_t)blockIdx.y * HW_ * 256;
    const bf16* cb = curbf + (size_t)b * HW_ * 256;
    int tile = blockIdx.x;
    int ty0 = (tile / 12) * 8, tx0 = (tile % 12) * 8;
    int t = threadIdx.x, lane = t & 63, wq = t >> 6;
    int l15 = lane & 15, lk = lane >> 4;

    size_t aoff[4];
    #pragma unroll
    for (int mt = 0; mt < 4; mt++) {
        int m = mt * 16 + l15;
        int gpx = (ty0 + (m >> 3)) * W_ + tx0 + (m & 7);
        aoff[mt] = (size_t)gpx * 256 + lk * 8;
    }
    bool pred[4];
    size_t boff[4];
    int gx = tx0 - 4 + l15;
    bool colok = (gx >= 0) && (gx < W_);
    #pragma unroll
    for (int nt = 0; nt < 4; nt++) {
        int gy = ty0 - 4 + wq * 4 + nt;
        pred[nt] = colok && (gy >= 0) && (gy < H_);
        boff[nt] = pred[nt] ? ((size_t)(gy * W_ + gx) * 256 + lk * 8) : 0;
    }

    f32x4 acc[4][4] = {};
    const short8 Z8 = {0, 0, 0, 0, 0, 0, 0, 0};
    for (int kc = 0; kc < 8; kc++) {
        short8 a[4], bb[4];
        #pragma unroll
        for (int mt = 0; mt < 4; mt++)
            a[mt] = *reinterpret_cast<const short8*>(cb + aoff[mt] + kc * 32);
        #pragma unroll
        for (int nt = 0; nt < 4; nt++) {
            short8 v = Z8;
            if (pred[nt]) v = *reinterpret_cast<const short8*>(pb + boff[nt] + kc * 32);
            bb[nt] = v;
        }
        #pragma unroll
        for (int mt = 0; mt < 4; mt++)
            #pragma unroll
            for (int nt = 0; nt < 4; nt++)
                acc[mt][nt] = __builtin_amdgcn_mfma_f32_16x16x32_bf16(
                    a[mt], bb[nt], acc[mt][nt], 0, 0, 0);
    }
    #pragma unroll
    for (int mt = 0; mt < 4; mt++)
        #pragma unroll
        for (int nt = 0; nt < 4; nt++)
            #pragma unroll
            for (int r = 0; r < 4; r++)
                gl[(mt * 16 + lk * 4 + r) * GSTR + wq * 64 + nt * 16 + l15] = acc[mt][nt][r];
    #pragma unroll
    for (int it = 0; it < 2; it++) {
        int f = t + it * 256;
        int s = f >> 8, wp = f & 255;
        int wy = wp >> 4, wx = wp & 15;
        int gy = ty0 - 4 + wy, gxx = tx0 - 4 + wx;
        float v = 0.f;
        if (gy >= 0 && gy < H_ && gxx >= 0 && gxx < W_)
            v = prev_seg[((size_t)b * 2 + s) * HW_ + gy * W_ + gxx] * (1.f / 256.f);
        gl[SEGB + f] = v;
    }
    __syncthreads();
    {
        int m = t & 63;
        int sh = t >> 6;
        int s = sh >> 1, hh = sh & 1;
        int py = m >> 3, lx = m & 7;
        const float* gr = gl + m * GSTR;
        const float* sr = gl + SEGB + s * 256;
        float mx = -INFINITY;
        int wr0 = hh * 5, wr1 = hh ? 9 : 5;
        for (int wr = wr0; wr < wr1; ++wr) {
            int base = (py + wr) * 16 + lx;
            #pragma unroll
            for (int wc = 0; wc < 9; ++wc)
                mx = fmaxf(mx, gr[base + wc] * sr[base + wc]);
        }
        gl[REDB + sh * 64 + m] = mx;
    }
    __syncthreads();
    if (t < 128) {
        int s = t >> 6, m = t & 63;
        float v = fmaxf(gl[REDB + (s * 2 + 0) * 64 + m], gl[REDB + (s * 2 + 1) * 64 + m]);
        int gpx = (ty0 + (m >> 3)) * W_ + tx0 + (m & 7);
        lout[((size_t)b * 2 + s) * HW_ + gpx] = v;
    }
}

// ---------------------------------------------------------------- packs ----
__global__ __launch_bounds__(256)
void pack_dec_kernel(const float* __restrict__ dec, bf16* __restrict__ hcat8)
{
    __shared__ float tile[64][68];
    int b = blockIdx.z, c0 = blockIdx.y * 64, p0 = blockIdx.x * 64;
    int t = threadIdx.x;
    const float* src = dec + ((size_t)b * C_ + c0) * HW_ + p0;
    #pragma unroll
    for (int it = 0; it < 4; it++) {
        int f = t + it * 256;
        int cl = f >> 4, p4 = (f & 15) * 4;
        float4 v = *reinterpret_cast<const float4*>(src + (size_t)cl * HW_ + p4);
        *reinterpret_cast<float4*>(&tile[cl][p4]) = v;
    }
    __syncthreads();
    #pragma unroll
    for (int it = 0; it < 4; it++) {
        int f = t + it * 256;
        int pl = f >> 4, c4 = (f & 15) * 4;
        int p = p0 + pl;
        int y = p / 96, x = p % 96;
        int pos = (y + 1) * HP_ + x + 1;
        int ch = c0 + c4;
        ushort4 u;
        u.x = bfb(tile[c4 + 0][pl]); u.y = bfb(tile[c4 + 1][pl]);
        u.z = bfb(tile[c4 + 2][pl]); u.w = bfb(tile[c4 + 3][pl]);
        bf16* dst = hcat8 + ((size_t)b * 8 + (ch >> 5)) * CHK + (size_t)pos * 32 + (ch & 31);
        *reinterpret_cast<ushort4*>(dst) = u;
    }
}

__global__ __launch_bounds__(256)
void pack_small_kernel(const float* __restrict__ gout,
                       const float* __restrict__ lout,
                       const float* __restrict__ init_seg,
                       const float* __restrict__ prev_seg,
                       bf16* __restrict__ hcat1)
{
    int idx = blockIdx.x * 256 + threadIdx.x;
    if (idx >= B_ * HW_) return;
    int b = idx / HW_, p = idx % HW_;
    int y = p / 96, x = p % 96;
    int pos = (y + 1) * HP_ + x + 1;
    bf16* dst = hcat1 + ((size_t)b * HPW + pos) * 8;
    float g0 = gout[((size_t)b * 2 + 0) * HW_ + p];
    float g1 = gout[((size_t)b * 2 + 1) * HW_ + p];
    float i0 = init_seg[((size_t)b * 2 + 0) * HW_ + p];
    float i1 = init_seg[((size_t)b * 2 + 1) * HW_ + p];
    float l0 = lout[((size_t)b * 2 + 0) * HW_ + p];
    float l1 = lout[((size_t)b * 2 + 1) * HW_ + p];
    float q0 = prev_seg[((size_t)b * 2 + 0) * HW_ + p];
    float q1 = prev_seg[((size_t)b * 2 + 1) * HW_ + p];
    ushort4 u; u.x = bfb(g0); u.y = bfb(g1); u.z = bfb(i0); u.w = bfb(i1);
    *reinterpret_cast<ushort4*>(dst) = u;
    ushort4 u2; u2.x = bfb(l0); u2.y = bfb(l1); u2.z = bfb(q0); u2.w = bfb(q1);
    *reinterpret_cast<ushort4*>(dst + 4) = u2;
}

// ---------------------------------------------------------------- conv1 ----
// Row-aligned: 128 oc x 96 px (one image row per block). Grid 768 = 3 blocks/CU.
// 28KB single-buffered LDS (A 16K + B 12K), 2 barriers/step, 41 BK=64 steps.
// Epilogue: acc -> swizzled LDS [96px][128ch] -> flat contiguous copy to hmid_pad.
__global__ __launch_bounds__(256)
void conv1_mfma(const bf16* __restrict__ hcat8, const bf16* __restrict__ hcat1,
                const bf16* __restrict__ w1bf, const float* __restrict__ b1,
                bf16* __restrict__ hmidp)
{
    __shared__ bf16 S[14336];                 // A = S[0..8191], B = S[8192..14335]
    bf16* Abuf = S;
    bf16* Bbuf = S + 8192;
    int gid = blockIdx.x;                     // 768 = 8 b x 96 rows
    int b = gid & 7;
    int row = gid >> 3;                       // 0..95
    int tid = threadIdx.x, lane = tid & 63;
    int w = tid >> 6, wm = w & 1, wn = w >> 1;
    int l15 = lane & 15, lk = lane >> 4;
    const bf16* hb8 = hcat8 + (size_t)b * 8 * CHK;
    const bf16* hb1 = hcat1 + (size_t)b * HPW * 8;

    int wbase = tid & 192;
    int t3 = (tid >> 3) & 7;
    int cX = (tid & 7) ^ t3;
    int selX = cX >> 2;
    int cin8 = (cX & 3) * 8;
    int r0 = tid >> 3;                        // 0..31
    int swzE0 = ((lk) ^ (l15 & 7)) * 8;
    int swzE1 = ((4 + lk) ^ (l15 & 7)) * 8;

    f32x4 acc[4][3] = {};

    auto STAGE = [&](int p) {
        int s0 = 2 * p, s1 = s0 + 1;
        int icc0 = s0 / 9, tap0 = s0 - icc0 * 9;
        int icc1 = s1 / 9, tap1 = s1 - icc1 * 9;
        // A: 4 chunks/thread
        const bf16* gA = w1bf + (size_t)p * 8192 + (size_t)selX * 4096 + cin8;
        #pragma unroll
        for (int i = 0; i < 4; i++)
            gload_lds16(gA + (i * 32 + r0) * 32,
                        &Abuf[(size_t)(i * 256 + wbase) * 8]);
        // B: 3 chunks/thread (96 px x 8 chunks)
        int tapS = selX ? tap1 : tap0;
        int iccS = selX ? icc1 : icc0;
        int posT = (row + tapS / 3) * HP_ + (tapS % 3);
        bool is8 = (iccS >= 8);
        const bf16* gb = is8 ? hb1 : (hb8 + (size_t)iccS * CHK);
        #pragma unroll
        for (int i = 0; i < 3; i++) {
            int c = i * 32 + r0;
            const bf16* g = is8 ? (gb + (size_t)(posT + c) * 8)
                                : (gb + (size_t)(posT + c) * 32 + cin8);
            gload_lds16(g, &Bbuf[(size_t)(i * 256 + wbase) * 8]);
        }
    };

    auto COMPUTE = [&]() {
        #pragma unroll
        for (int k = 0; k < 2; k++) {
            int swz = k ? swzE1 : swzE0;
            short8 a[4], bq[3];
            #pragma unroll
            for (int mt = 0; mt < 4; mt++)
                a[mt] = *reinterpret_cast<const short8*>(
                    &Abuf[(size_t)(wm * 64 + mt * 16 + l15) * 64 + swz]);
            #pragma unroll
            for (int nt = 0; nt < 3; nt++)
                bq[nt] = *reinterpret_cast<const short8*>(
                    &Bbuf[(size_t)(wn * 48 + nt * 16 + l15) * 64 + swz]);
            #pragma unroll
            for (int mt = 0; mt < 4; mt++)
                #pragma unroll
                for (int nt = 0; nt < 3; nt++)
                    acc[mt][nt] = __builtin_amdgcn_mfma_f32_16x16x32_bf16(
                        a[mt], bq[nt], acc[mt][nt], 0, 0, 0);
        }
    };

    for (int p = 0; p < 41; ++p) {
        STAGE(p);
        __syncthreads();
        COMPUTE();
        __syncthreads();
    }

    // epilogue: acc -> swizzled LDS [96 px][16 chunks of 8ch], then flat copy.
    #pragma unroll
    for (int nt = 0; nt < 3; nt++) {
        int pxl = wn * 48 + nt * 16 + l15;
        #pragma unroll
        for (int mt = 0; mt < 4; mt++) {
            int ocb = wm * 64 + mt * 16 + lk * 4;
            float4 bias = *reinterpret_cast<const float4*>(b1 + ocb);
            const float* bp = reinterpret_cast<const float*>(&bias);
            ushort4 u;
            u.x = bfb(fmaxf(acc[mt][nt][0] + bp[0], 0.f));
            u.y = bfb(fmaxf(acc[mt][nt][1] + bp[1], 0.f));
            u.z = bfb(fmaxf(acc[mt][nt][2] + bp[2], 0.f));
            u.w = bfb(fmaxf(acc[mt][nt][3] + bp[3], 0.f));
            int chunk = (ocb >> 3) ^ (pxl & 7);       // swizzled 16B chunk
            *reinterpret_cast<ushort4*>(&S[(size_t)pxl * 128 + chunk * 8 + (lk & 1) * 4]) = u;
        }
    }
    __syncthreads();
    {
        bf16* dst = hmidp + (size_t)b * HPW * 128 + ((size_t)(row + 1) * HP_ + 1) * 128;
        #pragma unroll
        for (int i = 0; i < 6; i++) {
            int f = tid + i * 256;                    // 16B chunk id, 0..1535
            int px = f >> 4, cc = f & 15;
            short8 v = *reinterpret_cast<const short8*>(
                &S[(size_t)px * 128 + (cc ^ (px & 7)) * 8]);
            *reinterpret_cast<short8*>(dst + (size_t)f * 8) = v;
        }
    }
}

// ---------------------------------------------------------------- conv2 ----
__global__ __launch_bounds__(256)
void conv2_mfma(const bf16* __restrict__ hmidp, const bf16* __restrict__ w2bf,
                const float* __restrict__ b2, float* __restrict__ out)
{
    __shared__ bf16 Abuf[1024];
    __shared__ bf16 Bbuf[8192];
    int gid = blockIdx.x;             // 576 = 8 b x 72 px-tiles
    int b = gid & 7;
    int p0 = (gid >> 3) * 128;
    int tid = threadIdx.x, lane = tid & 63;
    int wn = tid >> 6;
    int l15 = lane & 15, lk = lane >> 4;
    const bf16* hb = hmidp + (size_t)b * HPW * 128;

    int wbase = tid & 192;
    int t3 = (tid >> 3) & 7;
    int cX = (tid & 7) ^ t3;
    int r0 = tid >> 3;
    int posB[4];
    #pragma unroll
    for (int i = 0; i < 4; i++) {
        int px = p0 + i * 32 + r0;
        posB[i] = (px / 96) * HP_ + (px % 96);
    }
    int swzE0 = ((lk) ^ (l15 & 7)) * 8;
    int swzE1 = ((4 + lk) ^ (l15 & 7)) * 8;

    f32x4 acc[2] = {};

    auto STAGE = [&](int s) {
        int tap = s >> 1, half = s & 1;
        int toff = (tap / 3) * HP_ + (tap % 3);
        if (tid < 128)
            gload_lds16(w2bf + ((size_t)s * 16 + r0) * 64 + cX * 8,
                        &Abuf[(size_t)(tid & 192) * 8]);
        #pragma unroll
        for (int i = 0; i < 4; i++)
            gload_lds16(hb + (size_t)(posB[i] + toff) * 128 + half * 64 + cX * 8,
                        &Bbuf[(size_t)(i * 256 + wbase) * 8]);
    };

    auto COMPUTE = [&]() {
        #pragma unroll
        for (int k = 0; k < 2; k++) {
            int swz = k ? swzE1 : swzE0;
            short8 a = *reinterpret_cast<const short8*>(&Abuf[(size_t)l15 * 64 + swz]);
            #pragma unroll
            for (int nt = 0; nt < 2; nt++) {
                short8 bq = *reinterpret_cast<const short8*>(
                    &Bbuf[(size_t)(wn * 32 + nt * 16 + l15) * 64 + swz]);
                acc[nt] = __builtin_amdgcn_mfma_f32_16x16x32_bf16(a, bq, acc[nt], 0, 0, 0);
            }
        }
    };

    for (int s = 0; s < 18; ++s) {
        STAGE(s);
        __syncthreads();
        COMPUTE();
        __syncthreads();
    }

    if (lk == 0) {
        float bb0 = b2[0], bb1 = b2[1];
        #pragma unroll
        for (int nt = 0; nt < 2; nt++) {
            int px = p0 + wn * 32 + nt * 16 + l15;
            out[((size_t)b * 2 + 0) * HW_ + px] = acc[nt][0] + bb0;
            out[((size_t)b * 2 + 1) * HW_ + px] = acc[nt][1] + bb1;
        }
    }
}

// ---------------------------------------------------------------- launch ----
extern "C" void kernel_launch(void* const* d_in, const int* in_sizes, int n_in,
                              void* d_out, int out_size, void* d_ws, size_t ws_size,
                              hipStream_t stream)
{
    const float* cur_embed  = (const float*)d_in[0];
    const float* cur_decode = (const float*)d_in[1];
    const float* init_embed = (const float*)d_in[2];
    const float* init_seg   = (const float*)d_in[3];
    const float* prev_embed = (const float*)d_in[4];
    const float* prev_seg   = (const float*)d_in[5];
    const float* W1 = (const float*)d_in[6];
    const float* b1 = (const float*)d_in[7];
    const float* W2 = (const float*)d_in[8];
    const float* b2 = (const float*)d_in[9];
    float* out = (float*)d_out;

    char* ws = (char*)d_ws;
    bf16* hcat8 = (bf16*)ws;
    bf16* curbf = (bf16*)ws;                          // alias (dead at memset)
    bf16* hcat1 = (bf16*)(ws + 39337984);
    const size_t HCAT_REGION = 40567296;
    const size_t HMID_SIZE   = 19668992;
    bf16* hmidp  = (bf16*)(ws + HCAT_REGION);
    bf16* fibf   = (bf16*)(ws + HCAT_REGION);
    bf16* prevbf = (bf16*)(ws + HCAT_REGION);
    float* si  = (float*)(ws + HCAT_REGION + 2621440);
    bf16* w1bf = (bf16*)(ws + 60236288);
    bf16* w2bf = (bf16*)(ws + 60908032);
    float* gout = (float*)(ws + 60944896);
    float* lout = (float*)(ws + 61534720);

    { int total = 82 * 128 * 32;
      w1cvt_kernel<<<(total + 255) / 256, 256, 0, stream>>>(W1, w1bf); }
    { int total = 18 * 16 * 64;
      w2cvt_kernel<<<(total + 255) / 256, 256, 0, stream>>>(W2, w2bf); }
    { dim3 g(144, 4, B_);
      tcur_kernel<<<g, 256, 0, stream>>>(cur_embed, curbf); }
    { int total = B_ * (C_ + 2) * KPP;
      pool_kernel<<<(total + 255) / 256, 256, 0, stream>>>(init_embed, init_seg, fibf, si); }
    { gmap_mfma<<<576, 256, 0, stream>>>(curbf, fibf, si, gout); }
    for (int g = 0; g < 2; g++) {
        dim3 gt(144, 4, 4);
        tcur_kernel<<<gt, 256, 0, stream>>>(prev_embed + (size_t)g * 4 * C_ * HW_, prevbf);
        dim3 gl(144, 4);
        lmap_mfma<<<gl, 256, 0, stream>>>(curbf, prevbf, prev_seg, lout, g * 4);
    }
    hipMemsetAsync(ws, 0, HCAT_REGION + HMID_SIZE, stream);
    { dim3 g(144, 4, B_);
      pack_dec_kernel<<<g, 256, 0, stream>>>(cur_decode, hcat8); }
    { int total = B_ * HW_;
      pack_small_kernel<<<(total + 255) / 256, 256, 0, stream>>>(gout, lout, init_seg, prev_seg, hcat1); }
    { conv1_mfma<<<768, 256, 0, stream>>>(hcat8, hcat1, w1bf, b1, hmidp); }
    { conv2_mfma<<<576, 256, 0, stream>>>(hmidp, w2bf, b2, out); }
}

// Round 14
// 264.131 us; speedup vs baseline: 2.8171x; 1.0893x over previous
//
#include <hip/hip_runtime.h>
#include <hip/hip_bf16.h>

// Round 14: lmap -> LDS-staged GEMM (conv1 template; zero-redirect for pad rows;
//           staging LDS unioned with G/seg scan buffer). memset(60MB) ->
//           border-zero kernel (2.4MB pad rings only). Everything else = r13.
// ws layout (62.12 MB, aliased):
//   [0, 39,337,984)           hcat8 bf16 [8][8][9604][32]   -- ALSO curbf bf16 [8][9216][256]
//   [39,337,984, 40,567,296)  hcat1 bf16 [8][9604][8]
//   [40,567,296, 60,236,288)  hmid_pad bf16 [8][9604][128]
//       -- phase1 alias: fibf bf16 [8][640][256] @ +0, si f32 [8][2][640] @ +2,621,440
//       -- phase2 alias: prevbf bf16 [4][9216][256]
//   [60,236,288, 60,908,032)  W1bf bf16 [82][128][32]  (slab 81 = zeros; doubles as zbuf)
//   [60,908,032, 60,944,896)  W2bf bf16 [18][16][64]
//   [60,944,896, 61,534,720)  gout f32 [8][2][9216]
//   [61,534,720, 62,124,544)  lout f32 [8][2][9216]

typedef __hip_bfloat16 bf16;
typedef __attribute__((ext_vector_type(8))) short short8;
typedef __attribute__((ext_vector_type(4))) float f32x4;

constexpr int B_  = 8;
constexpr int C_  = 256;
constexpr int H_  = 96;
constexpr int W_  = 96;
constexpr int HW_ = H_ * W_;       // 9216
constexpr int PW_ = 24;
constexpr int KP_ = 576;
constexpr int KPP = 640;
constexpr int HP_ = 98;
constexpr int HPW = HP_ * HP_;     // 9604
constexpr int C1O = 128;
constexpr int CHK = HPW * 32;

__device__ __forceinline__ unsigned short bfb(float f) {
    bf16 h = __float2bfloat16(f);
    return *reinterpret_cast<unsigned short*>(&h);
}

__device__ __forceinline__ void gload_lds16(const bf16* g, bf16* l) {
    __builtin_amdgcn_global_load_lds((const void*)g, (void*)l, 16, 0, 0);
}

// ------------------------------------------------------------ W1 convert ----
__global__ __launch_bounds__(256)
void w1cvt_kernel(const float* __restrict__ W1, bf16* __restrict__ w1bf)
{
    int idx = blockIdx.x * 256 + threadIdx.x;
    if (idx >= 82 * 128 * 32) return;
    int ic = idx & 31;
    int oc = (idx >> 5) & 127;
    int ks = idx >> 12;
    int icc = ks / 9, tap = ks % 9;
    int icg = icc * 32 + ic;
    float v = (icg < 264) ? W1[((size_t)oc * 264 + icg) * 9 + tap] : 0.f;
    w1bf[idx] = __float2bfloat16(v);
}

// ------------------------------------------------------------ W2 convert ----
__global__ __launch_bounds__(256)
void w2cvt_kernel(const float* __restrict__ W2, bf16* __restrict__ w2bf)
{
    int idx = blockIdx.x * 256 + threadIdx.x;
    if (idx >= 18 * 16 * 64) return;
    int c  = idx & 63;
    int oc = (idx >> 6) & 15;
    int s  = idx >> 10;
    int tap = s >> 1, half = s & 1;
    float v = (oc < 2) ? W2[((size_t)oc * 128 + half * 64 + c) * 9 + tap] : 0.f;
    w2bf[idx] = __float2bfloat16(v);
}

// ------------------------------------------------------- NCHW->NHWC bf16 ----
__global__ __launch_bounds__(256)
void tcur_kernel(const float* __restrict__ cur, bf16* __restrict__ curbf)
{
    __shared__ float tile[64][68];
    int b = blockIdx.z, c0 = blockIdx.y * 64, p0 = blockIdx.x * 64;
    int t = threadIdx.x;
    const float* src = cur + ((size_t)b * C_ + c0) * HW_ + p0;
    #pragma unroll
    for (int it = 0; it < 4; it++) {
        int f = t + it * 256;
        int cl = f >> 4, p4 = (f & 15) * 4;
        float4 v = *reinterpret_cast<const float4*>(src + (size_t)cl * HW_ + p4);
        *reinterpret_cast<float4*>(&tile[cl][p4]) = v;
    }
    __syncthreads();
    bf16* dst = curbf + ((size_t)b * HW_ + p0) * 256 + c0;
    #pragma unroll
    for (int it = 0; it < 4; it++) {
        int f = t + it * 256;
        int pl = f >> 4, c4 = (f & 15) * 4;
        ushort4 u;
        u.x = bfb(tile[c4 + 0][pl]); u.y = bfb(tile[c4 + 1][pl]);
        u.z = bfb(tile[c4 + 2][pl]); u.w = bfb(tile[c4 + 3][pl]);
        *reinterpret_cast<ushort4*>(dst + (size_t)pl * 256 + c4) = u;
    }
}

// ---------------------------------------------------------------- pool ----
__global__ __launch_bounds__(256)
void pool_kernel(const float* __restrict__ init_embed,
                 const float* __restrict__ init_seg,
                 bf16* __restrict__ fibf, float* __restrict__ si)
{
    int idx = blockIdx.x * 256 + threadIdx.x;
    int total = B_ * (C_ + 2) * KPP;
    if (idx >= total) return;
    int k  = idx % KPP;
    int ch = (idx / KPP) % (C_ + 2);
    int b  = idx / (KPP * (C_ + 2));
    float s = 0.f;
    if (k < KP_) {
        int ph = k / PW_, pw = k % PW_;
        const float* src = (ch < C_)
            ? (init_embed + (((size_t)b * C_ + ch) * H_ + ph * 4) * W_ + pw * 4)
            : (init_seg   + (((size_t)b * 2 + (ch - C_)) * H_ + ph * 4) * W_ + pw * 4);
        #pragma unroll
        for (int r = 0; r < 4; r++) {
            float4 v = *reinterpret_cast<const float4*>(src + r * W_);
            s += v.x + v.y + v.z + v.w;
        }
        s *= (1.f / 16.f);
    }
    if (ch < C_) fibf[((size_t)b * KPP + k) * C_ + ch] = __float2bfloat16(s);
    else         si[(size_t)b * 2 * KPP + (ch - C_) * KPP + k] = s;
}

// ---------------------------------------------------------------- gmap ----
__global__ __launch_bounds__(256)
void gmap_mfma(const bf16* __restrict__ curbf, const bf16* __restrict__ fibf,
               const float* __restrict__ si, float* __restrict__ gout)
{
    __shared__ bf16 Abuf[8192];
    __shared__ bf16 Bbuf[8192];
    __shared__ float bred[2][2][2][64];
    int gid = blockIdx.x;             // 576 = 8 b x 72 px-tiles
    int b = gid & 7;
    int p0 = (gid >> 3) * 128;
    int tid = threadIdx.x, lane = tid & 63;
    int w = tid >> 6, wm = w & 1, wn = w >> 1;
    int l15 = lane & 15, lk = lane >> 4;
    const bf16* fb = fibf + (size_t)b * KPP * 256;
    const bf16* cb = curbf + (size_t)b * HW_ * 256;
    const float* sib = si + (size_t)b * 2 * KPP;

    int wbase = tid & 192;
    int t3 = (tid >> 3) & 7;
    int cX = (tid & 7) ^ t3;
    int r0 = tid >> 3;
    int swzE0 = ((lk) ^ (l15 & 7)) * 8;
    int swzE1 = ((4 + lk) ^ (l15 & 7)) * 8;

    float best[2][4];
    #pragma unroll
    for (int s = 0; s < 2; s++)
        #pragma unroll
        for (int nt = 0; nt < 4; nt++) best[s][nt] = -INFINITY;
    f32x4 acc[4][4] = {};

    auto STAGE = [&](int q) {
        int chunk = q >> 2, ks = q & 3;
        int koff = ks * 64 + cX * 8;
        #pragma unroll
        for (int i = 0; i < 4; i++) {
            int row = i * 32 + r0;
            gload_lds16(fb + (size_t)(chunk * 128 + row) * 256 + koff,
                        &Abuf[(size_t)(i * 256 + wbase) * 8]);
            gload_lds16(cb + (size_t)(p0 + row) * 256 + koff,
                        &Bbuf[(size_t)(i * 256 + wbase) * 8]);
        }
    };

    auto COMPUTE = [&]() {
        #pragma unroll
        for (int k = 0; k < 2; k++) {
            int swz = k ? swzE1 : swzE0;
            short8 a[4], bq[4];
            #pragma unroll
            for (int mt = 0; mt < 4; mt++)
                a[mt] = *reinterpret_cast<const short8*>(
                    &Abuf[(size_t)(wm * 64 + mt * 16 + l15) * 64 + swz]);
            #pragma unroll
            for (int nt = 0; nt < 4; nt++)
                bq[nt] = *reinterpret_cast<const short8*>(
                    &Bbuf[(size_t)(wn * 64 + nt * 16 + l15) * 64 + swz]);
            #pragma unroll
            for (int mt = 0; mt < 4; mt++)
                #pragma unroll
                for (int nt = 0; nt < 4; nt++)
                    acc[mt][nt] = __builtin_amdgcn_mfma_f32_16x16x32_bf16(
                        a[mt], bq[nt], acc[mt][nt], 0, 0, 0);
        }
    };

    for (int q = 0; q < 20; ++q) {
        STAGE(q);
        __syncthreads();
        COMPUTE();
        if ((q & 3) == 3) {
            int kp0 = (q >> 2) * 128;
            #pragma unroll
            for (int mt = 0; mt < 4; mt++) {
                int rb = kp0 + wm * 64 + mt * 16 + lk * 4;
                float4 s0 = *reinterpret_cast<const float4*>(sib + rb);
                float4 s1 = *reinterpret_cast<const float4*>(sib + KPP + rb);
                const float* s0p = reinterpret_cast<const float*>(&s0);
                const float* s1p = reinterpret_cast<const float*>(&s1);
                #pragma unroll
                for (int nt = 0; nt < 4; nt++) {
                    #pragma unroll
                    for (int r = 0; r < 4; r++) {
                        float v = acc[mt][nt][r];
                        best[0][nt] = fmaxf(best[0][nt], v * s0p[r]);
                        best[1][nt] = fmaxf(best[1][nt], v * s1p[r]);
                    }
                    acc[mt][nt] = (f32x4){0.f, 0.f, 0.f, 0.f};
                }
            }
        }
        __syncthreads();
    }
    #pragma unroll
    for (int s = 0; s < 2; s++)
        #pragma unroll
        for (int nt = 0; nt < 4; nt++) {
            float v = best[s][nt];
            v = fmaxf(v, __shfl_xor(v, 16));
            v = fmaxf(v, __shfl_xor(v, 32));
            if (lk == 0) bred[wm][wn][s][nt * 16 + l15] = v;
        }
    __syncthreads();
    {
        int wn2 = tid >> 7, s2 = (tid >> 6) & 1, pxl = tid & 63;
        float v = fmaxf(bred[0][wn2][s2][pxl], bred[1][wn2][s2][pxl]);
        gout[((size_t)b * 2 + s2) * HW_ + p0 + wn2 * 64 + pxl] = v;
    }
}

// ---------------------------------------------------------------- lmap ----
// LDS-staged Gram: A = 64 cur px, B = 256 window px, K=256 in 4 BK=64 steps.
// Pad rows redirect source to zbuf (w1bf slab 81, zeros). Staging LDS unioned
// with the G/seg scan buffer.
__global__ __launch_bounds__(256)
void lmap_mfma(const bf16* __restrict__ curbf, const bf16* __restrict__ prevbf,
               const bf16* __restrict__ zbuf,
               const float* __restrict__ prev_seg, float* __restrict__ lout, int b0)
{
    constexpr int GSTR = 257;
    constexpr int SEGB = 64 * GSTR;          // float idx 16448
    constexpr int REDB = SEGB + 512;         // 16960
    __shared__ __align__(16) char Smem[(REDB + 256) * 4];   // 68,864 B
    bf16* Abuf = (bf16*)Smem;                // 8 KB  (64 rows x 64 ch)
    bf16* Bbuf = (bf16*)(Smem + 8192);       // 32 KB (256 rows x 64 ch)
    float* gl  = (float*)Smem;               // reused after K-loop

    int b = b0 + blockIdx.y;
    const bf16* pb = prevbf + (size_t)blockIdx.y * HW_ * 256;
    const bf16* cb = curbf + (size_t)b * HW_ * 256;
    int tile = blockIdx.x;
    int ty0 = (tile / 12) * 8, tx0 = (tile % 12) * 8;
    int tid = threadIdx.x, lane = tid & 63, wn = tid >> 6;
    int l15 = lane & 15, lk = lane >> 4;

    int wbase = tid & 192;
    int t3 = (tid >> 3) & 7;
    int cX = (tid & 7) ^ t3;                 // true chunk (inverse swizzle)
    int r0 = tid >> 3;                       // 0..31
    int swzE0 = ((lk) ^ (l15 & 7)) * 8;
    int swzE1 = ((4 + lk) ^ (l15 & 7)) * 8;

    // A source rows (cur px of this tile)
    int gpxA0 = (ty0 + (r0 >> 3)) * W_ + tx0 + (r0 & 7);
    int gpxA1 = (ty0 + (r0 >> 3) + 4) * W_ + tx0 + (r0 & 7);
    // B source rows (window px, zero-redirect for pads)
    const bf16* rowB[8];
    #pragma unroll
    for (int i = 0; i < 8; i++) {
        int wrow = i * 32 + r0;              // 0..255
        int wy = wrow >> 4, wx = wrow & 15;
        int gy = ty0 - 4 + wy, gx = tx0 - 4 + wx;
        bool ok = (gy >= 0) && (gy < H_) && (gx >= 0) && (gx < W_);
        rowB[i] = ok ? (pb + (size_t)(gy * W_ + gx) * 256) : zbuf;
    }

    f32x4 acc[4][4] = {};

    for (int ks = 0; ks < 4; ++ks) {
        int koff = ks * 64 + cX * 8;
        gload_lds16(cb + (size_t)gpxA0 * 256 + koff, &Abuf[(size_t)(wbase) * 8]);
        gload_lds16(cb + (size_t)gpxA1 * 256 + koff, &Abuf[(size_t)(256 + wbase) * 8]);
        #pragma unroll
        for (int i = 0; i < 8; i++)
            gload_lds16(rowB[i] + koff, &Bbuf[(size_t)(i * 256 + wbase) * 8]);
        __syncthreads();
        #pragma unroll
        for (int k = 0; k < 2; k++) {
            int swz = k ? swzE1 : swzE0;
            short8 a[4], bq[4];
            #pragma unroll
            for (int mt = 0; mt < 4; mt++)
                a[mt] = *reinterpret_cast<const short8*>(
                    &Abuf[(size_t)(mt * 16 + l15) * 64 + swz]);
            #pragma unroll
            for (int nt = 0; nt < 4; nt++)
                bq[nt] = *reinterpret_cast<const short8*>(
                    &Bbuf[(size_t)(wn * 64 + nt * 16 + l15) * 64 + swz]);
            #pragma unroll
            for (int mt = 0; mt < 4; mt++)
                #pragma unroll
                for (int nt = 0; nt < 4; nt++)
                    acc[mt][nt] = __builtin_amdgcn_mfma_f32_16x16x32_bf16(
                        a[mt], bq[nt], acc[mt][nt], 0, 0, 0);
        }
        __syncthreads();
    }

    // G -> LDS (staging area now dead)
    #pragma unroll
    for (int mt = 0; mt < 4; mt++)
        #pragma unroll
        for (int nt = 0; nt < 4; nt++)
            #pragma unroll
            for (int r = 0; r < 4; r++)
                gl[(mt * 16 + lk * 4 + r) * GSTR + wn * 64 + nt * 16 + l15] = acc[mt][nt][r];
    #pragma unroll
    for (int it = 0; it < 2; it++) {
        int f = tid + it * 256;
        int s = f >> 8, wp = f & 255;
        int wy = wp >> 4, wx = wp & 15;
        int gy = ty0 - 4 + wy, gxx = tx0 - 4 + wx;
        float v = 0.f;
        if (gy >= 0 && gy < H_ && gxx >= 0 && gxx < W_)
            v = prev_seg[((size_t)b * 2 + s) * HW_ + gy * W_ + gxx] * (1.f / 256.f);
        gl[SEGB + f] = v;
    }
    __syncthreads();
    {
        int m = tid & 63;
        int sh = tid >> 6;
        int s = sh >> 1, hh = sh & 1;
        int py = m >> 3, lx = m & 7;
        const float* gr = gl + m * GSTR;
        const float* sr = gl + SEGB + s * 256;
        float mx = -INFINITY;
        int wr0 = hh * 5, wr1 = hh ? 9 : 5;
        for (int wr = wr0; wr < wr1; ++wr) {
            int base = (py + wr) * 16 + lx;
            #pragma unroll
            for (int wc = 0; wc < 9; ++wc)
                mx = fmaxf(mx, gr[base + wc] * sr[base + wc]);
        }
        gl[REDB + sh * 64 + m] = mx;
    }
    __syncthreads();
    if (tid < 128) {
        int s = tid >> 6, m = tid & 63;
        float v = fmaxf(gl[REDB + (s * 2 + 0) * 64 + m], gl[REDB + (s * 2 + 1) * 64 + m]);
        int gpx = (ty0 + (m >> 3)) * W_ + tx0 + (m & 7);
        lout[((size_t)b * 2 + s) * HW_ + gpx] = v;
    }
}

// ---------------------------------------------------------------- packs ----
__global__ __launch_bounds__(256)
void pack_dec_kernel(const float* __restrict__ dec, bf16* __restrict__ hcat8)
{
    __shared__ float tile[64][68];
    int b = blockIdx.z, c0 = blockIdx.y * 64, p0 = blockIdx.x * 64;
    int t = threadIdx.x;
    const float* src = dec + ((size_t)b * C_ + c0) * HW_ + p0;
    #pragma unroll
    for (int it = 0; it < 4; it++) {
        int f = t + it * 256;
        int cl = f >> 4, p4 = (f & 15) * 4;
        float4 v = *reinterpret_cast<const float4*>(src + (size_t)cl * HW_ + p4);
        *reinterpret_cast<float4*>(&tile[cl][p4]) = v;
    }
    __syncthreads();
    #pragma unroll
    for (int it = 0; it < 4; it++) {
        int f = t + it * 256;
        int pl = f >> 4, c4 = (f & 15) * 4;
        int p = p0 + pl;
        int y = p / 96, x = p % 96;
        int pos = (y + 1) * HP_ + x + 1;
        int ch = c0 + c4;
        ushort4 u;
        u.x = bfb(tile[c4 + 0][pl]); u.y = bfb(tile[c4 + 1][pl]);
        u.z = bfb(tile[c4 + 2][pl]); u.w = bfb(tile[c4 + 3][pl]);
        bf16* dst = hcat8 + ((size_t)b * 8 + (ch >> 5)) * CHK + (size_t)pos * 32 + (ch & 31);
        *reinterpret_cast<ushort4*>(dst) = u;
    }
}

__global__ __launch_bounds__(256)
void pack_small_kernel(const float* __restrict__ gout,
                       const float* __restrict__ lout,
                       const float* __restrict__ init_seg,
                       const float* __restrict__ prev_seg,
                       bf16* __restrict__ hcat1)
{
    int idx = blockIdx.x * 256 + threadIdx.x;
    if (idx >= B_ * HW_) return;
    int b = idx / HW_, p = idx % HW_;
    int y = p / 96, x = p % 96;
    int pos = (y + 1) * HP_ + x + 1;
    bf16* dst = hcat1 + ((size_t)b * HPW + pos) * 8;
    float g0 = gout[((size_t)b * 2 + 0) * HW_ + p];
    float g1 = gout[((size_t)b * 2 + 1) * HW_ + p];
    float i0 = init_seg[((size_t)b * 2 + 0) * HW_ + p];
    float i1 = init_seg[((size_t)b * 2 + 1) * HW_ + p];
    float l0 = lout[((size_t)b * 2 + 0) * HW_ + p];
    float l1 = lout[((size_t)b * 2 + 1) * HW_ + p];
    float q0 = prev_seg[((size_t)b * 2 + 0) * HW_ + p];
    float q1 = prev_seg[((size_t)b * 2 + 1) * HW_ + p];
    ushort4 u; u.x = bfb(g0); u.y = bfb(g1); u.z = bfb(i0); u.w = bfb(i1);
    *reinterpret_cast<ushort4*>(dst) = u;
    ushort4 u2; u2.x = bfb(l0); u2.y = bfb(l1); u2.z = bfb(q0); u2.w = bfb(q1);
    *reinterpret_cast<ushort4*>(dst + 4) = u2;
}

// ------------------------------------------------------------ border zero ----
// Zero the pad rings of hcat8 / hcat1 / hmidp (388 border positions per image).
__global__ __launch_bounds__(256)
void zero_border_kernel(bf16* __restrict__ hcat8, bf16* __restrict__ hcat1,
                        bf16* __restrict__ hmidp)
{
    int idx = blockIdx.x * 256 + threadIdx.x;
    if (idx >= B_ * 388) return;
    int b = idx / 388, bi = idx % 388;
    int pos;
    if (bi < 98) pos = bi;
    else if (bi < 196) pos = 97 * HP_ + (bi - 98);
    else if (bi < 292) pos = (bi - 196 + 1) * HP_;
    else pos = (bi - 292 + 1) * HP_ + 97;
    const short8 Z = {0, 0, 0, 0, 0, 0, 0, 0};
    #pragma unroll
    for (int c = 0; c < 8; c++) {
        bf16* p = hcat8 + ((size_t)b * 8 + c) * CHK + (size_t)pos * 32;
        #pragma unroll
        for (int j = 0; j < 4; j++)
            *reinterpret_cast<short8*>(p + j * 8) = Z;
    }
    *reinterpret_cast<short8*>(hcat1 + ((size_t)b * HPW + pos) * 8) = Z;
    bf16* q = hmidp + ((size_t)b * HPW + pos) * 128;
    #pragma unroll
    for (int j = 0; j < 16; j++)
        *reinterpret_cast<short8*>(q + j * 8) = Z;
}

// ---------------------------------------------------------------- conv1 ----
__global__ __launch_bounds__(256)
void conv1_mfma(const bf16* __restrict__ hcat8, const bf16* __restrict__ hcat1,
                const bf16* __restrict__ w1bf, const float* __restrict__ b1,
                bf16* __restrict__ hmidp)
{
    __shared__ bf16 S[14336];                 // A = S[0..8191], B = S[8192..14335]
    bf16* Abuf = S;
    bf16* Bbuf = S + 8192;
    int gid = blockIdx.x;                     // 768 = 8 b x 96 rows
    int b = gid & 7;
    int row = gid >> 3;
    int tid = threadIdx.x, lane = tid & 63;
    int w = tid >> 6, wm = w & 1, wn = w >> 1;
    int l15 = lane & 15, lk = lane >> 4;
    const bf16* hb8 = hcat8 + (size_t)b * 8 * CHK;
    const bf16* hb1 = hcat1 + (size_t)b * HPW * 8;

    int wbase = tid & 192;
    int t3 = (tid >> 3) & 7;
    int cX = (tid & 7) ^ t3;
    int selX = cX >> 2;
    int cin8 = (cX & 3) * 8;
    int r0 = tid >> 3;
    int swzE0 = ((lk) ^ (l15 & 7)) * 8;
    int swzE1 = ((4 + lk) ^ (l15 & 7)) * 8;

    f32x4 acc[4][3] = {};

    auto STAGE = [&](int p) {
        int s0 = 2 * p, s1 = s0 + 1;
        int icc0 = s0 / 9, tap0 = s0 - icc0 * 9;
        int icc1 = s1 / 9, tap1 = s1 - icc1 * 9;
        const bf16* gA = w1bf + (size_t)p * 8192 + (size_t)selX * 4096 + cin8;
        #pragma unroll
        for (int i = 0; i < 4; i++)
            gload_lds16(gA + (i * 32 + r0) * 32,
                        &Abuf[(size_t)(i * 256 + wbase) * 8]);
        int tapS = selX ? tap1 : tap0;
        int iccS = selX ? icc1 : icc0;
        int posT = (row + tapS / 3) * HP_ + (tapS % 3);
        bool is8 = (iccS >= 8);
        const bf16* gb = is8 ? hb1 : (hb8 + (size_t)iccS * CHK);
        #pragma unroll
        for (int i = 0; i < 3; i++) {
            int c = i * 32 + r0;
            const bf16* g = is8 ? (gb + (size_t)(posT + c) * 8)
                                : (gb + (size_t)(posT + c) * 32 + cin8);
            gload_lds16(g, &Bbuf[(size_t)(i * 256 + wbase) * 8]);
        }
    };

    auto COMPUTE = [&]() {
        #pragma unroll
        for (int k = 0; k < 2; k++) {
            int swz = k ? swzE1 : swzE0;
            short8 a[4], bq[3];
            #pragma unroll
            for (int mt = 0; mt < 4; mt++)
                a[mt] = *reinterpret_cast<const short8*>(
                    &Abuf[(size_t)(wm * 64 + mt * 16 + l15) * 64 + swz]);
            #pragma unroll
            for (int nt = 0; nt < 3; nt++)
                bq[nt] = *reinterpret_cast<const short8*>(
                    &Bbuf[(size_t)(wn * 48 + nt * 16 + l15) * 64 + swz]);
            #pragma unroll
            for (int mt = 0; mt < 4; mt++)
                #pragma unroll
                for (int nt = 0; nt < 3; nt++)
                    acc[mt][nt] = __builtin_amdgcn_mfma_f32_16x16x32_bf16(
                        a[mt], bq[nt], acc[mt][nt], 0, 0, 0);
        }
    };

    for (int p = 0; p < 41; ++p) {
        STAGE(p);
        __syncthreads();
        COMPUTE();
        __syncthreads();
    }

    #pragma unroll
    for (int nt = 0; nt < 3; nt++) {
        int pxl = wn * 48 + nt * 16 + l15;
        #pragma unroll
        for (int mt = 0; mt < 4; mt++) {
            int ocb = wm * 64 + mt * 16 + lk * 4;
            float4 bias = *reinterpret_cast<const float4*>(b1 + ocb);
            const float* bp = reinterpret_cast<const float*>(&bias);
            ushort4 u;
            u.x = bfb(fmaxf(acc[mt][nt][0] + bp[0], 0.f));
            u.y = bfb(fmaxf(acc[mt][nt][1] + bp[1], 0.f));
            u.z = bfb(fmaxf(acc[mt][nt][2] + bp[2], 0.f));
            u.w = bfb(fmaxf(acc[mt][nt][3] + bp[3], 0.f));
            int chunk = (ocb >> 3) ^ (pxl & 7);
            *reinterpret_cast<ushort4*>(&S[(size_t)pxl * 128 + chunk * 8 + (lk & 1) * 4]) = u;
        }
    }
    __syncthreads();
    {
        bf16* dst = hmidp + (size_t)b * HPW * 128 + ((size_t)(row + 1) * HP_ + 1) * 128;
        #pragma unroll
        for (int i = 0; i < 6; i++) {
            int f = tid + i * 256;
            int px = f >> 4, cc = f & 15;
            short8 v = *reinterpret_cast<const short8*>(
                &S[(size_t)px * 128 + (cc ^ (px & 7)) * 8]);
            *reinterpret_cast<short8*>(dst + (size_t)f * 8) = v;
        }
    }
}

// ---------------------------------------------------------------- conv2 ----
__global__ __launch_bounds__(256)
void conv2_mfma(const bf16* __restrict__ hmidp, const bf16* __restrict__ w2bf,
                const float* __restrict__ b2, float* __restrict__ out)
{
    __shared__ bf16 Abuf[1024];
    __shared__ bf16 Bbuf[8192];
    int gid = blockIdx.x;             // 576 = 8 b x 72 px-tiles
    int b = gid & 7;
    int p0 = (gid >> 3) * 128;
    int tid = threadIdx.x, lane = tid & 63;
    int wn = tid >> 6;
    int l15 = lane & 15, lk = lane >> 4;
    const bf16* hb = hmidp + (size_t)b * HPW * 128;

    int wbase = tid & 192;
    int t3 = (tid >> 3) & 7;
    int cX = (tid & 7) ^ t3;
    int r0 = tid >> 3;
    int posB[4];
    #pragma unroll
    for (int i = 0; i < 4; i++) {
        int px = p0 + i * 32 + r0;
        posB[i] = (px / 96) * HP_ + (px % 96);
    }
    int swzE0 = ((lk) ^ (l15 & 7)) * 8;
    int swzE1 = ((4 + lk) ^ (l15 & 7)) * 8;

    f32x4 acc[2] = {};

    auto STAGE = [&](int s) {
        int tap = s >> 1, half = s & 1;
        int toff = (tap / 3) * HP_ + (tap % 3);
        if (tid < 128)
            gload_lds16(w2bf + ((size_t)s * 16 + r0) * 64 + cX * 8,
                        &Abuf[(size_t)(tid & 192) * 8]);
        #pragma unroll
        for (int i = 0; i < 4; i++)
            gload_lds16(hb + (size_t)(posB[i] + toff) * 128 + half * 64 + cX * 8,
                        &Bbuf[(size_t)(i * 256 + wbase) * 8]);
    };

    auto COMPUTE = [&]() {
        #pragma unroll
        for (int k = 0; k < 2; k++) {
            int swz = k ? swzE1 : swzE0;
            short8 a = *reinterpret_cast<const short8*>(&Abuf[(size_t)l15 * 64 + swz]);
            #pragma unroll
            for (int nt = 0; nt < 2; nt++) {
                short8 bq = *reinterpret_cast<const short8*>(
                    &Bbuf[(size_t)(wn * 32 + nt * 16 + l15) * 64 + swz]);
                acc[nt] = __builtin_amdgcn_mfma_f32_16x16x32_bf16(a, bq, acc[nt], 0, 0, 0);
            }
        }
    };

    for (int s = 0; s < 18; ++s) {
        STAGE(s);
        __syncthreads();
        COMPUTE();
        __syncthreads();
    }

    if (lk == 0) {
        float bb0 = b2[0], bb1 = b2[1];
        #pragma unroll
        for (int nt = 0; nt < 2; nt++) {
            int px = p0 + wn * 32 + nt * 16 + l15;
            out[((size_t)b * 2 + 0) * HW_ + px] = acc[nt][0] + bb0;
            out[((size_t)b * 2 + 1) * HW_ + px] = acc[nt][1] + bb1;
        }
    }
}

// ---------------------------------------------------------------- launch ----
extern "C" void kernel_launch(void* const* d_in, const int* in_sizes, int n_in,
                              void* d_out, int out_size, void* d_ws, size_t ws_size,
                              hipStream_t stream)
{
    const float* cur_embed  = (const float*)d_in[0];
    const float* cur_decode = (const float*)d_in[1];
    const float* init_embed = (const float*)d_in[2];
    const float* init_seg   = (const float*)d_in[3];
    const float* prev_embed = (const float*)d_in[4];
    const float* prev_seg   = (const float*)d_in[5];
    const float* W1 = (const float*)d_in[6];
    const float* b1 = (const float*)d_in[7];
    const float* W2 = (const float*)d_in[8];
    const float* b2 = (const float*)d_in[9];
    float* out = (float*)d_out;

    char* ws = (char*)d_ws;
    bf16* hcat8 = (bf16*)ws;
    bf16* curbf = (bf16*)ws;                          // alias (dead after lmap)
    bf16* hcat1 = (bf16*)(ws + 39337984);
    const size_t HCAT_REGION = 40567296;
    bf16* hmidp  = (bf16*)(ws + HCAT_REGION);
    bf16* fibf   = (bf16*)(ws + HCAT_REGION);
    bf16* prevbf = (bf16*)(ws + HCAT_REGION);
    float* si  = (float*)(ws + HCAT_REGION + 2621440);
    bf16* w1bf = (bf16*)(ws + 60236288);
    bf16* w2bf = (bf16*)(ws + 60908032);
    float* gout = (float*)(ws + 60944896);
    float* lout = (float*)(ws + 61534720);
    const bf16* zbuf = w1bf + (size_t)81 * 4096;      // slab 81 = zeros

    { int total = 82 * 128 * 32;
      w1cvt_kernel<<<(total + 255) / 256, 256, 0, stream>>>(W1, w1bf); }
    { int total = 18 * 16 * 64;
      w2cvt_kernel<<<(total + 255) / 256, 256, 0, stream>>>(W2, w2bf); }
    { dim3 g(144, 4, B_);
      tcur_kernel<<<g, 256, 0, stream>>>(cur_embed, curbf); }
    { int total = B_ * (C_ + 2) * KPP;
      pool_kernel<<<(total + 255) / 256, 256, 0, stream>>>(init_embed, init_seg, fibf, si); }
    { gmap_mfma<<<576, 256, 0, stream>>>(curbf, fibf, si, gout); }
    for (int g = 0; g < 2; g++) {
        dim3 gt(144, 4, 4);
        tcur_kernel<<<gt, 256, 0, stream>>>(prev_embed + (size_t)g * 4 * C_ * HW_, prevbf);
        dim3 gl(144, 4);
        lmap_mfma<<<gl, 256, 0, stream>>>(curbf, prevbf, zbuf, prev_seg, lout, g * 4);
    }
    { int total = B_ * 388;
      zero_border_kernel<<<(total + 255) / 256, 256, 0, stream>>>(hcat8, hcat1, hmidp); }
    { dim3 g(144, 4, B_);
      pack_dec_kernel<<<g, 256, 0, stream>>>(cur_decode, hcat8); }
    { int total = B_ * HW_;
      pack_small_kernel<<<(total + 255) / 256, 256, 0, stream>>>(gout, lout, init_seg, prev_seg, hcat1); }
    { conv1_mfma<<<768, 256, 0, stream>>>(hcat8, hcat1, w1bf, b1, hmidp); }
    { conv2_mfma<<<576, 256, 0, stream>>>(hmidp, w2bf, b2, out); }
}

// Round 15
// 253.307 us; speedup vs baseline: 2.9374x; 1.0427x over previous
//
#include <hip/hip_runtime.h>
#include <hip/hip_bf16.h>

// Round 15: gmap + conv2 rebalanced to row-aligned 96px tiles / grid 768
//           (3.0 blocks/CU, the r13 conv1 mechanism); w1cvt+w2cvt merged.
//           Everything else identical to r14 (passing, 264 us).
// ws layout (62.12 MB, aliased):
//   [0, 39,337,984)           hcat8 bf16 [8][8][9604][32]   -- ALSO curbf bf16 [8][9216][256]
//   [39,337,984, 40,567,296)  hcat1 bf16 [8][9604][8]
//   [40,567,296, 60,236,288)  hmid_pad bf16 [8][9604][128]
//       -- phase1 alias: fibf bf16 [8][640][256] @ +0, si f32 [8][2][640] @ +2,621,440
//       -- phase2 alias: prevbf bf16 [4][9216][256]
//   [60,236,288, 60,908,032)  W1bf bf16 [82][128][32]  (slab 81 = zeros; doubles as zbuf)
//   [60,908,032, 60,944,896)  W2bf bf16 [18][16][64]
//   [60,944,896, 61,534,720)  gout f32 [8][2][9216]
//   [61,534,720, 62,124,544)  lout f32 [8][2][9216]

typedef __hip_bfloat16 bf16;
typedef __attribute__((ext_vector_type(8))) short short8;
typedef __attribute__((ext_vector_type(4))) float f32x4;

constexpr int B_  = 8;
constexpr int C_  = 256;
constexpr int H_  = 96;
constexpr int W_  = 96;
constexpr int HW_ = H_ * W_;       // 9216
constexpr int PW_ = 24;
constexpr int KP_ = 576;
constexpr int KPP = 640;
constexpr int HP_ = 98;
constexpr int HPW = HP_ * HP_;     // 9604
constexpr int C1O = 128;
constexpr int CHK = HPW * 32;

__device__ __forceinline__ unsigned short bfb(float f) {
    bf16 h = __float2bfloat16(f);
    return *reinterpret_cast<unsigned short*>(&h);
}

__device__ __forceinline__ void gload_lds16(const bf16* g, bf16* l) {
    __builtin_amdgcn_global_load_lds((const void*)g, (void*)l, 16, 0, 0);
}

// ------------------------------------------------------------ W convert ----
// W1bf slab s = icc*9+tap : [128 oc][32 ic], slab 81 zeros; then W2bf appended.
__global__ __launch_bounds__(256)
void wcvt_kernel(const float* __restrict__ W1, const float* __restrict__ W2,
                 bf16* __restrict__ w1bf, bf16* __restrict__ w2bf)
{
    int idx = blockIdx.x * 256 + threadIdx.x;
    if (idx < 82 * 128 * 32) {
        int ic = idx & 31;
        int oc = (idx >> 5) & 127;
        int ks = idx >> 12;
        int icc = ks / 9, tap = ks % 9;
        int icg = icc * 32 + ic;
        float v = (icg < 264) ? W1[((size_t)oc * 264 + icg) * 9 + tap] : 0.f;
        w1bf[idx] = __float2bfloat16(v);
    } else {
        int j = idx - 82 * 128 * 32;
        if (j >= 18 * 16 * 64) return;
        int c  = j & 63;
        int oc = (j >> 6) & 15;
        int s  = j >> 10;
        int tap = s >> 1, half = s & 1;
        float v = (oc < 2) ? W2[((size_t)oc * 128 + half * 64 + c) * 9 + tap] : 0.f;
        w2bf[j] = __float2bfloat16(v);
    }
}

// ------------------------------------------------------- NCHW->NHWC bf16 ----
__global__ __launch_bounds__(256)
void tcur_kernel(const float* __restrict__ cur, bf16* __restrict__ curbf)
{
    __shared__ float tile[64][68];
    int b = blockIdx.z, c0 = blockIdx.y * 64, p0 = blockIdx.x * 64;
    int t = threadIdx.x;
    const float* src = cur + ((size_t)b * C_ + c0) * HW_ + p0;
    #pragma unroll
    for (int it = 0; it < 4; it++) {
        int f = t + it * 256;
        int cl = f >> 4, p4 = (f & 15) * 4;
        float4 v = *reinterpret_cast<const float4*>(src + (size_t)cl * HW_ + p4);
        *reinterpret_cast<float4*>(&tile[cl][p4]) = v;
    }
    __syncthreads();
    bf16* dst = curbf + ((size_t)b * HW_ + p0) * 256 + c0;
    #pragma unroll
    for (int it = 0; it < 4; it++) {
        int f = t + it * 256;
        int pl = f >> 4, c4 = (f & 15) * 4;
        ushort4 u;
        u.x = bfb(tile[c4 + 0][pl]); u.y = bfb(tile[c4 + 1][pl]);
        u.z = bfb(tile[c4 + 2][pl]); u.w = bfb(tile[c4 + 3][pl]);
        *reinterpret_cast<ushort4*>(dst + (size_t)pl * 256 + c4) = u;
    }
}

// ---------------------------------------------------------------- pool ----
__global__ __launch_bounds__(256)
void pool_kernel(const float* __restrict__ init_embed,
                 const float* __restrict__ init_seg,
                 bf16* __restrict__ fibf, float* __restrict__ si)
{
    int idx = blockIdx.x * 256 + threadIdx.x;
    int total = B_ * (C_ + 2) * KPP;
    if (idx >= total) return;
    int k  = idx % KPP;
    int ch = (idx / KPP) % (C_ + 2);
    int b  = idx / (KPP * (C_ + 2));
    float s = 0.f;
    if (k < KP_) {
        int ph = k / PW_, pw = k % PW_;
        const float* src = (ch < C_)
            ? (init_embed + (((size_t)b * C_ + ch) * H_ + ph * 4) * W_ + pw * 4)
            : (init_seg   + (((size_t)b * 2 + (ch - C_)) * H_ + ph * 4) * W_ + pw * 4);
        #pragma unroll
        for (int r = 0; r < 4; r++) {
            float4 v = *reinterpret_cast<const float4*>(src + r * W_);
            s += v.x + v.y + v.z + v.w;
        }
        s *= (1.f / 16.f);
    }
    if (ch < C_) fibf[((size_t)b * KPP + k) * C_ + ch] = __float2bfloat16(s);
    else         si[(size_t)b * 2 * KPP + (ch - C_) * KPP + k] = s;
}

// ---------------------------------------------------------------- gmap ----
// Row-aligned LDS-GEMM: 128 kp x 96 px, 4 waves (2M x 2N), BK=64, 20 K-steps,
// per-chunk seg-max epilogue, grid 768 (3 blocks/CU), 1 batch/XCD.
__global__ __launch_bounds__(256)
void gmap_mfma(const bf16* __restrict__ curbf, const bf16* __restrict__ fibf,
               const float* __restrict__ si, float* __restrict__ gout)
{
    __shared__ bf16 Abuf[8192];       // 128 kp x 64 ch  16 KB
    __shared__ bf16 Bbuf[6144];       //  96 px x 64 ch  12 KB
    __shared__ float bred[2][2][2][48];
    int gid = blockIdx.x;             // 768 = 8 b x 96 px-tiles
    int b = gid & 7;
    int p0 = (gid >> 3) * 96;
    int tid = threadIdx.x, lane = tid & 63;
    int w = tid >> 6, wm = w & 1, wn = w >> 1;
    int l15 = lane & 15, lk = lane >> 4;
    const bf16* fb = fibf + (size_t)b * KPP * 256;
    const bf16* cb = curbf + (size_t)b * HW_ * 256;
    const float* sib = si + (size_t)b * 2 * KPP;

    int wbase = tid & 192;
    int t3 = (tid >> 3) & 7;
    int cX = (tid & 7) ^ t3;
    int r0 = tid >> 3;
    int swzE0 = ((lk) ^ (l15 & 7)) * 8;
    int swzE1 = ((4 + lk) ^ (l15 & 7)) * 8;

    float best[2][3];
    #pragma unroll
    for (int s = 0; s < 2; s++)
        #pragma unroll
        for (int nt = 0; nt < 3; nt++) best[s][nt] = -INFINITY;
    f32x4 acc[4][3] = {};

    auto STAGE = [&](int q) {
        int chunk = q >> 2, ks = q & 3;
        int koff = ks * 64 + cX * 8;
        #pragma unroll
        for (int i = 0; i < 4; i++) {
            int row = i * 32 + r0;
            gload_lds16(fb + (size_t)(chunk * 128 + row) * 256 + koff,
                        &Abuf[(size_t)(i * 256 + wbase) * 8]);
        }
        #pragma unroll
        for (int i = 0; i < 3; i++) {
            int row = i * 32 + r0;
            gload_lds16(cb + (size_t)(p0 + row) * 256 + koff,
                        &Bbuf[(size_t)(i * 256 + wbase) * 8]);
        }
    };

    auto COMPUTE = [&]() {
        #pragma unroll
        for (int k = 0; k < 2; k++) {
            int swz = k ? swzE1 : swzE0;
            short8 a[4], bq[3];
            #pragma unroll
            for (int mt = 0; mt < 4; mt++)
                a[mt] = *reinterpret_cast<const short8*>(
                    &Abuf[(size_t)(wm * 64 + mt * 16 + l15) * 64 + swz]);
            #pragma unroll
            for (int nt = 0; nt < 3; nt++)
                bq[nt] = *reinterpret_cast<const short8*>(
                    &Bbuf[(size_t)(wn * 48 + nt * 16 + l15) * 64 + swz]);
            #pragma unroll
            for (int mt = 0; mt < 4; mt++)
                #pragma unroll
                for (int nt = 0; nt < 3; nt++)
                    acc[mt][nt] = __builtin_amdgcn_mfma_f32_16x16x32_bf16(
                        a[mt], bq[nt], acc[mt][nt], 0, 0, 0);
        }
    };

    for (int q = 0; q < 20; ++q) {
        STAGE(q);
        __syncthreads();
        COMPUTE();
        if ((q & 3) == 3) {
            int kp0 = (q >> 2) * 128;
            #pragma unroll
            for (int mt = 0; mt < 4; mt++) {
                int rb = kp0 + wm * 64 + mt * 16 + lk * 4;
                float4 s0 = *reinterpret_cast<const float4*>(sib + rb);
                float4 s1 = *reinterpret_cast<const float4*>(sib + KPP + rb);
                const float* s0p = reinterpret_cast<const float*>(&s0);
                const float* s1p = reinterpret_cast<const float*>(&s1);
                #pragma unroll
                for (int nt = 0; nt < 3; nt++) {
                    #pragma unroll
                    for (int r = 0; r < 4; r++) {
                        float v = acc[mt][nt][r];
                        best[0][nt] = fmaxf(best[0][nt], v * s0p[r]);
                        best[1][nt] = fmaxf(best[1][nt], v * s1p[r]);
                    }
                    acc[mt][nt] = (f32x4){0.f, 0.f, 0.f, 0.f};
                }
            }
        }
        __syncthreads();
    }
    #pragma unroll
    for (int s = 0; s < 2; s++)
        #pragma unroll
        for (int nt = 0; nt < 3; nt++) {
            float v = best[s][nt];
            v = fmaxf(v, __shfl_xor(v, 16));
            v = fmaxf(v, __shfl_xor(v, 32));
            if (lk == 0) bred[wm][wn][s][nt * 16 + l15] = v;
        }
    __syncthreads();
    if (tid < 192) {
        int s2 = tid / 96, pxl = tid % 96;
        float v = fmaxf(bred[0][pxl / 48][s2][pxl % 48],
                        bred[1][pxl / 48][s2][pxl % 48]);
        gout[((size_t)b * 2 + s2) * HW_ + p0 + pxl] = v;
    }
}

// ---------------------------------------------------------------- lmap ----
__global__ __launch_bounds__(256)
void lmap_mfma(const bf16* __restrict__ curbf, const bf16* __restrict__ prevbf,
               const bf16* __restrict__ zbuf,
               const float* __restrict__ prev_seg, float* __restrict__ lout, int b0)
{
    constexpr int GSTR = 257;
    constexpr int SEGB = 64 * GSTR;
    constexpr int REDB = SEGB + 512;
    __shared__ __align__(16) char Smem[(REDB + 256) * 4];
    bf16* Abuf = (bf16*)Smem;
    bf16* Bbuf = (bf16*)(Smem + 8192);
    float* gl  = (float*)Smem;

    int b = b0 + blockIdx.y;
    const bf16* pb = prevbf + (size_t)blockIdx.y * HW_ * 256;
    const bf16* cb = curbf + (size_t)b * HW_ * 256;
    int tile = blockIdx.x;
    int ty0 = (tile / 12) * 8, tx0 = (tile % 12) * 8;
    int tid = threadIdx.x, lane = tid & 63, wn = tid >> 6;
    int l15 = lane & 15, lk = lane >> 4;

    int wbase = tid & 192;
    int t3 = (tid >> 3) & 7;
    int cX = (tid & 7) ^ t3;
    int r0 = tid >> 3;
    int swzE0 = ((lk) ^ (l15 & 7)) * 8;
    int swzE1 = ((4 + lk) ^ (l15 & 7)) * 8;

    int gpxA0 = (ty0 + (r0 >> 3)) * W_ + tx0 + (r0 & 7);
    int gpxA1 = (ty0 + (r0 >> 3) + 4) * W_ + tx0 + (r0 & 7);
    const bf16* rowB[8];
    #pragma unroll
    for (int i = 0; i < 8; i++) {
        int wrow = i * 32 + r0;
        int wy = wrow >> 4, wx = wrow & 15;
        int gy = ty0 - 4 + wy, gx = tx0 - 4 + wx;
        bool ok = (gy >= 0) && (gy < H_) && (gx >= 0) && (gx < W_);
        rowB[i] = ok ? (pb + (size_t)(gy * W_ + gx) * 256) : zbuf;
    }

    f32x4 acc[4][4] = {};

    for (int ks = 0; ks < 4; ++ks) {
        int koff = ks * 64 + cX * 8;
        gload_lds16(cb + (size_t)gpxA0 * 256 + koff, &Abuf[(size_t)(wbase) * 8]);
        gload_lds16(cb + (size_t)gpxA1 * 256 + koff, &Abuf[(size_t)(256 + wbase) * 8]);
        #pragma unroll
        for (int i = 0; i < 8; i++)
            gload_lds16(rowB[i] + koff, &Bbuf[(size_t)(i * 256 + wbase) * 8]);
        __syncthreads();
        #pragma unroll
        for (int k = 0; k < 2; k++) {
            int swz = k ? swzE1 : swzE0;
            short8 a[4], bq[4];
            #pragma unroll
            for (int mt = 0; mt < 4; mt++)
                a[mt] = *reinterpret_cast<const short8*>(
                    &Abuf[(size_t)(mt * 16 + l15) * 64 + swz]);
            #pragma unroll
            for (int nt = 0; nt < 4; nt++)
                bq[nt] = *reinterpret_cast<const short8*>(
                    &Bbuf[(size_t)(wn * 64 + nt * 16 + l15) * 64 + swz]);
            #pragma unroll
            for (int mt = 0; mt < 4; mt++)
                #pragma unroll
                for (int nt = 0; nt < 4; nt++)
                    acc[mt][nt] = __builtin_amdgcn_mfma_f32_16x16x32_bf16(
                        a[mt], bq[nt], acc[mt][nt], 0, 0, 0);
        }
        __syncthreads();
    }

    #pragma unroll
    for (int mt = 0; mt < 4; mt++)
        #pragma unroll
        for (int nt = 0; nt < 4; nt++)
            #pragma unroll
            for (int r = 0; r < 4; r++)
                gl[(mt * 16 + lk * 4 + r) * GSTR + wn * 64 + nt * 16 + l15] = acc[mt][nt][r];
    #pragma unroll
    for (int it = 0; it < 2; it++) {
        int f = tid + it * 256;
        int s = f >> 8, wp = f & 255;
        int wy = wp >> 4, wx = wp & 15;
        int gy = ty0 - 4 + wy, gxx = tx0 - 4 + wx;
        float v = 0.f;
        if (gy >= 0 && gy < H_ && gxx >= 0 && gxx < W_)
            v = prev_seg[((size_t)b * 2 + s) * HW_ + gy * W_ + gxx] * (1.f / 256.f);
        gl[SEGB + f] = v;
    }
    __syncthreads();
    {
        int m = tid & 63;
        int sh = tid >> 6;
        int s = sh >> 1, hh = sh & 1;
        int py = m >> 3, lx = m & 7;
        const float* gr = gl + m * GSTR;
        const float* sr = gl + SEGB + s * 256;
        float mx = -INFINITY;
        int wr0 = hh * 5, wr1 = hh ? 9 : 5;
        for (int wr = wr0; wr < wr1; ++wr) {
            int base = (py + wr) * 16 + lx;
            #pragma unroll
            for (int wc = 0; wc < 9; ++wc)
                mx = fmaxf(mx, gr[base + wc] * sr[base + wc]);
        }
        gl[REDB + sh * 64 + m] = mx;
    }
    __syncthreads();
    if (tid < 128) {
        int s = tid >> 6, m = tid & 63;
        float v = fmaxf(gl[REDB + (s * 2 + 0) * 64 + m], gl[REDB + (s * 2 + 1) * 64 + m]);
        int gpx = (ty0 + (m >> 3)) * W_ + tx0 + (m & 7);
        lout[((size_t)b * 2 + s) * HW_ + gpx] = v;
    }
}

// ---------------------------------------------------------------- packs ----
__global__ __launch_bounds__(256)
void pack_dec_kernel(const float* __restrict__ dec, bf16* __restrict__ hcat8)
{
    __shared__ float tile[64][68];
    int b = blockIdx.z, c0 = blockIdx.y * 64, p0 = blockIdx.x * 64;
    int t = threadIdx.x;
    const float* src = dec + ((size_t)b * C_ + c0) * HW_ + p0;
    #pragma unroll
    for (int it = 0; it < 4; it++) {
        int f = t + it * 256;
        int cl = f >> 4, p4 = (f & 15) * 4;
        float4 v = *reinterpret_cast<const float4*>(src + (size_t)cl * HW_ + p4);
        *reinterpret_cast<float4*>(&tile[cl][p4]) = v;
    }
    __syncthreads();
    #pragma unroll
    for (int it = 0; it < 4; it++) {
        int f = t + it * 256;
        int pl = f >> 4, c4 = (f & 15) * 4;
        int p = p0 + pl;
        int y = p / 96, x = p % 96;
        int pos = (y + 1) * HP_ + x + 1;
        int ch = c0 + c4;
        ushort4 u;
        u.x = bfb(tile[c4 + 0][pl]); u.y = bfb(tile[c4 + 1][pl]);
        u.z = bfb(tile[c4 + 2][pl]); u.w = bfb(tile[c4 + 3][pl]);
        bf16* dst = hcat8 + ((size_t)b * 8 + (ch >> 5)) * CHK + (size_t)pos * 32 + (ch & 31);
        *reinterpret_cast<ushort4*>(dst) = u;
    }
}

__global__ __launch_bounds__(256)
void pack_small_kernel(const float* __restrict__ gout,
                       const float* __restrict__ lout,
                       const float* __restrict__ init_seg,
                       const float* __restrict__ prev_seg,
                       bf16* __restrict__ hcat1)
{
    int idx = blockIdx.x * 256 + threadIdx.x;
    if (idx >= B_ * HW_) return;
    int b = idx / HW_, p = idx % HW_;
    int y = p / 96, x = p % 96;
    int pos = (y + 1) * HP_ + x + 1;
    bf16* dst = hcat1 + ((size_t)b * HPW + pos) * 8;
    float g0 = gout[((size_t)b * 2 + 0) * HW_ + p];
    float g1 = gout[((size_t)b * 2 + 1) * HW_ + p];
    float i0 = init_seg[((size_t)b * 2 + 0) * HW_ + p];
    float i1 = init_seg[((size_t)b * 2 + 1) * HW_ + p];
    float l0 = lout[((size_t)b * 2 + 0) * HW_ + p];
    float l1 = lout[((size_t)b * 2 + 1) * HW_ + p];
    float q0 = prev_seg[((size_t)b * 2 + 0) * HW_ + p];
    float q1 = prev_seg[((size_t)b * 2 + 1) * HW_ + p];
    ushort4 u; u.x = bfb(g0); u.y = bfb(g1); u.z = bfb(i0); u.w = bfb(i1);
    *reinterpret_cast<ushort4*>(dst) = u;
    ushort4 u2; u2.x = bfb(l0); u2.y = bfb(l1); u2.z = bfb(q0); u2.w = bfb(q1);
    *reinterpret_cast<ushort4*>(dst + 4) = u2;
}

// ------------------------------------------------------------ border zero ----
__global__ __launch_bounds__(256)
void zero_border_kernel(bf16* __restrict__ hcat8, bf16* __restrict__ hcat1,
                        bf16* __restrict__ hmidp)
{
    int idx = blockIdx.x * 256 + threadIdx.x;
    if (idx >= B_ * 388) return;
    int b = idx / 388, bi = idx % 388;
    int pos;
    if (bi < 98) pos = bi;
    else if (bi < 196) pos = 97 * HP_ + (bi - 98);
    else if (bi < 292) pos = (bi - 196 + 1) * HP_;
    else pos = (bi - 292 + 1) * HP_ + 97;
    const short8 Z = {0, 0, 0, 0, 0, 0, 0, 0};
    #pragma unroll
    for (int c = 0; c < 8; c++) {
        bf16* p = hcat8 + ((size_t)b * 8 + c) * CHK + (size_t)pos * 32;
        #pragma unroll
        for (int j = 0; j < 4; j++)
            *reinterpret_cast<short8*>(p + j * 8) = Z;
    }
    *reinterpret_cast<short8*>(hcat1 + ((size_t)b * HPW + pos) * 8) = Z;
    bf16* q = hmidp + ((size_t)b * HPW + pos) * 128;
    #pragma unroll
    for (int j = 0; j < 16; j++)
        *reinterpret_cast<short8*>(q + j * 8) = Z;
}

// ---------------------------------------------------------------- conv1 ----
__global__ __launch_bounds__(256)
void conv1_mfma(const bf16* __restrict__ hcat8, const bf16* __restrict__ hcat1,
                const bf16* __restrict__ w1bf, const float* __restrict__ b1,
                bf16* __restrict__ hmidp)
{
    __shared__ bf16 S[14336];
    bf16* Abuf = S;
    bf16* Bbuf = S + 8192;
    int gid = blockIdx.x;                     // 768 = 8 b x 96 rows
    int b = gid & 7;
    int row = gid >> 3;
    int tid = threadIdx.x, lane = tid & 63;
    int w = tid >> 6, wm = w & 1, wn = w >> 1;
    int l15 = lane & 15, lk = lane >> 4;
    const bf16* hb8 = hcat8 + (size_t)b * 8 * CHK;
    const bf16* hb1 = hcat1 + (size_t)b * HPW * 8;

    int wbase = tid & 192;
    int t3 = (tid >> 3) & 7;
    int cX = (tid & 7) ^ t3;
    int selX = cX >> 2;
    int cin8 = (cX & 3) * 8;
    int r0 = tid >> 3;
    int swzE0 = ((lk) ^ (l15 & 7)) * 8;
    int swzE1 = ((4 + lk) ^ (l15 & 7)) * 8;

    f32x4 acc[4][3] = {};

    auto STAGE = [&](int p) {
        int s0 = 2 * p, s1 = s0 + 1;
        int icc0 = s0 / 9, tap0 = s0 - icc0 * 9;
        int icc1 = s1 / 9, tap1 = s1 - icc1 * 9;
        const bf16* gA = w1bf + (size_t)p * 8192 + (size_t)selX * 4096 + cin8;
        #pragma unroll
        for (int i = 0; i < 4; i++)
            gload_lds16(gA + (i * 32 + r0) * 32,
                        &Abuf[(size_t)(i * 256 + wbase) * 8]);
        int tapS = selX ? tap1 : tap0;
        int iccS = selX ? icc1 : icc0;
        int posT = (row + tapS / 3) * HP_ + (tapS % 3);
        bool is8 = (iccS >= 8);
        const bf16* gb = is8 ? hb1 : (hb8 + (size_t)iccS * CHK);
        #pragma unroll
        for (int i = 0; i < 3; i++) {
            int c = i * 32 + r0;
            const bf16* g = is8 ? (gb + (size_t)(posT + c) * 8)
                                : (gb + (size_t)(posT + c) * 32 + cin8);
            gload_lds16(g, &Bbuf[(size_t)(i * 256 + wbase) * 8]);
        }
    };

    auto COMPUTE = [&]() {
        #pragma unroll
        for (int k = 0; k < 2; k++) {
            int swz = k ? swzE1 : swzE0;
            short8 a[4], bq[3];
            #pragma unroll
            for (int mt = 0; mt < 4; mt++)
                a[mt] = *reinterpret_cast<const short8*>(
                    &Abuf[(size_t)(wm * 64 + mt * 16 + l15) * 64 + swz]);
            #pragma unroll
            for (int nt = 0; nt < 3; nt++)
                bq[nt] = *reinterpret_cast<const short8*>(
                    &Bbuf[(size_t)(wn * 48 + nt * 16 + l15) * 64 + swz]);
            #pragma unroll
            for (int mt = 0; mt < 4; mt++)
                #pragma unroll
                for (int nt = 0; nt < 3; nt++)
                    acc[mt][nt] = __builtin_amdgcn_mfma_f32_16x16x32_bf16(
                        a[mt], bq[nt], acc[mt][nt], 0, 0, 0);
        }
    };

    for (int p = 0; p < 41; ++p) {
        STAGE(p);
        __syncthreads();
        COMPUTE();
        __syncthreads();
    }

    #pragma unroll
    for (int nt = 0; nt < 3; nt++) {
        int pxl = wn * 48 + nt * 16 + l15;
        #pragma unroll
        for (int mt = 0; mt < 4; mt++) {
            int ocb = wm * 64 + mt * 16 + lk * 4;
            float4 bias = *reinterpret_cast<const float4*>(b1 + ocb);
            const float* bp = reinterpret_cast<const float*>(&bias);
            ushort4 u;
            u.x = bfb(fmaxf(acc[mt][nt][0] + bp[0], 0.f));
            u.y = bfb(fmaxf(acc[mt][nt][1] + bp[1], 0.f));
            u.z = bfb(fmaxf(acc[mt][nt][2] + bp[2], 0.f));
            u.w = bfb(fmaxf(acc[mt][nt][3] + bp[3], 0.f));
            int chunk = (ocb >> 3) ^ (pxl & 7);
            *reinterpret_cast<ushort4*>(&S[(size_t)pxl * 128 + chunk * 8 + (lk & 1) * 4]) = u;
        }
    }
    __syncthreads();
    {
        bf16* dst = hmidp + (size_t)b * HPW * 128 + ((size_t)(row + 1) * HP_ + 1) * 128;
        #pragma unroll
        for (int i = 0; i < 6; i++) {
            int f = tid + i * 256;
            int px = f >> 4, cc = f & 15;
            short8 v = *reinterpret_cast<const short8*>(
                &S[(size_t)px * 128 + (cc ^ (px & 7)) * 8]);
            *reinterpret_cast<short8*>(dst + (size_t)f * 8) = v;
        }
    }
}

// ---------------------------------------------------------------- conv2 ----
// Row-aligned: 16oc_pad x 96px, 2 waves (128 thr), grid 768, 14KB LDS.
__global__ __launch_bounds__(128)
void conv2_mfma(const bf16* __restrict__ hmidp, const bf16* __restrict__ w2bf,
                const float* __restrict__ b2, float* __restrict__ out)
{
    __shared__ bf16 Abuf[1024];       // 16 x 64   2 KB
    __shared__ bf16 Bbuf[6144];       // 96 x 64  12 KB
    int gid = blockIdx.x;             // 768 = 8 b x 96 rows
    int b = gid & 7;
    int y = gid >> 3;                 // image row
    int p0 = y * 96;
    int tid = threadIdx.x, lane = tid & 63;
    int wn = tid >> 6;                // 0..1, wave owns 48 px
    int l15 = lane & 15, lk = lane >> 4;
    const bf16* hb = hmidp + (size_t)b * HPW * 128;

    int wbase = tid & 64;
    int t3 = (tid >> 3) & 7;
    int cX = (tid & 7) ^ t3;
    int r0 = tid >> 3;                // 0..15
    int swzE0 = ((lk) ^ (l15 & 7)) * 8;
    int swzE1 = ((4 + lk) ^ (l15 & 7)) * 8;

    f32x4 acc[3] = {};

    auto STAGE = [&](int s) {
        int tap = s >> 1, half = s & 1;
        int toff = (tap / 3) * HP_ + (tap % 3);
        gload_lds16(w2bf + ((size_t)s * 16 + r0) * 64 + cX * 8,
                    &Abuf[(size_t)wbase * 8]);
        #pragma unroll
        for (int i = 0; i < 6; i++) {
            int c = i * 16 + r0;
            gload_lds16(hb + (size_t)(y * HP_ + c + toff) * 128 + half * 64 + cX * 8,
                        &Bbuf[(size_t)(i * 128 + wbase) * 8]);
        }
    };

    auto COMPUTE = [&]() {
        #pragma unroll
        for (int k = 0; k < 2; k++) {
            int swz = k ? swzE1 : swzE0;
            short8 a = *reinterpret_cast<const short8*>(&Abuf[(size_t)l15 * 64 + swz]);
            #pragma unroll
            for (int nt = 0; nt < 3; nt++) {
                short8 bq = *reinterpret_cast<const short8*>(
                    &Bbuf[(size_t)(wn * 48 + nt * 16 + l15) * 64 + swz]);
                acc[nt] = __builtin_amdgcn_mfma_f32_16x16x32_bf16(a, bq, acc[nt], 0, 0, 0);
            }
        }
    };

    for (int s = 0; s < 18; ++s) {
        STAGE(s);
        __syncthreads();
        COMPUTE();
        __syncthreads();
    }

    if (lk == 0) {
        float bb0 = b2[0], bb1 = b2[1];
        #pragma unroll
        for (int nt = 0; nt < 3; nt++) {
            int px = p0 + wn * 48 + nt * 16 + l15;
            out[((size_t)b * 2 + 0) * HW_ + px] = acc[nt][0] + bb0;
            out[((size_t)b * 2 + 1) * HW_ + px] = acc[nt][1] + bb1;
        }
    }
}

// ---------------------------------------------------------------- launch ----
extern "C" void kernel_launch(void* const* d_in, const int* in_sizes, int n_in,
                              void* d_out, int out_size, void* d_ws, size_t ws_size,
                              hipStream_t stream)
{
    const float* cur_embed  = (const float*)d_in[0];
    const float* cur_decode = (const float*)d_in[1];
    const float* init_embed = (const float*)d_in[2];
    const float* init_seg   = (const float*)d_in[3];
    const float* prev_embed = (const float*)d_in[4];
    const float* prev_seg   = (const float*)d_in[5];
    const float* W1 = (const float*)d_in[6];
    const float* b1 = (const float*)d_in[7];
    const float* W2 = (const float*)d_in[8];
    const float* b2 = (const float*)d_in[9];
    float* out = (float*)d_out;

    char* ws = (char*)d_ws;
    bf16* hcat8 = (bf16*)ws;
    bf16* curbf = (bf16*)ws;                          // alias (dead after lmap)
    bf16* hcat1 = (bf16*)(ws + 39337984);
    const size_t HCAT_REGION = 40567296;
    bf16* hmidp  = (bf16*)(ws + HCAT_REGION);
    bf16* fibf   = (bf16*)(ws + HCAT_REGION);
    bf16* prevbf = (bf16*)(ws + HCAT_REGION);
    float* si  = (float*)(ws + HCAT_REGION + 2621440);
    bf16* w1bf = (bf16*)(ws + 60236288);
    bf16* w2bf = (bf16*)(ws + 60908032);
    float* gout = (float*)(ws + 60944896);
    float* lout = (float*)(ws + 61534720);
    const bf16* zbuf = w1bf + (size_t)81 * 4096;      // slab 81 = zeros

    { int total = 82 * 128 * 32 + 18 * 16 * 64;
      wcvt_kernel<<<(total + 255) / 256, 256, 0, stream>>>(W1, W2, w1bf, w2bf); }
    { dim3 g(144, 4, B_);
      tcur_kernel<<<g, 256, 0, stream>>>(cur_embed, curbf); }
    { int total = B_ * (C_ + 2) * KPP;
      pool_kernel<<<(total + 255) / 256, 256, 0, stream>>>(init_embed, init_seg, fibf, si); }
    { gmap_mfma<<<768, 256, 0, stream>>>(curbf, fibf, si, gout); }
    for (int g = 0; g < 2; g++) {
        dim3 gt(144, 4, 4);
        tcur_kernel<<<gt, 256, 0, stream>>>(prev_embed + (size_t)g * 4 * C_ * HW_, prevbf);
        dim3 gl(144, 4);
        lmap_mfma<<<gl, 256, 0, stream>>>(curbf, prevbf, zbuf, prev_seg, lout, g * 4);
    }
    { int total = B_ * 388;
      zero_border_kernel<<<(total + 255) / 256, 256, 0, stream>>>(hcat8, hcat1, hmidp); }
    { dim3 g(144, 4, B_);
      pack_dec_kernel<<<g, 256, 0, stream>>>(cur_decode, hcat8); }
    { int total = B_ * HW_;
      pack_small_kernel<<<(total + 255) / 256, 256, 0, stream>>>(gout, lout, init_seg, prev_seg, hcat1); }
    { conv1_mfma<<<768, 256, 0, stream>>>(hcat8, hcat1, w1bf, b1, hmidp); }
    { conv2_mfma<<<768, 128, 0, stream>>>(hmidp, w2bf, b2, out); }
}

// Round 16
// 242.936 us; speedup vs baseline: 3.0629x; 1.0427x over previous
//
#include <hip/hip_runtime.h>
#include <hip/hip_bf16.h>

// Round 16: lmap scan-scratch f32->bf16 (LDS 68.9KB -> 40KB, 4 blocks/CU, one
//           residency wave); wcvt+pool merged (prep); zero+pack_small+pack_dec
//           merged (packall). gmap/conv1/conv2/tcur identical to r15 (253 us).
// ws layout (62.12 MB, aliased): unchanged from r15.

typedef __hip_bfloat16 bf16;
typedef __attribute__((ext_vector_type(8))) short short8;
typedef __attribute__((ext_vector_type(4))) float f32x4;

constexpr int B_  = 8;
constexpr int C_  = 256;
constexpr int H_  = 96;
constexpr int W_  = 96;
constexpr int HW_ = H_ * W_;       // 9216
constexpr int PW_ = 24;
constexpr int KP_ = 576;
constexpr int KPP = 640;
constexpr int HP_ = 98;
constexpr int HPW = HP_ * HP_;     // 9604
constexpr int CHK = HPW * 32;

__device__ __forceinline__ unsigned short bfb(float f) {
    bf16 h = __float2bfloat16(f);
    return *reinterpret_cast<unsigned short*>(&h);
}

__device__ __forceinline__ void gload_lds16(const bf16* g, bf16* l) {
    __builtin_amdgcn_global_load_lds((const void*)g, (void*)l, 16, 0, 0);
}

// ------------------------------------------------------------ prep ----
// blocks [0,1384): W1/W2 convert ; blocks [1384,6544): pool.
__global__ __launch_bounds__(256)
void prep_kernel(const float* __restrict__ W1, const float* __restrict__ W2,
                 const float* __restrict__ init_embed, const float* __restrict__ init_seg,
                 bf16* __restrict__ w1bf, bf16* __restrict__ w2bf,
                 bf16* __restrict__ fibf, float* __restrict__ si)
{
    int gid = blockIdx.x;
    if (gid < 1384) {
        int idx = gid * 256 + threadIdx.x;
        if (idx < 82 * 128 * 32) {
            int ic = idx & 31;
            int oc = (idx >> 5) & 127;
            int ks = idx >> 12;
            int icc = ks / 9, tap = ks % 9;
            int icg = icc * 32 + ic;
            float v = (icg < 264) ? W1[((size_t)oc * 264 + icg) * 9 + tap] : 0.f;
            w1bf[idx] = __float2bfloat16(v);
        } else {
            int j = idx - 82 * 128 * 32;
            if (j >= 18 * 16 * 64) return;
            int c  = j & 63;
            int oc = (j >> 6) & 15;
            int s  = j >> 10;
            int tap = s >> 1, half = s & 1;
            float v = (oc < 2) ? W2[((size_t)oc * 128 + half * 64 + c) * 9 + tap] : 0.f;
            w2bf[j] = __float2bfloat16(v);
        }
    } else {
        int idx = (gid - 1384) * 256 + threadIdx.x;
        int k  = idx % KPP;
        int ch = (idx / KPP) % (C_ + 2);
        int b  = idx / (KPP * (C_ + 2));
        float s = 0.f;
        if (k < KP_) {
            int ph = k / PW_, pw = k % PW_;
            const float* src = (ch < C_)
                ? (init_embed + (((size_t)b * C_ + ch) * H_ + ph * 4) * W_ + pw * 4)
                : (init_seg   + (((size_t)b * 2 + (ch - C_)) * H_ + ph * 4) * W_ + pw * 4);
            #pragma unroll
            for (int r = 0; r < 4; r++) {
                float4 v = *reinterpret_cast<const float4*>(src + r * W_);
                s += v.x + v.y + v.z + v.w;
            }
            s *= (1.f / 16.f);
        }
        if (ch < C_) fibf[((size_t)b * KPP + k) * C_ + ch] = __float2bfloat16(s);
        else         si[(size_t)b * 2 * KPP + (ch - C_) * KPP + k] = s;
    }
}

// ------------------------------------------------------- NCHW->NHWC bf16 ----
__global__ __launch_bounds__(256)
void tcur_kernel(const float* __restrict__ cur, bf16* __restrict__ curbf)
{
    __shared__ float tile[64][68];
    int b = blockIdx.z, c0 = blockIdx.y * 64, p0 = blockIdx.x * 64;
    int t = threadIdx.x;
    const float* src = cur + ((size_t)b * C_ + c0) * HW_ + p0;
    #pragma unroll
    for (int it = 0; it < 4; it++) {
        int f = t + it * 256;
        int cl = f >> 4, p4 = (f & 15) * 4;
        float4 v = *reinterpret_cast<const float4*>(src + (size_t)cl * HW_ + p4);
        *reinterpret_cast<float4*>(&tile[cl][p4]) = v;
    }
    __syncthreads();
    bf16* dst = curbf + ((size_t)b * HW_ + p0) * 256 + c0;
    #pragma unroll
    for (int it = 0; it < 4; it++) {
        int f = t + it * 256;
        int pl = f >> 4, c4 = (f & 15) * 4;
        ushort4 u;
        u.x = bfb(tile[c4 + 0][pl]); u.y = bfb(tile[c4 + 1][pl]);
        u.z = bfb(tile[c4 + 2][pl]); u.w = bfb(tile[c4 + 3][pl]);
        *reinterpret_cast<ushort4*>(dst + (size_t)pl * 256 + c4) = u;
    }
}

// ---------------------------------------------------------------- gmap ----
__global__ __launch_bounds__(256)
void gmap_mfma(const bf16* __restrict__ curbf, const bf16* __restrict__ fibf,
               const float* __restrict__ si, float* __restrict__ gout)
{
    __shared__ bf16 Abuf[8192];
    __shared__ bf16 Bbuf[6144];
    __shared__ float bred[2][2][2][48];
    int gid = blockIdx.x;             // 768 = 8 b x 96 px-tiles
    int b = gid & 7;
    int p0 = (gid >> 3) * 96;
    int tid = threadIdx.x, lane = tid & 63;
    int w = tid >> 6, wm = w & 1, wn = w >> 1;
    int l15 = lane & 15, lk = lane >> 4;
    const bf16* fb = fibf + (size_t)b * KPP * 256;
    const bf16* cb = curbf + (size_t)b * HW_ * 256;
    const float* sib = si + (size_t)b * 2 * KPP;

    int wbase = tid & 192;
    int t3 = (tid >> 3) & 7;
    int cX = (tid & 7) ^ t3;
    int r0 = tid >> 3;
    int swzE0 = ((lk) ^ (l15 & 7)) * 8;
    int swzE1 = ((4 + lk) ^ (l15 & 7)) * 8;

    float best[2][3];
    #pragma unroll
    for (int s = 0; s < 2; s++)
        #pragma unroll
        for (int nt = 0; nt < 3; nt++) best[s][nt] = -INFINITY;
    f32x4 acc[4][3] = {};

    auto STAGE = [&](int q) {
        int chunk = q >> 2, ks = q & 3;
        int koff = ks * 64 + cX * 8;
        #pragma unroll
        for (int i = 0; i < 4; i++) {
            int row = i * 32 + r0;
            gload_lds16(fb + (size_t)(chunk * 128 + row) * 256 + koff,
                        &Abuf[(size_t)(i * 256 + wbase) * 8]);
        }
        #pragma unroll
        for (int i = 0; i < 3; i++) {
            int row = i * 32 + r0;
            gload_lds16(cb + (size_t)(p0 + row) * 256 + koff,
                        &Bbuf[(size_t)(i * 256 + wbase) * 8]);
        }
    };

    auto COMPUTE = [&]() {
        #pragma unroll
        for (int k = 0; k < 2; k++) {
            int swz = k ? swzE1 : swzE0;
            short8 a[4], bq[3];
            #pragma unroll
            for (int mt = 0; mt < 4; mt++)
                a[mt] = *reinterpret_cast<const short8*>(
                    &Abuf[(size_t)(wm * 64 + mt * 16 + l15) * 64 + swz]);
            #pragma unroll
            for (int nt = 0; nt < 3; nt++)
                bq[nt] = *reinterpret_cast<const short8*>(
                    &Bbuf[(size_t)(wn * 48 + nt * 16 + l15) * 64 + swz]);
            #pragma unroll
            for (int mt = 0; mt < 4; mt++)
                #pragma unroll
                for (int nt = 0; nt < 3; nt++)
                    acc[mt][nt] = __builtin_amdgcn_mfma_f32_16x16x32_bf16(
                        a[mt], bq[nt], acc[mt][nt], 0, 0, 0);
        }
    };

    for (int q = 0; q < 20; ++q) {
        STAGE(q);
        __syncthreads();
        COMPUTE();
        if ((q & 3) == 3) {
            int kp0 = (q >> 2) * 128;
            #pragma unroll
            for (int mt = 0; mt < 4; mt++) {
                int rb = kp0 + wm * 64 + mt * 16 + lk * 4;
                float4 s0 = *reinterpret_cast<const float4*>(sib + rb);
                float4 s1 = *reinterpret_cast<const float4*>(sib + KPP + rb);
                const float* s0p = reinterpret_cast<const float*>(&s0);
                const float* s1p = reinterpret_cast<const float*>(&s1);
                #pragma unroll
                for (int nt = 0; nt < 3; nt++) {
                    #pragma unroll
                    for (int r = 0; r < 4; r++) {
                        float v = acc[mt][nt][r];
                        best[0][nt] = fmaxf(best[0][nt], v * s0p[r]);
                        best[1][nt] = fmaxf(best[1][nt], v * s1p[r]);
                    }
                    acc[mt][nt] = (f32x4){0.f, 0.f, 0.f, 0.f};
                }
            }
        }
        __syncthreads();
    }
    #pragma unroll
    for (int s = 0; s < 2; s++)
        #pragma unroll
        for (int nt = 0; nt < 3; nt++) {
            float v = best[s][nt];
            v = fmaxf(v, __shfl_xor(v, 16));
            v = fmaxf(v, __shfl_xor(v, 32));
            if (lk == 0) bred[wm][wn][s][nt * 16 + l15] = v;
        }
    __syncthreads();
    if (tid < 192) {
        int s2 = tid / 96, pxl = tid % 96;
        float v = fmaxf(bred[0][pxl / 48][s2][pxl % 48],
                        bred[1][pxl / 48][s2][pxl % 48]);
        gout[((size_t)b * 2 + s2) * HW_ + p0 + pxl] = v;
    }
}

// ---------------------------------------------------------------- lmap ----
// LDS-staged Gram; G stored bf16 (stride 258) -> total LDS 40KB, 4 blocks/CU.
__global__ __launch_bounds__(256)
void lmap_mfma(const bf16* __restrict__ curbf, const bf16* __restrict__ prevbf,
               const bf16* __restrict__ zbuf,
               const float* __restrict__ prev_seg, float* __restrict__ lout, int b0)
{
    constexpr int GSTR = 258;                 // bf16 elems per G row (1-bank row skew)
    __shared__ __align__(16) char Smem[40960];
    bf16* Abuf = (bf16*)Smem;                 // 8 KB
    bf16* Bbuf = (bf16*)(Smem + 8192);        // 32 KB
    bf16* Gb   = (bf16*)Smem;                 // scan union: 64*258*2 = 33,024 B
    float* segf = (float*)(Smem + 33024);     // [2][256] = 2 KB
    float* redf = (float*)(Smem + 35072);     // [4][64]  = 1 KB

    int b = b0 + blockIdx.y;
    const bf16* pb = prevbf + (size_t)blockIdx.y * HW_ * 256;
    const bf16* cb = curbf + (size_t)b * HW_ * 256;
    int tile = blockIdx.x;
    int ty0 = (tile / 12) * 8, tx0 = (tile % 12) * 8;
    int tid = threadIdx.x, lane = tid & 63, wn = tid >> 6;
    int l15 = lane & 15, lk = lane >> 4;

    int wbase = tid & 192;
    int t3 = (tid >> 3) & 7;
    int cX = (tid & 7) ^ t3;
    int r0 = tid >> 3;
    int swzE0 = ((lk) ^ (l15 & 7)) * 8;
    int swzE1 = ((4 + lk) ^ (l15 & 7)) * 8;

    int gpxA0 = (ty0 + (r0 >> 3)) * W_ + tx0 + (r0 & 7);
    int gpxA1 = (ty0 + (r0 >> 3) + 4) * W_ + tx0 + (r0 & 7);
    const bf16* rowB[8];
    #pragma unroll
    for (int i = 0; i < 8; i++) {
        int wrow = i * 32 + r0;
        int wy = wrow >> 4, wx = wrow & 15;
        int gy = ty0 - 4 + wy, gx = tx0 - 4 + wx;
        bool ok = (gy >= 0) && (gy < H_) && (gx >= 0) && (gx < W_);
        rowB[i] = ok ? (pb + (size_t)(gy * W_ + gx) * 256) : zbuf;
    }

    f32x4 acc[4][4] = {};

    for (int ks = 0; ks < 4; ++ks) {
        int koff = ks * 64 + cX * 8;
        gload_lds16(cb + (size_t)gpxA0 * 256 + koff, &Abuf[(size_t)(wbase) * 8]);
        gload_lds16(cb + (size_t)gpxA1 * 256 + koff, &Abuf[(size_t)(256 + wbase) * 8]);
        #pragma unroll
        for (int i = 0; i < 8; i++)
            gload_lds16(rowB[i] + koff, &Bbuf[(size_t)(i * 256 + wbase) * 8]);
        __syncthreads();
        #pragma unroll
        for (int k = 0; k < 2; k++) {
            int swz = k ? swzE1 : swzE0;
            short8 a[4], bq[4];
            #pragma unroll
            for (int mt = 0; mt < 4; mt++)
                a[mt] = *reinterpret_cast<const short8*>(
                    &Abuf[(size_t)(mt * 16 + l15) * 64 + swz]);
            #pragma unroll
            for (int nt = 0; nt < 4; nt++)
                bq[nt] = *reinterpret_cast<const short8*>(
                    &Bbuf[(size_t)(wn * 64 + nt * 16 + l15) * 64 + swz]);
            #pragma unroll
            for (int mt = 0; mt < 4; mt++)
                #pragma unroll
                for (int nt = 0; nt < 4; nt++)
                    acc[mt][nt] = __builtin_amdgcn_mfma_f32_16x16x32_bf16(
                        a[mt], bq[nt], acc[mt][nt], 0, 0, 0);
        }
        __syncthreads();
    }

    // G -> LDS as bf16 (staging area now dead)
    #pragma unroll
    for (int mt = 0; mt < 4; mt++)
        #pragma unroll
        for (int nt = 0; nt < 4; nt++)
            #pragma unroll
            for (int r = 0; r < 4; r++)
                Gb[(mt * 16 + lk * 4 + r) * GSTR + wn * 64 + nt * 16 + l15] =
                    __float2bfloat16(acc[mt][nt][r]);
    #pragma unroll
    for (int it = 0; it < 2; it++) {
        int f = tid + it * 256;
        int s = f >> 8, wp = f & 255;
        int wy = wp >> 4, wx = wp & 15;
        int gy = ty0 - 4 + wy, gxx = tx0 - 4 + wx;
        float v = 0.f;
        if (gy >= 0 && gy < H_ && gxx >= 0 && gxx < W_)
            v = prev_seg[((size_t)b * 2 + s) * HW_ + gy * W_ + gxx] * (1.f / 256.f);
        segf[f] = v;
    }
    __syncthreads();
    {
        int m = tid & 63;
        int sh = tid >> 6;
        int s = sh >> 1, hh = sh & 1;
        int py = m >> 3, lx = m & 7;
        const bf16* gr = Gb + (size_t)m * GSTR;
        const float* sr = segf + s * 256;
        float mx = -INFINITY;
        int wr0 = hh * 5, wr1 = hh ? 9 : 5;
        for (int wr = wr0; wr < wr1; ++wr) {
            int base = (py + wr) * 16 + lx;
            #pragma unroll
            for (int wc = 0; wc < 9; ++wc)
                mx = fmaxf(mx, __bfloat162float(gr[base + wc]) * sr[base + wc]);
        }
        redf[sh * 64 + m] = mx;
    }
    __syncthreads();
    if (tid < 128) {
        int s = tid >> 6, m = tid & 63;
        float v = fmaxf(redf[(s * 2 + 0) * 64 + m], redf[(s * 2 + 1) * 64 + m]);
        int gpx = (ty0 + (m >> 3)) * W_ + tx0 + (m & 7);
        lout[((size_t)b * 2 + s) * HW_ + gpx] = v;
    }
}

// ---------------------------------------------------------------- packall ----
// blocks [0,4608): pack_dec ; [4608,4896): pack_small ; [4896,4909): zero border.
__global__ __launch_bounds__(256)
void packall_kernel(const float* __restrict__ dec,
                    const float* __restrict__ gout, const float* __restrict__ lout,
                    const float* __restrict__ init_seg, const float* __restrict__ prev_seg,
                    bf16* __restrict__ hcat8, bf16* __restrict__ hcat1,
                    bf16* __restrict__ hmidp)
{
    __shared__ float tile[64][68];
    int gid = blockIdx.x;
    int t = threadIdx.x;
    if (gid < 4608) {
        int b = gid / 576;
        int rem = gid % 576;
        int c0 = (rem / 144) * 64, p0 = (rem % 144) * 64;
        const float* src = dec + ((size_t)b * C_ + c0) * HW_ + p0;
        #pragma unroll
        for (int it = 0; it < 4; it++) {
            int f = t + it * 256;
            int cl = f >> 4, p4 = (f & 15) * 4;
            float4 v = *reinterpret_cast<const float4*>(src + (size_t)cl * HW_ + p4);
            *reinterpret_cast<float4*>(&tile[cl][p4]) = v;
        }
        __syncthreads();
        #pragma unroll
        for (int it = 0; it < 4; it++) {
            int f = t + it * 256;
            int pl = f >> 4, c4 = (f & 15) * 4;
            int p = p0 + pl;
            int y = p / 96, x = p % 96;
            int pos = (y + 1) * HP_ + x + 1;
            int ch = c0 + c4;
            ushort4 u;
            u.x = bfb(tile[c4 + 0][pl]); u.y = bfb(tile[c4 + 1][pl]);
            u.z = bfb(tile[c4 + 2][pl]); u.w = bfb(tile[c4 + 3][pl]);
            bf16* dst = hcat8 + ((size_t)b * 8 + (ch >> 5)) * CHK + (size_t)pos * 32 + (ch & 31);
            *reinterpret_cast<ushort4*>(dst) = u;
        }
    } else if (gid < 4896) {
        int idx = (gid - 4608) * 256 + t;
        int b = idx / HW_, p = idx % HW_;
        int y = p / 96, x = p % 96;
        int pos = (y + 1) * HP_ + x + 1;
        bf16* dst = hcat1 + ((size_t)b * HPW + pos) * 8;
        float g0 = gout[((size_t)b * 2 + 0) * HW_ + p];
        float g1 = gout[((size_t)b * 2 + 1) * HW_ + p];
        float i0 = init_seg[((size_t)b * 2 + 0) * HW_ + p];
        float i1 = init_seg[((size_t)b * 2 + 1) * HW_ + p];
        float l0 = lout[((size_t)b * 2 + 0) * HW_ + p];
        float l1 = lout[((size_t)b * 2 + 1) * HW_ + p];
        float q0 = prev_seg[((size_t)b * 2 + 0) * HW_ + p];
        float q1 = prev_seg[((size_t)b * 2 + 1) * HW_ + p];
        ushort4 u; u.x = bfb(g0); u.y = bfb(g1); u.z = bfb(i0); u.w = bfb(i1);
        *reinterpret_cast<ushort4*>(dst) = u;
        ushort4 u2; u2.x = bfb(l0); u2.y = bfb(l1); u2.z = bfb(q0); u2.w = bfb(q1);
        *reinterpret_cast<ushort4*>(dst + 4) = u2;
    } else {
        int idx = (gid - 4896) * 256 + t;
        if (idx >= B_ * 388) return;
        int b = idx / 388, bi = idx % 388;
        int pos;
        if (bi < 98) pos = bi;
        else if (bi < 196) pos = 97 * HP_ + (bi - 98);
        else if (bi < 292) pos = (bi - 196 + 1) * HP_;
        else pos = (bi - 292 + 1) * HP_ + 97;
        const short8 Z = {0, 0, 0, 0, 0, 0, 0, 0};
        #pragma unroll
        for (int c = 0; c < 8; c++) {
            bf16* p = hcat8 + ((size_t)b * 8 + c) * CHK + (size_t)pos * 32;
            #pragma unroll
            for (int j = 0; j < 4; j++)
                *reinterpret_cast<short8*>(p + j * 8) = Z;
        }
        *reinterpret_cast<short8*>(hcat1 + ((size_t)b * HPW + pos) * 8) = Z;
        bf16* q = hmidp + ((size_t)b * HPW + pos) * 128;
        #pragma unroll
        for (int j = 0; j < 16; j++)
            *reinterpret_cast<short8*>(q + j * 8) = Z;
    }
}

// ---------------------------------------------------------------- conv1 ----
__global__ __launch_bounds__(256)
void conv1_mfma(const bf16* __restrict__ hcat8, const bf16* __restrict__ hcat1,
                const bf16* __restrict__ w1bf, const float* __restrict__ b1,
                bf16* __restrict__ hmidp)
{
    __shared__ bf16 S[14336];
    bf16* Abuf = S;
    bf16* Bbuf = S + 8192;
    int gid = blockIdx.x;                     // 768 = 8 b x 96 rows
    int b = gid & 7;
    int row = gid >> 3;
    int tid = threadIdx.x, lane = tid & 63;
    int w = tid >> 6, wm = w & 1, wn = w >> 1;
    int l15 = lane & 15, lk = lane >> 4;
    const bf16* hb8 = hcat8 + (size_t)b * 8 * CHK;
    const bf16* hb1 = hcat1 + (size_t)b * HPW * 8;

    int wbase = tid & 192;
    int t3 = (tid >> 3) & 7;
    int cX = (tid & 7) ^ t3;
    int selX = cX >> 2;
    int cin8 = (cX & 3) * 8;
    int r0 = tid >> 3;
    int swzE0 = ((lk) ^ (l15 & 7)) * 8;
    int swzE1 = ((4 + lk) ^ (l15 & 7)) * 8;

    f32x4 acc[4][3] = {};

    auto STAGE = [&](int p) {
        int s0 = 2 * p, s1 = s0 + 1;
        int icc0 = s0 / 9, tap0 = s0 - icc0 * 9;
        int icc1 = s1 / 9, tap1 = s1 - icc1 * 9;
        const bf16* gA = w1bf + (size_t)p * 8192 + (size_t)selX * 4096 + cin8;
        #pragma unroll
        for (int i = 0; i < 4; i++)
            gload_lds16(gA + (i * 32 + r0) * 32,
                        &Abuf[(size_t)(i * 256 + wbase) * 8]);
        int tapS = selX ? tap1 : tap0;
        int iccS = selX ? icc1 : icc0;
        int posT = (row + tapS / 3) * HP_ + (tapS % 3);
        bool is8 = (iccS >= 8);
        const bf16* gb = is8 ? hb1 : (hb8 + (size_t)iccS * CHK);
        #pragma unroll
        for (int i = 0; i < 3; i++) {
            int c = i * 32 + r0;
            const bf16* g = is8 ? (gb + (size_t)(posT + c) * 8)
                                : (gb + (size_t)(posT + c) * 32 + cin8);
            gload_lds16(g, &Bbuf[(size_t)(i * 256 + wbase) * 8]);
        }
    };

    auto COMPUTE = [&]() {
        #pragma unroll
        for (int k = 0; k < 2; k++) {
            int swz = k ? swzE1 : swzE0;
            short8 a[4], bq[3];
            #pragma unroll
            for (int mt = 0; mt < 4; mt++)
                a[mt] = *reinterpret_cast<const short8*>(
                    &Abuf[(size_t)(wm * 64 + mt * 16 + l15) * 64 + swz]);
            #pragma unroll
            for (int nt = 0; nt < 3; nt++)
                bq[nt] = *reinterpret_cast<const short8*>(
                    &Bbuf[(size_t)(wn * 48 + nt * 16 + l15) * 64 + swz]);
            #pragma unroll
            for (int mt = 0; mt < 4; mt++)
                #pragma unroll
                for (int nt = 0; nt < 3; nt++)
                    acc[mt][nt] = __builtin_amdgcn_mfma_f32_16x16x32_bf16(
                        a[mt], bq[nt], acc[mt][nt], 0, 0, 0);
        }
    };

    for (int p = 0; p < 41; ++p) {
        STAGE(p);
        __syncthreads();
        COMPUTE();
        __syncthreads();
    }

    #pragma unroll
    for (int nt = 0; nt < 3; nt++) {
        int pxl = wn * 48 + nt * 16 + l15;
        #pragma unroll
        for (int mt = 0; mt < 4; mt++) {
            int ocb = wm * 64 + mt * 16 + lk * 4;
            float4 bias = *reinterpret_cast<const float4*>(b1 + ocb);
            const float* bp = reinterpret_cast<const float*>(&bias);
            ushort4 u;
            u.x = bfb(fmaxf(acc[mt][nt][0] + bp[0], 0.f));
            u.y = bfb(fmaxf(acc[mt][nt][1] + bp[1], 0.f));
            u.z = bfb(fmaxf(acc[mt][nt][2] + bp[2], 0.f));
            u.w = bfb(fmaxf(acc[mt][nt][3] + bp[3], 0.f));
            int chunk = (ocb >> 3) ^ (pxl & 7);
            *reinterpret_cast<ushort4*>(&S[(size_t)pxl * 128 + chunk * 8 + (lk & 1) * 4]) = u;
        }
    }
    __syncthreads();
    {
        bf16* dst = hmidp + (size_t)b * HPW * 128 + ((size_t)(row + 1) * HP_ + 1) * 128;
        #pragma unroll
        for (int i = 0; i < 6; i++) {
            int f = tid + i * 256;
            int px = f >> 4, cc = f & 15;
            short8 v = *reinterpret_cast<const short8*>(
                &S[(size_t)px * 128 + (cc ^ (px & 7)) * 8]);
            *reinterpret_cast<short8*>(dst + (size_t)f * 8) = v;
        }
    }
}

// ---------------------------------------------------------------- conv2 ----
__global__ __launch_bounds__(128)
void conv2_mfma(const bf16* __restrict__ hmidp, const bf16* __restrict__ w2bf,
                const float* __restrict__ b2, float* __restrict__ out)
{
    __shared__ bf16 Abuf[1024];
    __shared__ bf16 Bbuf[6144];
    int gid = blockIdx.x;             // 768 = 8 b x 96 rows
    int b = gid & 7;
    int y = gid >> 3;
    int p0 = y * 96;
    int tid = threadIdx.x, lane = tid & 63;
    int wn = tid >> 6;
    int l15 = lane & 15, lk = lane >> 4;
    const bf16* hb = hmidp + (size_t)b * HPW * 128;

    int wbase = tid & 64;
    int t3 = (tid >> 3) & 7;
    int cX = (tid & 7) ^ t3;
    int r0 = tid >> 3;
    int swzE0 = ((lk) ^ (l15 & 7)) * 8;
    int swzE1 = ((4 + lk) ^ (l15 & 7)) * 8;

    f32x4 acc[3] = {};

    auto STAGE = [&](int s) {
        int tap = s >> 1, half = s & 1;
        int toff = (tap / 3) * HP_ + (tap % 3);
        gload_lds16(w2bf + ((size_t)s * 16 + r0) * 64 + cX * 8,
                    &Abuf[(size_t)wbase * 8]);
        #pragma unroll
        for (int i = 0; i < 6; i++) {
            int c = i * 16 + r0;
            gload_lds16(hb + (size_t)(y * HP_ + c + toff) * 128 + half * 64 + cX * 8,
                        &Bbuf[(size_t)(i * 128 + wbase) * 8]);
        }
    };

    auto COMPUTE = [&]() {
        #pragma unroll
        for (int k = 0; k < 2; k++) {
            int swz = k ? swzE1 : swzE0;
            short8 a = *reinterpret_cast<const short8*>(&Abuf[(size_t)l15 * 64 + swz]);
            #pragma unroll
            for (int nt = 0; nt < 3; nt++) {
                short8 bq = *reinterpret_cast<const short8*>(
                    &Bbuf[(size_t)(wn * 48 + nt * 16 + l15) * 64 + swz]);
                acc[nt] = __builtin_amdgcn_mfma_f32_16x16x32_bf16(a, bq, acc[nt], 0, 0, 0);
            }
        }
    };

    for (int s = 0; s < 18; ++s) {
        STAGE(s);
        __syncthreads();
        COMPUTE();
        __syncthreads();
    }

    if (lk == 0) {
        float bb0 = b2[0], bb1 = b2[1];
        #pragma unroll
        for (int nt = 0; nt < 3; nt++) {
            int px = p0 + wn * 48 + nt * 16 + l15;
            out[((size_t)b * 2 + 0) * HW_ + px] = acc[nt][0] + bb0;
            out[((size_t)b * 2 + 1) * HW_ + px] = acc[nt][1] + bb1;
        }
    }
}

// ---------------------------------------------------------------- launch ----
extern "C" void kernel_launch(void* const* d_in, const int* in_sizes, int n_in,
                              void* d_out, int out_size, void* d_ws, size_t ws_size,
                              hipStream_t stream)
{
    const float* cur_embed  = (const float*)d_in[0];
    const float* cur_decode = (const float*)d_in[1];
    const float* init_embed = (const float*)d_in[2];
    const float* init_seg   = (const float*)d_in[3];
    const float* prev_embed = (const float*)d_in[4];
    const float* prev_seg   = (const float*)d_in[5];
    const float* W1 = (const float*)d_in[6];
    const float* b1 = (const float*)d_in[7];
    const float* W2 = (const float*)d_in[8];
    const float* b2 = (const float*)d_in[9];
    float* out = (float*)d_out;

    char* ws = (char*)d_ws;
    bf16* hcat8 = (bf16*)ws;
    bf16* curbf = (bf16*)ws;                          // alias (dead after lmap)
    bf16* hcat1 = (bf16*)(ws + 39337984);
    const size_t HCAT_REGION = 40567296;
    bf16* hmidp  = (bf16*)(ws + HCAT_REGION);
    bf16* fibf   = (bf16*)(ws + HCAT_REGION);
    bf16* prevbf = (bf16*)(ws + HCAT_REGION);
    float* si  = (float*)(ws + HCAT_REGION + 2621440);
    bf16* w1bf = (bf16*)(ws + 60236288);
    bf16* w2bf = (bf16*)(ws + 60908032);
    float* gout = (float*)(ws + 60944896);
    float* lout = (float*)(ws + 61534720);
    const bf16* zbuf = w1bf + (size_t)81 * 4096;      // slab 81 = zeros

    { prep_kernel<<<6544, 256, 0, stream>>>(W1, W2, init_embed, init_seg,
                                            w1bf, w2bf, fibf, si); }
    { dim3 g(144, 4, B_);
      tcur_kernel<<<g, 256, 0, stream>>>(cur_embed, curbf); }
    { gmap_mfma<<<768, 256, 0, stream>>>(curbf, fibf, si, gout); }
    for (int g = 0; g < 2; g++) {
        dim3 gt(144, 4, 4);
        tcur_kernel<<<gt, 256, 0, stream>>>(prev_embed + (size_t)g * 4 * C_ * HW_, prevbf);
        dim3 gl(144, 4);
        lmap_mfma<<<gl, 256, 0, stream>>>(curbf, prevbf, zbuf, prev_seg, lout, g * 4);
    }
    { packall_kernel<<<4909, 256, 0, stream>>>(cur_decode, gout, lout, init_seg,
                                               prev_seg, hcat8, hcat1, hmidp); }
    { conv1_mfma<<<768, 256, 0, stream>>>(hcat8, hcat1, w1bf, b1, hmidp); }
    { conv2_mfma<<<768, 128, 0, stream>>>(hmidp, w2bf, b2, out); }
}

// Round 17
// 239.805 us; speedup vs baseline: 3.1028x; 1.0131x over previous
//
#include <hip/hip_runtime.h>
#include <hip/hip_bf16.h>

// Round 17: tcur(cur) folded into prep (3rd gid-range; no aliasing: curbf region
//           disjoint from wcvt/pool outputs). 10 -> 9 launches (dataflow floor).
//           All compute kernels byte-identical to r16 (passing, 243 us).
// ws layout (62.12 MB, aliased): unchanged from r16.

typedef __hip_bfloat16 bf16;
typedef __attribute__((ext_vector_type(8))) short short8;
typedef __attribute__((ext_vector_type(4))) float f32x4;

constexpr int B_  = 8;
constexpr int C_  = 256;
constexpr int H_  = 96;
constexpr int W_  = 96;
constexpr int HW_ = H_ * W_;       // 9216
constexpr int PW_ = 24;
constexpr int KP_ = 576;
constexpr int KPP = 640;
constexpr int HP_ = 98;
constexpr int HPW = HP_ * HP_;     // 9604
constexpr int CHK = HPW * 32;

__device__ __forceinline__ unsigned short bfb(float f) {
    bf16 h = __float2bfloat16(f);
    return *reinterpret_cast<unsigned short*>(&h);
}

__device__ __forceinline__ void gload_lds16(const bf16* g, bf16* l) {
    __builtin_amdgcn_global_load_lds((const void*)g, (void*)l, 16, 0, 0);
}

// ------------------------------------------------------------ prep ----
// blocks [0,1384): W1/W2 convert ; [1384,6544): pool ; [6544,11152): tcur(cur).
__global__ __launch_bounds__(256)
void prep_kernel(const float* __restrict__ W1, const float* __restrict__ W2,
                 const float* __restrict__ init_embed, const float* __restrict__ init_seg,
                 const float* __restrict__ cur_embed,
                 bf16* __restrict__ w1bf, bf16* __restrict__ w2bf,
                 bf16* __restrict__ fibf, float* __restrict__ si,
                 bf16* __restrict__ curbf)
{
    __shared__ float tile[64][68];
    int gid = blockIdx.x;
    int t = threadIdx.x;
    if (gid < 1384) {
        int idx = gid * 256 + t;
        if (idx < 82 * 128 * 32) {
            int ic = idx & 31;
            int oc = (idx >> 5) & 127;
            int ks = idx >> 12;
            int icc = ks / 9, tap = ks % 9;
            int icg = icc * 32 + ic;
            float v = (icg < 264) ? W1[((size_t)oc * 264 + icg) * 9 + tap] : 0.f;
            w1bf[idx] = __float2bfloat16(v);
        } else {
            int j = idx - 82 * 128 * 32;
            if (j >= 18 * 16 * 64) return;
            int c  = j & 63;
            int oc = (j >> 6) & 15;
            int s  = j >> 10;
            int tap = s >> 1, half = s & 1;
            float v = (oc < 2) ? W2[((size_t)oc * 128 + half * 64 + c) * 9 + tap] : 0.f;
            w2bf[j] = __float2bfloat16(v);
        }
    } else if (gid < 6544) {
        int idx = (gid - 1384) * 256 + t;
        int k  = idx % KPP;
        int ch = (idx / KPP) % (C_ + 2);
        int b  = idx / (KPP * (C_ + 2));
        float s = 0.f;
        if (k < KP_) {
            int ph = k / PW_, pw = k % PW_;
            const float* src = (ch < C_)
                ? (init_embed + (((size_t)b * C_ + ch) * H_ + ph * 4) * W_ + pw * 4)
                : (init_seg   + (((size_t)b * 2 + (ch - C_)) * H_ + ph * 4) * W_ + pw * 4);
            #pragma unroll
            for (int r = 0; r < 4; r++) {
                float4 v = *reinterpret_cast<const float4*>(src + r * W_);
                s += v.x + v.y + v.z + v.w;
            }
            s *= (1.f / 16.f);
        }
        if (ch < C_) fibf[((size_t)b * KPP + k) * C_ + ch] = __float2bfloat16(s);
        else         si[(size_t)b * 2 * KPP + (ch - C_) * KPP + k] = s;
    } else {
        int t6 = gid - 6544;                  // [0,4608): 8 b x 4 cgrp x 144 pgrp
        int b = t6 / 576;
        int rem = t6 % 576;
        int c0 = (rem / 144) * 64, p0 = (rem % 144) * 64;
        const float* src = cur_embed + ((size_t)b * C_ + c0) * HW_ + p0;
        #pragma unroll
        for (int it = 0; it < 4; it++) {
            int f = t + it * 256;
            int cl = f >> 4, p4 = (f & 15) * 4;
            float4 v = *reinterpret_cast<const float4*>(src + (size_t)cl * HW_ + p4);
            *reinterpret_cast<float4*>(&tile[cl][p4]) = v;
        }
        __syncthreads();
        bf16* dst = curbf + ((size_t)b * HW_ + p0) * 256 + c0;
        #pragma unroll
        for (int it = 0; it < 4; it++) {
            int f = t + it * 256;
            int pl = f >> 4, c4 = (f & 15) * 4;
            ushort4 u;
            u.x = bfb(tile[c4 + 0][pl]); u.y = bfb(tile[c4 + 1][pl]);
            u.z = bfb(tile[c4 + 2][pl]); u.w = bfb(tile[c4 + 3][pl]);
            *reinterpret_cast<ushort4*>(dst + (size_t)pl * 256 + c4) = u;
        }
    }
}

// ------------------------------------------------------- NCHW->NHWC bf16 ----
__global__ __launch_bounds__(256)
void tcur_kernel(const float* __restrict__ cur, bf16* __restrict__ curbf)
{
    __shared__ float tile[64][68];
    int b = blockIdx.z, c0 = blockIdx.y * 64, p0 = blockIdx.x * 64;
    int t = threadIdx.x;
    const float* src = cur + ((size_t)b * C_ + c0) * HW_ + p0;
    #pragma unroll
    for (int it = 0; it < 4; it++) {
        int f = t + it * 256;
        int cl = f >> 4, p4 = (f & 15) * 4;
        float4 v = *reinterpret_cast<const float4*>(src + (size_t)cl * HW_ + p4);
        *reinterpret_cast<float4*>(&tile[cl][p4]) = v;
    }
    __syncthreads();
    bf16* dst = curbf + ((size_t)b * HW_ + p0) * 256 + c0;
    #pragma unroll
    for (int it = 0; it < 4; it++) {
        int f = t + it * 256;
        int pl = f >> 4, c4 = (f & 15) * 4;
        ushort4 u;
        u.x = bfb(tile[c4 + 0][pl]); u.y = bfb(tile[c4 + 1][pl]);
        u.z = bfb(tile[c4 + 2][pl]); u.w = bfb(tile[c4 + 3][pl]);
        *reinterpret_cast<ushort4*>(dst + (size_t)pl * 256 + c4) = u;
    }
}

// ---------------------------------------------------------------- gmap ----
__global__ __launch_bounds__(256)
void gmap_mfma(const bf16* __restrict__ curbf, const bf16* __restrict__ fibf,
               const float* __restrict__ si, float* __restrict__ gout)
{
    __shared__ bf16 Abuf[8192];
    __shared__ bf16 Bbuf[6144];
    __shared__ float bred[2][2][2][48];
    int gid = blockIdx.x;             // 768 = 8 b x 96 px-tiles
    int b = gid & 7;
    int p0 = (gid >> 3) * 96;
    int tid = threadIdx.x, lane = tid & 63;
    int w = tid >> 6, wm = w & 1, wn = w >> 1;
    int l15 = lane & 15, lk = lane >> 4;
    const bf16* fb = fibf + (size_t)b * KPP * 256;
    const bf16* cb = curbf + (size_t)b * HW_ * 256;
    const float* sib = si + (size_t)b * 2 * KPP;

    int wbase = tid & 192;
    int t3 = (tid >> 3) & 7;
    int cX = (tid & 7) ^ t3;
    int r0 = tid >> 3;
    int swzE0 = ((lk) ^ (l15 & 7)) * 8;
    int swzE1 = ((4 + lk) ^ (l15 & 7)) * 8;

    float best[2][3];
    #pragma unroll
    for (int s = 0; s < 2; s++)
        #pragma unroll
        for (int nt = 0; nt < 3; nt++) best[s][nt] = -INFINITY;
    f32x4 acc[4][3] = {};

    auto STAGE = [&](int q) {
        int chunk = q >> 2, ks = q & 3;
        int koff = ks * 64 + cX * 8;
        #pragma unroll
        for (int i = 0; i < 4; i++) {
            int row = i * 32 + r0;
            gload_lds16(fb + (size_t)(chunk * 128 + row) * 256 + koff,
                        &Abuf[(size_t)(i * 256 + wbase) * 8]);
        }
        #pragma unroll
        for (int i = 0; i < 3; i++) {
            int row = i * 32 + r0;
            gload_lds16(cb + (size_t)(p0 + row) * 256 + koff,
                        &Bbuf[(size_t)(i * 256 + wbase) * 8]);
        }
    };

    auto COMPUTE = [&]() {
        #pragma unroll
        for (int k = 0; k < 2; k++) {
            int swz = k ? swzE1 : swzE0;
            short8 a[4], bq[3];
            #pragma unroll
            for (int mt = 0; mt < 4; mt++)
                a[mt] = *reinterpret_cast<const short8*>(
                    &Abuf[(size_t)(wm * 64 + mt * 16 + l15) * 64 + swz]);
            #pragma unroll
            for (int nt = 0; nt < 3; nt++)
                bq[nt] = *reinterpret_cast<const short8*>(
                    &Bbuf[(size_t)(wn * 48 + nt * 16 + l15) * 64 + swz]);
            #pragma unroll
            for (int mt = 0; mt < 4; mt++)
                #pragma unroll
                for (int nt = 0; nt < 3; nt++)
                    acc[mt][nt] = __builtin_amdgcn_mfma_f32_16x16x32_bf16(
                        a[mt], bq[nt], acc[mt][nt], 0, 0, 0);
        }
    };

    for (int q = 0; q < 20; ++q) {
        STAGE(q);
        __syncthreads();
        COMPUTE();
        if ((q & 3) == 3) {
            int kp0 = (q >> 2) * 128;
            #pragma unroll
            for (int mt = 0; mt < 4; mt++) {
                int rb = kp0 + wm * 64 + mt * 16 + lk * 4;
                float4 s0 = *reinterpret_cast<const float4*>(sib + rb);
                float4 s1 = *reinterpret_cast<const float4*>(sib + KPP + rb);
                const float* s0p = reinterpret_cast<const float*>(&s0);
                const float* s1p = reinterpret_cast<const float*>(&s1);
                #pragma unroll
                for (int nt = 0; nt < 3; nt++) {
                    #pragma unroll
                    for (int r = 0; r < 4; r++) {
                        float v = acc[mt][nt][r];
                        best[0][nt] = fmaxf(best[0][nt], v * s0p[r]);
                        best[1][nt] = fmaxf(best[1][nt], v * s1p[r]);
                    }
                    acc[mt][nt] = (f32x4){0.f, 0.f, 0.f, 0.f};
                }
            }
        }
        __syncthreads();
    }
    #pragma unroll
    for (int s = 0; s < 2; s++)
        #pragma unroll
        for (int nt = 0; nt < 3; nt++) {
            float v = best[s][nt];
            v = fmaxf(v, __shfl_xor(v, 16));
            v = fmaxf(v, __shfl_xor(v, 32));
            if (lk == 0) bred[wm][wn][s][nt * 16 + l15] = v;
        }
    __syncthreads();
    if (tid < 192) {
        int s2 = tid / 96, pxl = tid % 96;
        float v = fmaxf(bred[0][pxl / 48][s2][pxl % 48],
                        bred[1][pxl / 48][s2][pxl % 48]);
        gout[((size_t)b * 2 + s2) * HW_ + p0 + pxl] = v;
    }
}

// ---------------------------------------------------------------- lmap ----
__global__ __launch_bounds__(256)
void lmap_mfma(const bf16* __restrict__ curbf, const bf16* __restrict__ prevbf,
               const bf16* __restrict__ zbuf,
               const float* __restrict__ prev_seg, float* __restrict__ lout, int b0)
{
    constexpr int GSTR = 258;
    __shared__ __align__(16) char Smem[40960];
    bf16* Abuf = (bf16*)Smem;
    bf16* Bbuf = (bf16*)(Smem + 8192);
    bf16* Gb   = (bf16*)Smem;
    float* segf = (float*)(Smem + 33024);
    float* redf = (float*)(Smem + 35072);

    int b = b0 + blockIdx.y;
    const bf16* pb = prevbf + (size_t)blockIdx.y * HW_ * 256;
    const bf16* cb = curbf + (size_t)b * HW_ * 256;
    int tile = blockIdx.x;
    int ty0 = (tile / 12) * 8, tx0 = (tile % 12) * 8;
    int tid = threadIdx.x, lane = tid & 63, wn = tid >> 6;
    int l15 = lane & 15, lk = lane >> 4;

    int wbase = tid & 192;
    int t3 = (tid >> 3) & 7;
    int cX = (tid & 7) ^ t3;
    int r0 = tid >> 3;
    int swzE0 = ((lk) ^ (l15 & 7)) * 8;
    int swzE1 = ((4 + lk) ^ (l15 & 7)) * 8;

    int gpxA0 = (ty0 + (r0 >> 3)) * W_ + tx0 + (r0 & 7);
    int gpxA1 = (ty0 + (r0 >> 3) + 4) * W_ + tx0 + (r0 & 7);
    const bf16* rowB[8];
    #pragma unroll
    for (int i = 0; i < 8; i++) {
        int wrow = i * 32 + r0;
        int wy = wrow >> 4, wx = wrow & 15;
        int gy = ty0 - 4 + wy, gx = tx0 - 4 + wx;
        bool ok = (gy >= 0) && (gy < H_) && (gx >= 0) && (gx < W_);
        rowB[i] = ok ? (pb + (size_t)(gy * W_ + gx) * 256) : zbuf;
    }

    f32x4 acc[4][4] = {};

    for (int ks = 0; ks < 4; ++ks) {
        int koff = ks * 64 + cX * 8;
        gload_lds16(cb + (size_t)gpxA0 * 256 + koff, &Abuf[(size_t)(wbase) * 8]);
        gload_lds16(cb + (size_t)gpxA1 * 256 + koff, &Abuf[(size_t)(256 + wbase) * 8]);
        #pragma unroll
        for (int i = 0; i < 8; i++)
            gload_lds16(rowB[i] + koff, &Bbuf[(size_t)(i * 256 + wbase) * 8]);
        __syncthreads();
        #pragma unroll
        for (int k = 0; k < 2; k++) {
            int swz = k ? swzE1 : swzE0;
            short8 a[4], bq[4];
            #pragma unroll
            for (int mt = 0; mt < 4; mt++)
                a[mt] = *reinterpret_cast<const short8*>(
                    &Abuf[(size_t)(mt * 16 + l15) * 64 + swz]);
            #pragma unroll
            for (int nt = 0; nt < 4; nt++)
                bq[nt] = *reinterpret_cast<const short8*>(
                    &Bbuf[(size_t)(wn * 64 + nt * 16 + l15) * 64 + swz]);
            #pragma unroll
            for (int mt = 0; mt < 4; mt++)
                #pragma unroll
                for (int nt = 0; nt < 4; nt++)
                    acc[mt][nt] = __builtin_amdgcn_mfma_f32_16x16x32_bf16(
                        a[mt], bq[nt], acc[mt][nt], 0, 0, 0);
        }
        __syncthreads();
    }

    #pragma unroll
    for (int mt = 0; mt < 4; mt++)
        #pragma unroll
        for (int nt = 0; nt < 4; nt++)
            #pragma unroll
            for (int r = 0; r < 4; r++)
                Gb[(mt * 16 + lk * 4 + r) * GSTR + wn * 64 + nt * 16 + l15] =
                    __float2bfloat16(acc[mt][nt][r]);
    #pragma unroll
    for (int it = 0; it < 2; it++) {
        int f = tid + it * 256;
        int s = f >> 8, wp = f & 255;
        int wy = wp >> 4, wx = wp & 15;
        int gy = ty0 - 4 + wy, gxx = tx0 - 4 + wx;
        float v = 0.f;
        if (gy >= 0 && gy < H_ && gxx >= 0 && gxx < W_)
            v = prev_seg[((size_t)b * 2 + s) * HW_ + gy * W_ + gxx] * (1.f / 256.f);
        segf[f] = v;
    }
    __syncthreads();
    {
        int m = tid & 63;
        int sh = tid >> 6;
        int s = sh >> 1, hh = sh & 1;
        int py = m >> 3, lx = m & 7;
        const bf16* gr = Gb + (size_t)m * GSTR;
        const float* sr = segf + s * 256;
        float mx = -INFINITY;
        int wr0 = hh * 5, wr1 = hh ? 9 : 5;
        for (int wr = wr0; wr < wr1; ++wr) {
            int base = (py + wr) * 16 + lx;
            #pragma unroll
            for (int wc = 0; wc < 9; ++wc)
                mx = fmaxf(mx, __bfloat162float(gr[base + wc]) * sr[base + wc]);
        }
        redf[sh * 64 + m] = mx;
    }
    __syncthreads();
    if (tid < 128) {
        int s = tid >> 6, m = tid & 63;
        float v = fmaxf(redf[(s * 2 + 0) * 64 + m], redf[(s * 2 + 1) * 64 + m]);
        int gpx = (ty0 + (m >> 3)) * W_ + tx0 + (m & 7);
        lout[((size_t)b * 2 + s) * HW_ + gpx] = v;
    }
}

// ---------------------------------------------------------------- packall ----
__global__ __launch_bounds__(256)
void packall_kernel(const float* __restrict__ dec,
                    const float* __restrict__ gout, const float* __restrict__ lout,
                    const float* __restrict__ init_seg, const float* __restrict__ prev_seg,
                    bf16* __restrict__ hcat8, bf16* __restrict__ hcat1,
                    bf16* __restrict__ hmidp)
{
    __shared__ float tile[64][68];
    int gid = blockIdx.x;
    int t = threadIdx.x;
    if (gid < 4608) {
        int b = gid / 576;
        int rem = gid % 576;
        int c0 = (rem / 144) * 64, p0 = (rem % 144) * 64;
        const float* src = dec + ((size_t)b * C_ + c0) * HW_ + p0;
        #pragma unroll
        for (int it = 0; it < 4; it++) {
            int f = t + it * 256;
            int cl = f >> 4, p4 = (f & 15) * 4;
            float4 v = *reinterpret_cast<const float4*>(src + (size_t)cl * HW_ + p4);
            *reinterpret_cast<float4*>(&tile[cl][p4]) = v;
        }
        __syncthreads();
        #pragma unroll
        for (int it = 0; it < 4; it++) {
            int f = t + it * 256;
            int pl = f >> 4, c4 = (f & 15) * 4;
            int p = p0 + pl;
            int y = p / 96, x = p % 96;
            int pos = (y + 1) * HP_ + x + 1;
            int ch = c0 + c4;
            ushort4 u;
            u.x = bfb(tile[c4 + 0][pl]); u.y = bfb(tile[c4 + 1][pl]);
            u.z = bfb(tile[c4 + 2][pl]); u.w = bfb(tile[c4 + 3][pl]);
            bf16* dst = hcat8 + ((size_t)b * 8 + (ch >> 5)) * CHK + (size_t)pos * 32 + (ch & 31);
            *reinterpret_cast<ushort4*>(dst) = u;
        }
    } else if (gid < 4896) {
        int idx = (gid - 4608) * 256 + t;
        int b = idx / HW_, p = idx % HW_;
        int y = p / 96, x = p % 96;
        int pos = (y + 1) * HP_ + x + 1;
        bf16* dst = hcat1 + ((size_t)b * HPW + pos) * 8;
        float g0 = gout[((size_t)b * 2 + 0) * HW_ + p];
        float g1 = gout[((size_t)b * 2 + 1) * HW_ + p];
        float i0 = init_seg[((size_t)b * 2 + 0) * HW_ + p];
        float i1 = init_seg[((size_t)b * 2 + 1) * HW_ + p];
        float l0 = lout[((size_t)b * 2 + 0) * HW_ + p];
        float l1 = lout[((size_t)b * 2 + 1) * HW_ + p];
        float q0 = prev_seg[((size_t)b * 2 + 0) * HW_ + p];
        float q1 = prev_seg[((size_t)b * 2 + 1) * HW_ + p];
        ushort4 u; u.x = bfb(g0); u.y = bfb(g1); u.z = bfb(i0); u.w = bfb(i1);
        *reinterpret_cast<ushort4*>(dst) = u;
        ushort4 u2; u2.x = bfb(l0); u2.y = bfb(l1); u2.z = bfb(q0); u2.w = bfb(q1);
        *reinterpret_cast<ushort4*>(dst + 4) = u2;
    } else {
        int idx = (gid - 4896) * 256 + t;
        if (idx >= B_ * 388) return;
        int b = idx / 388, bi = idx % 388;
        int pos;
        if (bi < 98) pos = bi;
        else if (bi < 196) pos = 97 * HP_ + (bi - 98);
        else if (bi < 292) pos = (bi - 196 + 1) * HP_;
        else pos = (bi - 292 + 1) * HP_ + 97;
        const short8 Z = {0, 0, 0, 0, 0, 0, 0, 0};
        #pragma unroll
        for (int c = 0; c < 8; c++) {
            bf16* p = hcat8 + ((size_t)b * 8 + c) * CHK + (size_t)pos * 32;
            #pragma unroll
            for (int j = 0; j < 4; j++)
                *reinterpret_cast<short8*>(p + j * 8) = Z;
        }
        *reinterpret_cast<short8*>(hcat1 + ((size_t)b * HPW + pos) * 8) = Z;
        bf16* q = hmidp + ((size_t)b * HPW + pos) * 128;
        #pragma unroll
        for (int j = 0; j < 16; j++)
            *reinterpret_cast<short8*>(q + j * 8) = Z;
    }
}

// ---------------------------------------------------------------- conv1 ----
__global__ __launch_bounds__(256)
void conv1_mfma(const bf16* __restrict__ hcat8, const bf16* __restrict__ hcat1,
                const bf16* __restrict__ w1bf, const float* __restrict__ b1,
                bf16* __restrict__ hmidp)
{
    __shared__ bf16 S[14336];
    bf16* Abuf = S;
    bf16* Bbuf = S + 8192;
    int gid = blockIdx.x;                     // 768 = 8 b x 96 rows
    int b = gid & 7;
    int row = gid >> 3;
    int tid = threadIdx.x, lane = tid & 63;
    int w = tid >> 6, wm = w & 1, wn = w >> 1;
    int l15 = lane & 15, lk = lane >> 4;
    const bf16* hb8 = hcat8 + (size_t)b * 8 * CHK;
    const bf16* hb1 = hcat1 + (size_t)b * HPW * 8;

    int wbase = tid & 192;
    int t3 = (tid >> 3) & 7;
    int cX = (tid & 7) ^ t3;
    int selX = cX >> 2;
    int cin8 = (cX & 3) * 8;
    int r0 = tid >> 3;
    int swzE0 = ((lk) ^ (l15 & 7)) * 8;
    int swzE1 = ((4 + lk) ^ (l15 & 7)) * 8;

    f32x4 acc[4][3] = {};

    auto STAGE = [&](int p) {
        int s0 = 2 * p, s1 = s0 + 1;
        int icc0 = s0 / 9, tap0 = s0 - icc0 * 9;
        int icc1 = s1 / 9, tap1 = s1 - icc1 * 9;
        const bf16* gA = w1bf + (size_t)p * 8192 + (size_t)selX * 4096 + cin8;
        #pragma unroll
        for (int i = 0; i < 4; i++)
            gload_lds16(gA + (i * 32 + r0) * 32,
                        &Abuf[(size_t)(i * 256 + wbase) * 8]);
        int tapS = selX ? tap1 : tap0;
        int iccS = selX ? icc1 : icc0;
        int posT = (row + tapS / 3) * HP_ + (tapS % 3);
        bool is8 = (iccS >= 8);
        const bf16* gb = is8 ? hb1 : (hb8 + (size_t)iccS * CHK);
        #pragma unroll
        for (int i = 0; i < 3; i++) {
            int c = i * 32 + r0;
            const bf16* g = is8 ? (gb + (size_t)(posT + c) * 8)
                                : (gb + (size_t)(posT + c) * 32 + cin8);
            gload_lds16(g, &Bbuf[(size_t)(i * 256 + wbase) * 8]);
        }
    };

    auto COMPUTE = [&]() {
        #pragma unroll
        for (int k = 0; k < 2; k++) {
            int swz = k ? swzE1 : swzE0;
            short8 a[4], bq[3];
            #pragma unroll
            for (int mt = 0; mt < 4; mt++)
                a[mt] = *reinterpret_cast<const short8*>(
                    &Abuf[(size_t)(wm * 64 + mt * 16 + l15) * 64 + swz]);
            #pragma unroll
            for (int nt = 0; nt < 3; nt++)
                bq[nt] = *reinterpret_cast<const short8*>(
                    &Bbuf[(size_t)(wn * 48 + nt * 16 + l15) * 64 + swz]);
            #pragma unroll
            for (int mt = 0; mt < 4; mt++)
                #pragma unroll
                for (int nt = 0; nt < 3; nt++)
                    acc[mt][nt] = __builtin_amdgcn_mfma_f32_16x16x32_bf16(
                        a[mt], bq[nt], acc[mt][nt], 0, 0, 0);
        }
    };

    for (int p = 0; p < 41; ++p) {
        STAGE(p);
        __syncthreads();
        COMPUTE();
        __syncthreads();
    }

    #pragma unroll
    for (int nt = 0; nt < 3; nt++) {
        int pxl = wn * 48 + nt * 16 + l15;
        #pragma unroll
        for (int mt = 0; mt < 4; mt++) {
            int ocb = wm * 64 + mt * 16 + lk * 4;
            float4 bias = *reinterpret_cast<const float4*>(b1 + ocb);
            const float* bp = reinterpret_cast<const float*>(&bias);
            ushort4 u;
            u.x = bfb(fmaxf(acc[mt][nt][0] + bp[0], 0.f));
            u.y = bfb(fmaxf(acc[mt][nt][1] + bp[1], 0.f));
            u.z = bfb(fmaxf(acc[mt][nt][2] + bp[2], 0.f));
            u.w = bfb(fmaxf(acc[mt][nt][3] + bp[3], 0.f));
            int chunk = (ocb >> 3) ^ (pxl & 7);
            *reinterpret_cast<ushort4*>(&S[(size_t)pxl * 128 + chunk * 8 + (lk & 1) * 4]) = u;
        }
    }
    __syncthreads();
    {
        bf16* dst = hmidp + (size_t)b * HPW * 128 + ((size_t)(row + 1) * HP_ + 1) * 128;
        #pragma unroll
        for (int i = 0; i < 6; i++) {
            int f = tid + i * 256;
            int px = f >> 4, cc = f & 15;
            short8 v = *reinterpret_cast<const short8*>(
                &S[(size_t)px * 128 + (cc ^ (px & 7)) * 8]);
            *reinterpret_cast<short8*>(dst + (size_t)f * 8) = v;
        }
    }
}

// ---------------------------------------------------------------- conv2 ----
__global__ __launch_bounds__(128)
void conv2_mfma(const bf16* __restrict__ hmidp, const bf16* __restrict__ w2bf,
                const float* __restrict__ b2, float* __restrict__ out)
{
    __shared__ bf16 Abuf[1024];
    __shared__ bf16 Bbuf[6144];
    int gid = blockIdx.x;             // 768 = 8 b x 96 rows
    int b = gid & 7;
    int y = gid >> 3;
    int p0 = y * 96;
    int tid = threadIdx.x, lane = tid & 63;
    int wn = tid >> 6;
    int l15 = lane & 15, lk = lane >> 4;
    const bf16* hb = hmidp + (size_t)b * HPW * 128;

    int wbase = tid & 64;
    int t3 = (tid >> 3) & 7;
    int cX = (tid & 7) ^ t3;
    int r0 = tid >> 3;
    int swzE0 = ((lk) ^ (l15 & 7)) * 8;
    int swzE1 = ((4 + lk) ^ (l15 & 7)) * 8;

    f32x4 acc[3] = {};

    auto STAGE = [&](int s) {
        int tap = s >> 1, half = s & 1;
        int toff = (tap / 3) * HP_ + (tap % 3);
        gload_lds16(w2bf + ((size_t)s * 16 + r0) * 64 + cX * 8,
                    &Abuf[(size_t)wbase * 8]);
        #pragma unroll
        for (int i = 0; i < 6; i++) {
            int c = i * 16 + r0;
            gload_lds16(hb + (size_t)(y * HP_ + c + toff) * 128 + half * 64 + cX * 8,
                        &Bbuf[(size_t)(i * 128 + wbase) * 8]);
        }
    };

    auto COMPUTE = [&]() {
        #pragma unroll
        for (int k = 0; k < 2; k++) {
            int swz = k ? swzE1 : swzE0;
            short8 a = *reinterpret_cast<const short8*>(&Abuf[(size_t)l15 * 64 + swz]);
            #pragma unroll
            for (int nt = 0; nt < 3; nt++) {
                short8 bq = *reinterpret_cast<const short8*>(
                    &Bbuf[(size_t)(wn * 48 + nt * 16 + l15) * 64 + swz]);
                acc[nt] = __builtin_amdgcn_mfma_f32_16x16x32_bf16(a, bq, acc[nt], 0, 0, 0);
            }
        }
    };

    for (int s = 0; s < 18; ++s) {
        STAGE(s);
        __syncthreads();
        COMPUTE();
        __syncthreads();
    }

    if (lk == 0) {
        float bb0 = b2[0], bb1 = b2[1];
        #pragma unroll
        for (int nt = 0; nt < 3; nt++) {
            int px = p0 + wn * 48 + nt * 16 + l15;
            out[((size_t)b * 2 + 0) * HW_ + px] = acc[nt][0] + bb0;
            out[((size_t)b * 2 + 1) * HW_ + px] = acc[nt][1] + bb1;
        }
    }
}

// ---------------------------------------------------------------- launch ----
extern "C" void kernel_launch(void* const* d_in, const int* in_sizes, int n_in,
                              void* d_out, int out_size, void* d_ws, size_t ws_size,
                              hipStream_t stream)
{
    const float* cur_embed  = (const float*)d_in[0];
    const float* cur_decode = (const float*)d_in[1];
    const float* init_embed = (const float*)d_in[2];
    const float* init_seg   = (const float*)d_in[3];
    const float* prev_embed = (const float*)d_in[4];
    const float* prev_seg   = (const float*)d_in[5];
    const float* W1 = (const float*)d_in[6];
    const float* b1 = (const float*)d_in[7];
    const float* W2 = (const float*)d_in[8];
    const float* b2 = (const float*)d_in[9];
    float* out = (float*)d_out;

    char* ws = (char*)d_ws;
    bf16* hcat8 = (bf16*)ws;
    bf16* curbf = (bf16*)ws;                          // alias (dead after lmap)
    bf16* hcat1 = (bf16*)(ws + 39337984);
    const size_t HCAT_REGION = 40567296;
    bf16* hmidp  = (bf16*)(ws + HCAT_REGION);
    bf16* fibf   = (bf16*)(ws + HCAT_REGION);
    bf16* prevbf = (bf16*)(ws + HCAT_REGION);
    float* si  = (float*)(ws + HCAT_REGION + 2621440);
    bf16* w1bf = (bf16*)(ws + 60236288);
    bf16* w2bf = (bf16*)(ws + 60908032);
    float* gout = (float*)(ws + 60944896);
    float* lout = (float*)(ws + 61534720);
    const bf16* zbuf = w1bf + (size_t)81 * 4096;      // slab 81 = zeros

    { prep_kernel<<<11152, 256, 0, stream>>>(W1, W2, init_embed, init_seg, cur_embed,
                                             w1bf, w2bf, fibf, si, curbf); }
    { gmap_mfma<<<768, 256, 0, stream>>>(curbf, fibf, si, gout); }
    for (int g = 0; g < 2; g++) {
        dim3 gt(144, 4, 4);
        tcur_kernel<<<gt, 256, 0, stream>>>(prev_embed + (size_t)g * 4 * C_ * HW_, prevbf);
        dim3 gl(144, 4);
        lmap_mfma<<<gl, 256, 0, stream>>>(curbf, prevbf, zbuf, prev_seg, lout, g * 4);
    }
    { packall_kernel<<<4909, 256, 0, stream>>>(cur_decode, gout, lout, init_seg,
                                               prev_seg, hcat8, hcat1, hmidp); }
    { conv1_mfma<<<768, 256, 0, stream>>>(hcat8, hcat1, w1bf, b1, hmidp); }
    { conv2_mfma<<<768, 128, 0, stream>>>(hmidp, w2bf, b2, out); }
}

// Round 18
// 239.200 us; speedup vs baseline: 3.1107x; 1.0025x over previous
//
#include <hip/hip_runtime.h>
#include <hip/hip_bf16.h>

// Round 18: transpose-tile XOR swizzle (16B-chunk ^ row-quad) in prep/tcur/packall
//           kills the 8-way LDS read conflict (4.1M conflicts/dispatch).
//           All MFMA kernels byte-identical to r17 (passing, 240 us).
// ws layout (62.12 MB, aliased): unchanged from r17.

typedef __hip_bfloat16 bf16;
typedef __attribute__((ext_vector_type(8))) short short8;
typedef __attribute__((ext_vector_type(4))) float f32x4;

constexpr int B_  = 8;
constexpr int C_  = 256;
constexpr int H_  = 96;
constexpr int W_  = 96;
constexpr int HW_ = H_ * W_;       // 9216
constexpr int PW_ = 24;
constexpr int KP_ = 576;
constexpr int KPP = 640;
constexpr int HP_ = 98;
constexpr int HPW = HP_ * HP_;     // 9604
constexpr int CHK = HPW * 32;

__device__ __forceinline__ unsigned short bfb(float f) {
    bf16 h = __float2bfloat16(f);
    return *reinterpret_cast<unsigned short*>(&h);
}

__device__ __forceinline__ void gload_lds16(const bf16* g, bf16* l) {
    __builtin_amdgcn_global_load_lds((const void*)g, (void*)l, 16, 0, 0);
}

// swizzled transpose helpers: store row r, 16B-chunk c at chunk c ^ ((r>>2)&7)
__device__ __forceinline__ int tswz(int col, int row) {   // element col -> physical col
    return (col & 3) + 4 * (((col >> 2) ^ (row >> 2)) & 7 ? (((col >> 2) ^ (row >> 2)) & 15) : (((col >> 2) ^ (row >> 2)) & 15));
}

// ------------------------------------------------------------ prep ----
// blocks [0,1384): W1/W2 convert ; [1384,6544): pool ; [6544,11152): tcur(cur).
__global__ __launch_bounds__(256)
void prep_kernel(const float* __restrict__ W1, const float* __restrict__ W2,
                 const float* __restrict__ init_embed, const float* __restrict__ init_seg,
                 const float* __restrict__ cur_embed,
                 bf16* __restrict__ w1bf, bf16* __restrict__ w2bf,
                 bf16* __restrict__ fibf, float* __restrict__ si,
                 bf16* __restrict__ curbf)
{
    __shared__ float tile[64][68];
    int gid = blockIdx.x;
    int t = threadIdx.x;
    if (gid < 1384) {
        int idx = gid * 256 + t;
        if (idx < 82 * 128 * 32) {
            int ic = idx & 31;
            int oc = (idx >> 5) & 127;
            int ks = idx >> 12;
            int icc = ks / 9, tap = ks % 9;
            int icg = icc * 32 + ic;
            float v = (icg < 264) ? W1[((size_t)oc * 264 + icg) * 9 + tap] : 0.f;
            w1bf[idx] = __float2bfloat16(v);
        } else {
            int j = idx - 82 * 128 * 32;
            if (j >= 18 * 16 * 64) return;
            int c  = j & 63;
            int oc = (j >> 6) & 15;
            int s  = j >> 10;
            int tap = s >> 1, half = s & 1;
            float v = (oc < 2) ? W2[((size_t)oc * 128 + half * 64 + c) * 9 + tap] : 0.f;
            w2bf[j] = __float2bfloat16(v);
        }
    } else if (gid < 6544) {
        int idx = (gid - 1384) * 256 + t;
        int k  = idx % KPP;
        int ch = (idx / KPP) % (C_ + 2);
        int b  = idx / (KPP * (C_ + 2));
        float s = 0.f;
        if (k < KP_) {
            int ph = k / PW_, pw = k % PW_;
            const float* src = (ch < C_)
                ? (init_embed + (((size_t)b * C_ + ch) * H_ + ph * 4) * W_ + pw * 4)
                : (init_seg   + (((size_t)b * 2 + (ch - C_)) * H_ + ph * 4) * W_ + pw * 4);
            #pragma unroll
            for (int r = 0; r < 4; r++) {
                float4 v = *reinterpret_cast<const float4*>(src + r * W_);
                s += v.x + v.y + v.z + v.w;
            }
            s *= (1.f / 16.f);
        }
        if (ch < C_) fibf[((size_t)b * KPP + k) * C_ + ch] = __float2bfloat16(s);
        else         si[(size_t)b * 2 * KPP + (ch - C_) * KPP + k] = s;
    } else {
        int t6 = gid - 6544;                  // [0,4608): 8 b x 4 cgrp x 144 pgrp
        int b = t6 / 576;
        int rem = t6 % 576;
        int c0 = (rem / 144) * 64, p0 = (rem % 144) * 64;
        const float* src = cur_embed + ((size_t)b * C_ + c0) * HW_ + p0;
        #pragma unroll
        for (int it = 0; it < 4; it++) {
            int f = t + it * 256;
            int cl = f >> 4, p4 = (f & 15) * 4;
            float4 v = *reinterpret_cast<const float4*>(src + (size_t)cl * HW_ + p4);
            int pc = 4 * (((p4 >> 2) ^ (cl >> 2)) & 15);
            *reinterpret_cast<float4*>(&tile[cl][pc]) = v;
        }
        __syncthreads();
        bf16* dst = curbf + ((size_t)b * HW_ + p0) * 256 + c0;
        #pragma unroll
        for (int it = 0; it < 4; it++) {
            int f = t + it * 256;
            int pl = f >> 4, c4 = (f & 15) * 4;
            int col = (pl & 3) + 4 * (((pl >> 2) ^ (c4 >> 2)) & 15);
            ushort4 u;
            u.x = bfb(tile[c4 + 0][col]); u.y = bfb(tile[c4 + 1][col]);
            u.z = bfb(tile[c4 + 2][col]); u.w = bfb(tile[c4 + 3][col]);
            *reinterpret_cast<ushort4*>(dst + (size_t)pl * 256 + c4) = u;
        }
    }
}

// ------------------------------------------------------- NCHW->NHWC bf16 ----
__global__ __launch_bounds__(256)
void tcur_kernel(const float* __restrict__ cur, bf16* __restrict__ curbf)
{
    __shared__ float tile[64][68];
    int b = blockIdx.z, c0 = blockIdx.y * 64, p0 = blockIdx.x * 64;
    int t = threadIdx.x;
    const float* src = cur + ((size_t)b * C_ + c0) * HW_ + p0;
    #pragma unroll
    for (int it = 0; it < 4; it++) {
        int f = t + it * 256;
        int cl = f >> 4, p4 = (f & 15) * 4;
        float4 v = *reinterpret_cast<const float4*>(src + (size_t)cl * HW_ + p4);
        int pc = 4 * (((p4 >> 2) ^ (cl >> 2)) & 15);
        *reinterpret_cast<float4*>(&tile[cl][pc]) = v;
    }
    __syncthreads();
    bf16* dst = curbf + ((size_t)b * HW_ + p0) * 256 + c0;
    #pragma unroll
    for (int it = 0; it < 4; it++) {
        int f = t + it * 256;
        int pl = f >> 4, c4 = (f & 15) * 4;
        int col = (pl & 3) + 4 * (((pl >> 2) ^ (c4 >> 2)) & 15);
        ushort4 u;
        u.x = bfb(tile[c4 + 0][col]); u.y = bfb(tile[c4 + 1][col]);
        u.z = bfb(tile[c4 + 2][col]); u.w = bfb(tile[c4 + 3][col]);
        *reinterpret_cast<ushort4*>(dst + (size_t)pl * 256 + c4) = u;
    }
}

// ---------------------------------------------------------------- gmap ----
__global__ __launch_bounds__(256)
void gmap_mfma(const bf16* __restrict__ curbf, const bf16* __restrict__ fibf,
               const float* __restrict__ si, float* __restrict__ gout)
{
    __shared__ bf16 Abuf[8192];
    __shared__ bf16 Bbuf[6144];
    __shared__ float bred[2][2][2][48];
    int gid = blockIdx.x;             // 768 = 8 b x 96 px-tiles
    int b = gid & 7;
    int p0 = (gid >> 3) * 96;
    int tid = threadIdx.x, lane = tid & 63;
    int w = tid >> 6, wm = w & 1, wn = w >> 1;
    int l15 = lane & 15, lk = lane >> 4;
    const bf16* fb = fibf + (size_t)b * KPP * 256;
    const bf16* cb = curbf + (size_t)b * HW_ * 256;
    const float* sib = si + (size_t)b * 2 * KPP;

    int wbase = tid & 192;
    int t3 = (tid >> 3) & 7;
    int cX = (tid & 7) ^ t3;
    int r0 = tid >> 3;
    int swzE0 = ((lk) ^ (l15 & 7)) * 8;
    int swzE1 = ((4 + lk) ^ (l15 & 7)) * 8;

    float best[2][3];
    #pragma unroll
    for (int s = 0; s < 2; s++)
        #pragma unroll
        for (int nt = 0; nt < 3; nt++) best[s][nt] = -INFINITY;
    f32x4 acc[4][3] = {};

    auto STAGE = [&](int q) {
        int chunk = q >> 2, ks = q & 3;
        int koff = ks * 64 + cX * 8;
        #pragma unroll
        for (int i = 0; i < 4; i++) {
            int row = i * 32 + r0;
            gload_lds16(fb + (size_t)(chunk * 128 + row) * 256 + koff,
                        &Abuf[(size_t)(i * 256 + wbase) * 8]);
        }
        #pragma unroll
        for (int i = 0; i < 3; i++) {
            int row = i * 32 + r0;
            gload_lds16(cb + (size_t)(p0 + row) * 256 + koff,
                        &Bbuf[(size_t)(i * 256 + wbase) * 8]);
        }
    };

    auto COMPUTE = [&]() {
        #pragma unroll
        for (int k = 0; k < 2; k++) {
            int swz = k ? swzE1 : swzE0;
            short8 a[4], bq[3];
            #pragma unroll
            for (int mt = 0; mt < 4; mt++)
                a[mt] = *reinterpret_cast<const short8*>(
                    &Abuf[(size_t)(wm * 64 + mt * 16 + l15) * 64 + swz]);
            #pragma unroll
            for (int nt = 0; nt < 3; nt++)
                bq[nt] = *reinterpret_cast<const short8*>(
                    &Bbuf[(size_t)(wn * 48 + nt * 16 + l15) * 64 + swz]);
            #pragma unroll
            for (int mt = 0; mt < 4; mt++)
                #pragma unroll
                for (int nt = 0; nt < 3; nt++)
                    acc[mt][nt] = __builtin_amdgcn_mfma_f32_16x16x32_bf16(
                        a[mt], bq[nt], acc[mt][nt], 0, 0, 0);
        }
    };

    for (int q = 0; q < 20; ++q) {
        STAGE(q);
        __syncthreads();
        COMPUTE();
        if ((q & 3) == 3) {
            int kp0 = (q >> 2) * 128;
            #pragma unroll
            for (int mt = 0; mt < 4; mt++) {
                int rb = kp0 + wm * 64 + mt * 16 + lk * 4;
                float4 s0 = *reinterpret_cast<const float4*>(sib + rb);
                float4 s1 = *reinterpret_cast<const float4*>(sib + KPP + rb);
                const float* s0p = reinterpret_cast<const float*>(&s0);
                const float* s1p = reinterpret_cast<const float*>(&s1);
                #pragma unroll
                for (int nt = 0; nt < 3; nt++) {
                    #pragma unroll
                    for (int r = 0; r < 4; r++) {
                        float v = acc[mt][nt][r];
                        best[0][nt] = fmaxf(best[0][nt], v * s0p[r]);
                        best[1][nt] = fmaxf(best[1][nt], v * s1p[r]);
                    }
                    acc[mt][nt] = (f32x4){0.f, 0.f, 0.f, 0.f};
                }
            }
        }
        __syncthreads();
    }
    #pragma unroll
    for (int s = 0; s < 2; s++)
        #pragma unroll
        for (int nt = 0; nt < 3; nt++) {
            float v = best[s][nt];
            v = fmaxf(v, __shfl_xor(v, 16));
            v = fmaxf(v, __shfl_xor(v, 32));
            if (lk == 0) bred[wm][wn][s][nt * 16 + l15] = v;
        }
    __syncthreads();
    if (tid < 192) {
        int s2 = tid / 96, pxl = tid % 96;
        float v = fmaxf(bred[0][pxl / 48][s2][pxl % 48],
                        bred[1][pxl / 48][s2][pxl % 48]);
        gout[((size_t)b * 2 + s2) * HW_ + p0 + pxl] = v;
    }
}

// ---------------------------------------------------------------- lmap ----
__global__ __launch_bounds__(256)
void lmap_mfma(const bf16* __restrict__ curbf, const bf16* __restrict__ prevbf,
               const bf16* __restrict__ zbuf,
               const float* __restrict__ prev_seg, float* __restrict__ lout, int b0)
{
    constexpr int GSTR = 258;
    __shared__ __align__(16) char Smem[40960];
    bf16* Abuf = (bf16*)Smem;
    bf16* Bbuf = (bf16*)(Smem + 8192);
    bf16* Gb   = (bf16*)Smem;
    float* segf = (float*)(Smem + 33024);
    float* redf = (float*)(Smem + 35072);

    int b = b0 + blockIdx.y;
    const bf16* pb = prevbf + (size_t)blockIdx.y * HW_ * 256;
    const bf16* cb = curbf + (size_t)b * HW_ * 256;
    int tile = blockIdx.x;
    int ty0 = (tile / 12) * 8, tx0 = (tile % 12) * 8;
    int tid = threadIdx.x, lane = tid & 63, wn = tid >> 6;
    int l15 = lane & 15, lk = lane >> 4;

    int wbase = tid & 192;
    int t3 = (tid >> 3) & 7;
    int cX = (tid & 7) ^ t3;
    int r0 = tid >> 3;
    int swzE0 = ((lk) ^ (l15 & 7)) * 8;
    int swzE1 = ((4 + lk) ^ (l15 & 7)) * 8;

    int gpxA0 = (ty0 + (r0 >> 3)) * W_ + tx0 + (r0 & 7);
    int gpxA1 = (ty0 + (r0 >> 3) + 4) * W_ + tx0 + (r0 & 7);
    const bf16* rowB[8];
    #pragma unroll
    for (int i = 0; i < 8; i++) {
        int wrow = i * 32 + r0;
        int wy = wrow >> 4, wx = wrow & 15;
        int gy = ty0 - 4 + wy, gx = tx0 - 4 + wx;
        bool ok = (gy >= 0) && (gy < H_) && (gx >= 0) && (gx < W_);
        rowB[i] = ok ? (pb + (size_t)(gy * W_ + gx) * 256) : zbuf;
    }

    f32x4 acc[4][4] = {};

    for (int ks = 0; ks < 4; ++ks) {
        int koff = ks * 64 + cX * 8;
        gload_lds16(cb + (size_t)gpxA0 * 256 + koff, &Abuf[(size_t)(wbase) * 8]);
        gload_lds16(cb + (size_t)gpxA1 * 256 + koff, &Abuf[(size_t)(256 + wbase) * 8]);
        #pragma unroll
        for (int i = 0; i < 8; i++)
            gload_lds16(rowB[i] + koff, &Bbuf[(size_t)(i * 256 + wbase) * 8]);
        __syncthreads();
        #pragma unroll
        for (int k = 0; k < 2; k++) {
            int swz = k ? swzE1 : swzE0;
            short8 a[4], bq[4];
            #pragma unroll
            for (int mt = 0; mt < 4; mt++)
                a[mt] = *reinterpret_cast<const short8*>(
                    &Abuf[(size_t)(mt * 16 + l15) * 64 + swz]);
            #pragma unroll
            for (int nt = 0; nt < 4; nt++)
                bq[nt] = *reinterpret_cast<const short8*>(
                    &Bbuf[(size_t)(wn * 64 + nt * 16 + l15) * 64 + swz]);
            #pragma unroll
            for (int mt = 0; mt < 4; mt++)
                #pragma unroll
                for (int nt = 0; nt < 4; nt++)
                    acc[mt][nt] = __builtin_amdgcn_mfma_f32_16x16x32_bf16(
                        a[mt], bq[nt], acc[mt][nt], 0, 0, 0);
        }
        __syncthreads();
    }

    #pragma unroll
    for (int mt = 0; mt < 4; mt++)
        #pragma unroll
        for (int nt = 0; nt < 4; nt++)
            #pragma unroll
            for (int r = 0; r < 4; r++)
                Gb[(mt * 16 + lk * 4 + r) * GSTR + wn * 64 + nt * 16 + l15] =
                    __float2bfloat16(acc[mt][nt][r]);
    #pragma unroll
    for (int it = 0; it < 2; it++) {
        int f = tid + it * 256;
        int s = f >> 8, wp = f & 255;
        int wy = wp >> 4, wx = wp & 15;
        int gy = ty0 - 4 + wy, gxx = tx0 - 4 + wx;
        float v = 0.f;
        if (gy >= 0 && gy < H_ && gxx >= 0 && gxx < W_)
            v = prev_seg[((size_t)b * 2 + s) * HW_ + gy * W_ + gxx] * (1.f / 256.f);
        segf[f] = v;
    }
    __syncthreads();
    {
        int m = tid & 63;
        int sh = tid >> 6;
        int s = sh >> 1, hh = sh & 1;
        int py = m >> 3, lx = m & 7;
        const bf16* gr = Gb + (size_t)m * GSTR;
        const float* sr = segf + s * 256;
        float mx = -INFINITY;
        int wr0 = hh * 5, wr1 = hh ? 9 : 5;
        for (int wr = wr0; wr < wr1; ++wr) {
            int base = (py + wr) * 16 + lx;
            #pragma unroll
            for (int wc = 0; wc < 9; ++wc)
                mx = fmaxf(mx, __bfloat162float(gr[base + wc]) * sr[base + wc]);
        }
        redf[sh * 64 + m] = mx;
    }
    __syncthreads();
    if (tid < 128) {
        int s = tid >> 6, m = tid & 63;
        float v = fmaxf(redf[(s * 2 + 0) * 64 + m], redf[(s * 2 + 1) * 64 + m]);
        int gpx = (ty0 + (m >> 3)) * W_ + tx0 + (m & 7);
        lout[((size_t)b * 2 + s) * HW_ + gpx] = v;
    }
}

// ---------------------------------------------------------------- packall ----
__global__ __launch_bounds__(256)
void packall_kernel(const float* __restrict__ dec,
                    const float* __restrict__ gout, const float* __restrict__ lout,
                    const float* __restrict__ init_seg, const float* __restrict__ prev_seg,
                    bf16* __restrict__ hcat8, bf16* __restrict__ hcat1,
                    bf16* __restrict__ hmidp)
{
    __shared__ float tile[64][68];
    int gid = blockIdx.x;
    int t = threadIdx.x;
    if (gid < 4608) {
        int b = gid / 576;
        int rem = gid % 576;
        int c0 = (rem / 144) * 64, p0 = (rem % 144) * 64;
        const float* src = dec + ((size_t)b * C_ + c0) * HW_ + p0;
        #pragma unroll
        for (int it = 0; it < 4; it++) {
            int f = t + it * 256;
            int cl = f >> 4, p4 = (f & 15) * 4;
            float4 v = *reinterpret_cast<const float4*>(src + (size_t)cl * HW_ + p4);
            int pc = 4 * (((p4 >> 2) ^ (cl >> 2)) & 15);
            *reinterpret_cast<float4*>(&tile[cl][pc]) = v;
        }
        __syncthreads();
        #pragma unroll
        for (int it = 0; it < 4; it++) {
            int f = t + it * 256;
            int pl = f >> 4, c4 = (f & 15) * 4;
            int p = p0 + pl;
            int y = p / 96, x = p % 96;
            int pos = (y + 1) * HP_ + x + 1;
            int ch = c0 + c4;
            int col = (pl & 3) + 4 * (((pl >> 2) ^ (c4 >> 2)) & 15);
            ushort4 u;
            u.x = bfb(tile[c4 + 0][col]); u.y = bfb(tile[c4 + 1][col]);
            u.z = bfb(tile[c4 + 2][col]); u.w = bfb(tile[c4 + 3][col]);
            bf16* dst = hcat8 + ((size_t)b * 8 + (ch >> 5)) * CHK + (size_t)pos * 32 + (ch & 31);
            *reinterpret_cast<ushort4*>(dst) = u;
        }
    } else if (gid < 4896) {
        int idx = (gid - 4608) * 256 + t;
        int b = idx / HW_, p = idx % HW_;
        int y = p / 96, x = p % 96;
        int pos = (y + 1) * HP_ + x + 1;
        bf16* dst = hcat1 + ((size_t)b * HPW + pos) * 8;
        float g0 = gout[((size_t)b * 2 + 0) * HW_ + p];
        float g1 = gout[((size_t)b * 2 + 1) * HW_ + p];
        float i0 = init_seg[((size_t)b * 2 + 0) * HW_ + p];
        float i1 = init_seg[((size_t)b * 2 + 1) * HW_ + p];
        float l0 = lout[((size_t)b * 2 + 0) * HW_ + p];
        float l1 = lout[((size_t)b * 2 + 1) * HW_ + p];
        float q0 = prev_seg[((size_t)b * 2 + 0) * HW_ + p];
        float q1 = prev_seg[((size_t)b * 2 + 1) * HW_ + p];
        ushort4 u; u.x = bfb(g0); u.y = bfb(g1); u.z = bfb(i0); u.w = bfb(i1);
        *reinterpret_cast<ushort4*>(dst) = u;
        ushort4 u2; u2.x = bfb(l0); u2.y = bfb(l1); u2.z = bfb(q0); u2.w = bfb(q1);
        *reinterpret_cast<ushort4*>(dst + 4) = u2;
    } else {
        int idx = (gid - 4896) * 256 + t;
        if (idx >= B_ * 388) return;
        int b = idx / 388, bi = idx % 388;
        int pos;
        if (bi < 98) pos = bi;
        else if (bi < 196) pos = 97 * HP_ + (bi - 98);
        else if (bi < 292) pos = (bi - 196 + 1) * HP_;
        else pos = (bi - 292 + 1) * HP_ + 97;
        const short8 Z = {0, 0, 0, 0, 0, 0, 0, 0};
        #pragma unroll
        for (int c = 0; c < 8; c++) {
            bf16* p = hcat8 + ((size_t)b * 8 + c) * CHK + (size_t)pos * 32;
            #pragma unroll
            for (int j = 0; j < 4; j++)
                *reinterpret_cast<short8*>(p + j * 8) = Z;
        }
        *reinterpret_cast<short8*>(hcat1 + ((size_t)b * HPW + pos) * 8) = Z;
        bf16* q = hmidp + ((size_t)b * HPW + pos) * 128;
        #pragma unroll
        for (int j = 0; j < 16; j++)
            *reinterpret_cast<short8*>(q + j * 8) = Z;
    }
}

// ---------------------------------------------------------------- conv1 ----
__global__ __launch_bounds__(256)
void conv1_mfma(const bf16* __restrict__ hcat8, const bf16* __restrict__ hcat1,
                const bf16* __restrict__ w1bf, const float* __restrict__ b1,
                bf16* __restrict__ hmidp)
{
    __shared__ bf16 S[14336];
    bf16* Abuf = S;
    bf16* Bbuf = S + 8192;
    int gid = blockIdx.x;                     // 768 = 8 b x 96 rows
    int b = gid & 7;
    int row = gid >> 3;
    int tid = threadIdx.x, lane = tid & 63;
    int w = tid >> 6, wm = w & 1, wn = w >> 1;
    int l15 = lane & 15, lk = lane >> 4;
    const bf16* hb8 = hcat8 + (size_t)b * 8 * CHK;
    const bf16* hb1 = hcat1 + (size_t)b * HPW * 8;

    int wbase = tid & 192;
    int t3 = (tid >> 3) & 7;
    int cX = (tid & 7) ^ t3;
    int selX = cX >> 2;
    int cin8 = (cX & 3) * 8;
    int r0 = tid >> 3;
    int swzE0 = ((lk) ^ (l15 & 7)) * 8;
    int swzE1 = ((4 + lk) ^ (l15 & 7)) * 8;

    f32x4 acc[4][3] = {};

    auto STAGE = [&](int p) {
        int s0 = 2 * p, s1 = s0 + 1;
        int icc0 = s0 / 9, tap0 = s0 - icc0 * 9;
        int icc1 = s1 / 9, tap1 = s1 - icc1 * 9;
        const bf16* gA = w1bf + (size_t)p * 8192 + (size_t)selX * 4096 + cin8;
        #pragma unroll
        for (int i = 0; i < 4; i++)
            gload_lds16(gA + (i * 32 + r0) * 32,
                        &Abuf[(size_t)(i * 256 + wbase) * 8]);
        int tapS = selX ? tap1 : tap0;
        int iccS = selX ? icc1 : icc0;
        int posT = (row + tapS / 3) * HP_ + (tapS % 3);
        bool is8 = (iccS >= 8);
        const bf16* gb = is8 ? hb1 : (hb8 + (size_t)iccS * CHK);
        #pragma unroll
        for (int i = 0; i < 3; i++) {
            int c = i * 32 + r0;
            const bf16* g = is8 ? (gb + (size_t)(posT + c) * 8)
                                : (gb + (size_t)(posT + c) * 32 + cin8);
            gload_lds16(g, &Bbuf[(size_t)(i * 256 + wbase) * 8]);
        }
    };

    auto COMPUTE = [&]() {
        #pragma unroll
        for (int k = 0; k < 2; k++) {
            int swz = k ? swzE1 : swzE0;
            short8 a[4], bq[3];
            #pragma unroll
            for (int mt = 0; mt < 4; mt++)
                a[mt] = *reinterpret_cast<const short8*>(
                    &Abuf[(size_t)(wm * 64 + mt * 16 + l15) * 64 + swz]);
            #pragma unroll
            for (int nt = 0; nt < 3; nt++)
                bq[nt] = *reinterpret_cast<const short8*>(
                    &Bbuf[(size_t)(wn * 48 + nt * 16 + l15) * 64 + swz]);
            #pragma unroll
            for (int mt = 0; mt < 4; mt++)
                #pragma unroll
                for (int nt = 0; nt < 3; nt++)
                    acc[mt][nt] = __builtin_amdgcn_mfma_f32_16x16x32_bf16(
                        a[mt], bq[nt], acc[mt][nt], 0, 0, 0);
        }
    };

    for (int p = 0; p < 41; ++p) {
        STAGE(p);
        __syncthreads();
        COMPUTE();
        __syncthreads();
    }

    #pragma unroll
    for (int nt = 0; nt < 3; nt++) {
        int pxl = wn * 48 + nt * 16 + l15;
        #pragma unroll
        for (int mt = 0; mt < 4; mt++) {
            int ocb = wm * 64 + mt * 16 + lk * 4;
            float4 bias = *reinterpret_cast<const float4*>(b1 + ocb);
            const float* bp = reinterpret_cast<const float*>(&bias);
            ushort4 u;
            u.x = bfb(fmaxf(acc[mt][nt][0] + bp[0], 0.f));
            u.y = bfb(fmaxf(acc[mt][nt][1] + bp[1], 0.f));
            u.z = bfb(fmaxf(acc[mt][nt][2] + bp[2], 0.f));
            u.w = bfb(fmaxf(acc[mt][nt][3] + bp[3], 0.f));
            int chunk = (ocb >> 3) ^ (pxl & 7);
            *reinterpret_cast<ushort4*>(&S[(size_t)pxl * 128 + chunk * 8 + (lk & 1) * 4]) = u;
        }
    }
    __syncthreads();
    {
        bf16* dst = hmidp + (size_t)b * HPW * 128 + ((size_t)(row + 1) * HP_ + 1) * 128;
        #pragma unroll
        for (int i = 0; i < 6; i++) {
            int f = tid + i * 256;
            int px = f >> 4, cc = f & 15;
            short8 v = *reinterpret_cast<const short8*>(
                &S[(size_t)px * 128 + (cc ^ (px & 7)) * 8]);
            *reinterpret_cast<short8*>(dst + (size_t)f * 8) = v;
        }
    }
}

// ---------------------------------------------------------------- conv2 ----
__global__ __launch_bounds__(128)
void conv2_mfma(const bf16* __restrict__ hmidp, const bf16* __restrict__ w2bf,
                const float* __restrict__ b2, float* __restrict__ out)
{
    __shared__ bf16 Abuf[1024];
    __shared__ bf16 Bbuf[6144];
    int gid = blockIdx.x;             // 768 = 8 b x 96 rows
    int b = gid & 7;
    int y = gid >> 3;
    int p0 = y * 96;
    int tid = threadIdx.x, lane = tid & 63;
    int wn = tid >> 6;
    int l15 = lane & 15, lk = lane >> 4;
    const bf16* hb = hmidp + (size_t)b * HPW * 128;

    int wbase = tid & 64;
    int t3 = (tid >> 3) & 7;
    int cX = (tid & 7) ^ t3;
    int r0 = tid >> 3;
    int swzE0 = ((lk) ^ (l15 & 7)) * 8;
    int swzE1 = ((4 + lk) ^ (l15 & 7)) * 8;

    f32x4 acc[3] = {};

    auto STAGE = [&](int s) {
        int tap = s >> 1, half = s & 1;
        int toff = (tap / 3) * HP_ + (tap % 3);
        gload_lds16(w2bf + ((size_t)s * 16 + r0) * 64 + cX * 8,
                    &Abuf[(size_t)wbase * 8]);
        #pragma unroll
        for (int i = 0; i < 6; i++) {
            int c = i * 16 + r0;
            gload_lds16(hb + (size_t)(y * HP_ + c + toff) * 128 + half * 64 + cX * 8,
                        &Bbuf[(size_t)(i * 128 + wbase) * 8]);
        }
    };

    auto COMPUTE = [&]() {
        #pragma unroll
        for (int k = 0; k < 2; k++) {
            int swz = k ? swzE1 : swzE0;
            short8 a = *reinterpret_cast<const short8*>(&Abuf[(size_t)l15 * 64 + swz]);
            #pragma unroll
            for (int nt = 0; nt < 3; nt++) {
                short8 bq = *reinterpret_cast<const short8*>(
                    &Bbuf[(size_t)(wn * 48 + nt * 16 + l15) * 64 + swz]);
                acc[nt] = __builtin_amdgcn_mfma_f32_16x16x32_bf16(a, bq, acc[nt], 0, 0, 0);
            }
        }
    };

    for (int s = 0; s < 18; ++s) {
        STAGE(s);
        __syncthreads();
        COMPUTE();
        __syncthreads();
    }

    if (lk == 0) {
        float bb0 = b2[0], bb1 = b2[1];
        #pragma unroll
        for (int nt = 0; nt < 3; nt++) {
            int px = p0 + wn * 48 + nt * 16 + l15;
            out[((size_t)b * 2 + 0) * HW_ + px] = acc[nt][0] + bb0;
            out[((size_t)b * 2 + 1) * HW_ + px] = acc[nt][1] + bb1;
        }
    }
}

// ---------------------------------------------------------------- launch ----
extern "C" void kernel_launch(void* const* d_in, const int* in_sizes, int n_in,
                              void* d_out, int out_size, void* d_ws, size_t ws_size,
                              hipStream_t stream)
{
    const float* cur_embed  = (const float*)d_in[0];
    const float* cur_decode = (const float*)d_in[1];
    const float* init_embed = (const float*)d_in[2];
    const float* init_seg   = (const float*)d_in[3];
    const float* prev_embed = (const float*)d_in[4];
    const float* prev_seg   = (const float*)d_in[5];
    const float* W1 = (const float*)d_in[6];
    const float* b1 = (const float*)d_in[7];
    const float* W2 = (const float*)d_in[8];
    const float* b2 = (const float*)d_in[9];
    float* out = (float*)d_out;

    char* ws = (char*)d_ws;
    bf16* hcat8 = (bf16*)ws;
    bf16* curbf = (bf16*)ws;                          // alias (dead after lmap)
    bf16* hcat1 = (bf16*)(ws + 39337984);
    const size_t HCAT_REGION = 40567296;
    bf16* hmidp  = (bf16*)(ws + HCAT_REGION);
    bf16* fibf   = (bf16*)(ws + HCAT_REGION);
    bf16* prevbf = (bf16*)(ws + HCAT_REGION);
    float* si  = (float*)(ws + HCAT_REGION + 2621440);
    bf16* w1bf = (bf16*)(ws + 60236288);
    bf16* w2bf = (bf16*)(ws + 60908032);
    float* gout = (float*)(ws + 60944896);
    float* lout = (float*)(ws + 61534720);
    const bf16* zbuf = w1bf + (size_t)81 * 4096;      // slab 81 = zeros

    { prep_kernel<<<11152, 256, 0, stream>>>(W1, W2, init_embed, init_seg, cur_embed,
                                             w1bf, w2bf, fibf, si, curbf); }
    { gmap_mfma<<<768, 256, 0, stream>>>(curbf, fibf, si, gout); }
    for (int g = 0; g < 2; g++) {
        dim3 gt(144, 4, 4);
        tcur_kernel<<<gt, 256, 0, stream>>>(prev_embed + (size_t)g * 4 * C_ * HW_, prevbf);
        dim3 gl(144, 4);
        lmap_mfma<<<gl, 256, 0, stream>>>(curbf, prevbf, zbuf, prev_seg, lout, g * 4);
    }
    { packall_kernel<<<4909, 256, 0, stream>>>(cur_decode, gout, lout, init_seg,
                                               prev_seg, hcat8, hcat1, hmidp); }
    { conv1_mfma<<<768, 256, 0, stream>>>(hcat8, hcat1, w1bf, b1, hmidp); }
    { conv2_mfma<<<768, 128, 0, stream>>>(hmidp, w2bf, b2, out); }
}